// Round 1
// baseline (1749.648 us; speedup 1.0000x reference)
//
#include <hip/hip_runtime.h>
#include <math.h>

// ---- problem constants ----
#define WAYS 5
#define SHOTS 5
#define PP 10
#define FDIMC 640
#define HD 512
#define SEQ 196
#define NB 100            // key batches
#define NQB 75            // query batches
#define NMHA 80           // 5 support + 75 query
#define M1 (NB*SEQ)       // 19600
#define MMHA (NMHA*SEQ)   // 15680
#define MQ (NQB*SEQ)      // 14700
#define OUT_UPD (NQB*FDIMC*SEQ)  // 9,408,000

// ---- workspace layout (float offsets) ----
#define OFF_CS1S 0
#define OFF_CS1Q 512
#define OFF_CS2S 1024
#define OFF_CS2Q 1664
#define OFF_FEA  2304   /* double, 2 floats, zeroed */
#define ZERO_FLOATS 2306
#define OFF_ST1SC 2308
#define OFF_ST1SH 2820
#define OFF_ST2SC 3332
#define OFF_ST2SH 3972
#define OFF_M    4612                 /* 980*10 */
#define OFF_PN   14412                /* 10*512 */
#define OFF_R0   20480                /* y1 (10,035,200) -> y2 (9,408,000) */
#define OFF_R1   (OFF_R0+10035200)    /* xbuf (8,028,160) -> newq (7,526,400) */
#define OFF_R2   (OFF_R1+8028160)     /* sraw (2,508,800) */
#define OFF_R3   (OFF_R2+2508800)     /* qb -> tmp (8,028,160) */
#define OFF_R4   (OFF_R3+8028160)     /* kb -> xout (8,028,160) */
#define OFF_R5   (OFF_R4+8028160)     /* vb */
#define OFF_R6   (OFF_R5+8028160)     /* ctx */

__device__ __forceinline__ float waveSum(float v) {
#pragma unroll
  for (int o = 32; o; o >>= 1) v += __shfl_xor(v, o, 64);
  return v;
}
__device__ __forceinline__ float waveMax(float v) {
#pragma unroll
  for (int o = 32; o; o >>= 1) v = fmaxf(v, __shfl_xor(v, o, 64));
  return v;
}

#define FMA_ROW(i, av)                            \
  acc[i][0] = fmaf(av, b4.x, acc[i][0]);          \
  acc[i][1] = fmaf(av, b4.y, acc[i][1]);          \
  acc[i][2] = fmaf(av, b4.z, acc[i][2]);          \
  acc[i][3] = fmaf(av, b4.w, acc[i][3]);

// conv1: per batch n, y1[n, m(hw), o] = sum_c key[n, c, m] * Wc[o, c] + bc[o]
// A is column-major [K=640][M=196] per batch; W row-major [512][640].
__global__ __launch_bounds__(256) void conv1_gemm(const float* __restrict__ key,
    const float* __restrict__ Wc, const float* __restrict__ bc, float* __restrict__ y1) {
  __shared__ float As[16][68];
  __shared__ float Bs[16][68];
  const int n = blockIdx.z;
  const int m0 = blockIdx.y * 64;
  const int n0 = blockIdx.x * 64;
  const int tid = threadIdx.x;
  const int tr = tid >> 4, tc = tid & 15;
  const float* Ab = key + n * (FDIMC*SEQ);
  const int akk = tid >> 4;          // k offset 0..15
  const int amm = (tid & 15) << 2;   // m offset 0..60
  const int brow = tid >> 2;         // o row 0..63
  const int bk4 = (tid & 3) << 2;    // k offset 0..12
  float acc[4][4] = {};
  for (int k0 = 0; k0 < FDIMC; k0 += 16) {
    float4 av = make_float4(0.f, 0.f, 0.f, 0.f);
    const int gm = m0 + amm;
    if (gm < SEQ) av = *(const float4*)(Ab + (k0 + akk)*SEQ + gm);
    As[akk][amm] = av.x; As[akk][amm+1] = av.y; As[akk][amm+2] = av.z; As[akk][amm+3] = av.w;
    const float4 bv = *(const float4*)(Wc + (n0 + brow)*FDIMC + k0 + bk4);
    Bs[bk4][brow] = bv.x; Bs[bk4+1][brow] = bv.y; Bs[bk4+2][brow] = bv.z; Bs[bk4+3][brow] = bv.w;
    __syncthreads();
#pragma unroll
    for (int kk = 0; kk < 16; ++kk) {
      const float4 a4 = *(const float4*)&As[kk][tr << 2];
      const float4 b4 = *(const float4*)&Bs[kk][tc << 2];
      FMA_ROW(0, a4.x) FMA_ROW(1, a4.y) FMA_ROW(2, a4.z) FMA_ROW(3, a4.w)
    }
    __syncthreads();
  }
  const float4 bb = *(const float4*)(bc + n0 + (tc << 2));
#pragma unroll
  for (int i = 0; i < 4; ++i) {
    const int gm = m0 + (tr << 2) + i;
    if (gm < SEQ) {
      float4 o4 = make_float4(acc[i][0] + bb.x, acc[i][1] + bb.y, acc[i][2] + bb.z, acc[i][3] + bb.w);
      *(float4*)(y1 + (n*SEQ + gm)*HD + n0 + (tc << 2)) = o4;
    }
  }
}

// C[m,n] = sum_k A[m,k]*W[n,k] + bias[n].  A row-major [M,K], W row-major [N,K].
__global__ __launch_bounds__(256) void gemm_nt(const float* __restrict__ A, const float* __restrict__ W,
    const float* __restrict__ bias, float* __restrict__ C, int M, int N, int K) {
  __shared__ float As[16][68];
  __shared__ float Bs[16][68];
  const int m0 = blockIdx.y * 64;
  const int n0 = blockIdx.x * 64;
  const int tid = threadIdx.x;
  const int tr = tid >> 4, tc = tid & 15;
  const int arow = tid >> 2;        // 0..63
  const int ak4 = (tid & 3) << 2;   // 0..12
  float acc[4][4] = {};
  for (int k0 = 0; k0 < K; k0 += 16) {
    float4 av = make_float4(0.f, 0.f, 0.f, 0.f);
    const int gm = m0 + arow;
    if (gm < M) av = *(const float4*)(A + (size_t)gm*K + k0 + ak4);
    As[ak4][arow] = av.x; As[ak4+1][arow] = av.y; As[ak4+2][arow] = av.z; As[ak4+3][arow] = av.w;
    const float4 bv = *(const float4*)(W + (size_t)(n0 + arow)*K + k0 + ak4);
    Bs[ak4][arow] = bv.x; Bs[ak4+1][arow] = bv.y; Bs[ak4+2][arow] = bv.z; Bs[ak4+3][arow] = bv.w;
    __syncthreads();
#pragma unroll
    for (int kk = 0; kk < 16; ++kk) {
      const float4 a4 = *(const float4*)&As[kk][tr << 2];
      const float4 b4 = *(const float4*)&Bs[kk][tc << 2];
      FMA_ROW(0, a4.x) FMA_ROW(1, a4.y) FMA_ROW(2, a4.z) FMA_ROW(3, a4.w)
    }
    __syncthreads();
  }
  const float4 bb = *(const float4*)(bias + n0 + (tc << 2));
#pragma unroll
  for (int i = 0; i < 4; ++i) {
    const int gm = m0 + (tr << 2) + i;
    if (gm < M) {
      float4 o4 = make_float4(acc[i][0] + bb.x, acc[i][1] + bb.y, acc[i][2] + bb.z, acc[i][3] + bb.w);
      *(float4*)(C + (size_t)gm*N + n0 + (tc << 2)) = o4;
    }
  }
}

// per-column sum and sumsq of y [M, C] into sums/sumsq (pre-zeroed)
__global__ __launch_bounds__(256) void colsum(const float* __restrict__ y, int M, int C,
    float* __restrict__ sums, float* __restrict__ sumsq) {
  float a[3] = {0.f, 0.f, 0.f}, q[3] = {0.f, 0.f, 0.f};
  for (int r = blockIdx.x; r < M; r += gridDim.x) {
    const float* row = y + (size_t)r*C;
#pragma unroll
    for (int cc = 0; cc < 3; ++cc) {
      const int c = threadIdx.x + cc*256;
      if (c < C) { const float v = row[c]; a[cc] += v; q[cc] += v*v; }
    }
  }
#pragma unroll
  for (int cc = 0; cc < 3; ++cc) {
    const int c = threadIdx.x + cc*256;
    if (c < C) { atomicAdd(&sums[c], a[cc]); atomicAdd(&sumsq[c], q[cc]); }
  }
}

__global__ void bn_finalize(const float* __restrict__ sums, const float* __restrict__ sumsq,
    const float* __restrict__ g, const float* __restrict__ b, int C, float invM,
    float* __restrict__ scale, float* __restrict__ shift) {
  const int c = blockIdx.x*256 + threadIdx.x;
  if (c >= C) return;
  const float mu = sums[c]*invM;
  const float var = sumsq[c]*invM - mu*mu;
  const float istd = rsqrtf(var + 1e-5f);
  const float sc = istd * g[c];
  scale[c] = sc;
  shift[c] = b[c] - mu*sc;
}

// BN1 apply + relu; route first 25 batches to sraw, rest to xbuf[5..79]
__global__ __launch_bounds__(256) void bn1_apply(const float* __restrict__ y1,
    const float* __restrict__ scale, const float* __restrict__ shift,
    float* __restrict__ sraw, float* __restrict__ xbuf) {
  const int i4 = blockIdx.x*256 + threadIdx.x;
  if (i4 >= M1*HD/4) return;
  const int e = i4 << 2;
  const int col = e & (HD - 1);
  float4 v = ((const float4*)y1)[i4];
  v.x = fmaxf(fmaf(v.x, scale[col],   shift[col]),   0.f);
  v.y = fmaxf(fmaf(v.y, scale[col+1], shift[col+1]), 0.f);
  v.z = fmaxf(fmaf(v.z, scale[col+2], shift[col+2]), 0.f);
  v.w = fmaxf(fmaf(v.w, scale[col+3], shift[col+3]), 0.f);
  if (e < 25*SEQ*HD) ((float4*)sraw)[i4] = v;
  else ((float4*)xbuf)[i4 - (20*SEQ*HD/4)] = v;
}

// xbuf[0..4] = mean over shots of sraw
__global__ void support_mean(const float* __restrict__ sraw, float* __restrict__ xbuf) {
  const int i4 = blockIdx.x*256 + threadIdx.x;
  if (i4 >= WAYS*SEQ*HD/4) return;
  const int e = i4 << 2;
  const int w = e / (SEQ*HD);
  const int rem = e - w*(SEQ*HD);
  float4 acc = make_float4(0.f, 0.f, 0.f, 0.f);
#pragma unroll
  for (int s = 0; s < SHOTS; ++s) {
    const float4 v = *(const float4*)(sraw + (s*WAYS + w)*(SEQ*HD) + rem);
    acc.x += v.x; acc.y += v.y; acc.z += v.z; acc.w += v.w;
  }
  acc.x *= 0.2f; acc.y *= 0.2f; acc.z *= 0.2f; acc.w *= 0.2f;
  ((float4*)xbuf)[i4] = acc;
}

// attention: one block per (b, h). K tile in LDS, per-wave softmax, 4 q-rows/wave.
__global__ __launch_bounds__(256) void attn(const float* __restrict__ qb, const float* __restrict__ kb,
    const float* __restrict__ vb, float* __restrict__ ctx) {
  __shared__ float Ks[SEQ][65];
  __shared__ float att_s[16][SEQ];
  const int bh = blockIdx.x;
  const int b = bh >> 3, h = bh & 7;
  const int base = b*SEQ*HD + h*64;
  const int tid = threadIdx.x;
  for (int idx = tid; idx < SEQ*16; idx += 256) {
    const int row = idx >> 4, c4 = (idx & 15) << 2;
    const float4 kv = *(const float4*)(kb + base + row*HD + c4);
    Ks[row][c4] = kv.x; Ks[row][c4+1] = kv.y; Ks[row][c4+2] = kv.z; Ks[row][c4+3] = kv.w;
  }
  __syncthreads();
  const int wave = tid >> 6, lane = tid & 63;
  const int j3 = 192 + (lane & 3);
  for (int chunk = 0; chunk < SEQ; chunk += 16) {
    const int r0c = chunk + wave*4;
#pragma unroll
    for (int rr = 0; rr < 4; ++rr) {
      const int r = r0c + rr;
      if (r < SEQ) {
        const float qreg = qb[base + r*HD + lane];
        float s0 = 0.f, s1 = 0.f, s2 = 0.f, s3 = 0.f;
#pragma unroll 8
        for (int d = 0; d < 64; ++d) {
          const float qd = __shfl(qreg, d, 64);
          s0 = fmaf(qd, Ks[lane][d], s0);
          s1 = fmaf(qd, Ks[64 + lane][d], s1);
          s2 = fmaf(qd, Ks[128 + lane][d], s2);
          s3 = fmaf(qd, Ks[j3][d], s3);
        }
        s0 *= 0.125f; s1 *= 0.125f; s2 *= 0.125f; s3 *= 0.125f;
        const float s3m = (lane < 4) ? s3 : -1e30f;
        float mx = fmaxf(fmaxf(s0, s1), fmaxf(s2, s3m));
        mx = waveMax(mx);
        const float e0 = expf(s0 - mx), e1 = expf(s1 - mx), e2 = expf(s2 - mx);
        const float e3 = (lane < 4) ? expf(s3 - mx) : 0.f;
        const float rs = 1.f / waveSum(e0 + e1 + e2 + e3);
        const int r16 = wave*4 + rr;
        att_s[r16][lane] = e0*rs;
        att_s[r16][64 + lane] = e1*rs;
        att_s[r16][128 + lane] = e2*rs;
        if (lane < 4) att_s[r16][192 + lane] = e3*rs;
      }
    }
    if (r0c < SEQ) {
      float a0 = 0.f, a1 = 0.f, a2 = 0.f, a3 = 0.f;
      const int rb = wave*4;
#pragma unroll 4
      for (int j = 0; j < SEQ; ++j) {
        const float vj = vb[base + j*HD + lane];
        a0 = fmaf(att_s[rb][j], vj, a0);
        a1 = fmaf(att_s[rb+1][j], vj, a1);
        a2 = fmaf(att_s[rb+2][j], vj, a2);
        a3 = fmaf(att_s[rb+3][j], vj, a3);
      }
      ctx[base + r0c*HD + lane] = a0;
      if (r0c + 1 < SEQ) ctx[base + (r0c+1)*HD + lane] = a1;
      if (r0c + 2 < SEQ) ctx[base + (r0c+2)*HD + lane] = a2;
      if (r0c + 3 < SEQ) ctx[base + (r0c+3)*HD + lane] = a3;
    }
  }
}

// residual + LayerNorm per row: out = LN(tmp + x) * g + b  (one wave per row)
__global__ __launch_bounds__(256) void ln_kernel(const float* __restrict__ tmp, const float* __restrict__ xin,
    const float* __restrict__ g, const float* __restrict__ bta, float* __restrict__ out) {
  const int row = blockIdx.x*4 + (threadIdx.x >> 6);
  const int lane = threadIdx.x & 63;
  const float* t = tmp + (size_t)row*HD;
  const float* x = xin + (size_t)row*HD;
  float v[8]; float s = 0.f;
#pragma unroll
  for (int i = 0; i < 8; ++i) { const float val = t[i*64 + lane] + x[i*64 + lane]; v[i] = val; s += val; }
  s = waveSum(s);
  const float mu = s * (1.f/HD);
  float sq = 0.f;
#pragma unroll
  for (int i = 0; i < 8; ++i) { const float d = v[i] - mu; sq += d*d; }
  sq = waveSum(sq);
  const float istd = rsqrtf(sq*(1.f/HD) + 1e-5f);
#pragma unroll
  for (int i = 0; i < 8; ++i) {
    const int d = i*64 + lane;
    out[(size_t)row*HD + d] = (v[i] - mu)*istd*g[d] + bta[d];
  }
}

// m[r,p] = dot(support_flat[r], Wm[p])  (one wave per row)
__global__ __launch_bounds__(256) void mw_kernel(const float* __restrict__ xout,
    const float* __restrict__ Wm, float* __restrict__ m) {
  const int row = blockIdx.x*4 + (threadIdx.x >> 6);
  const int lane = threadIdx.x & 63;
  const float* x = xout + (size_t)row*HD;
  float xv[8];
#pragma unroll
  for (int i = 0; i < 8; ++i) xv[i] = x[i*64 + lane];
#pragma unroll
  for (int p = 0; p < PP; ++p) {
    const float* wp = Wm + p*HD;
    float s = 0.f;
#pragma unroll
    for (int i = 0; i < 8; ++i) s = fmaf(xv[i], wp[i*64 + lane], s);
    s = waveSum(s);
    if (lane == 0) m[row*PP + p] = s;
  }
}

// softmax over axis-0 (980) per p, weighted pool, l2-normalize. one block per p.
__global__ __launch_bounds__(256) void protos_kernel(const float* __restrict__ m,
    const float* __restrict__ xout, float* __restrict__ pn) {
  __shared__ float wbuf[980];
  __shared__ float red[256];
  const int p = blockIdx.x, tid = threadIdx.x;
  float lmax = -1e30f;
  for (int r = tid; r < 980; r += 256) lmax = fmaxf(lmax, m[r*PP + p]);
  red[tid] = lmax; __syncthreads();
  for (int s = 128; s; s >>= 1) { if (tid < s) red[tid] = fmaxf(red[tid], red[tid + s]); __syncthreads(); }
  const float bmax = red[0]; __syncthreads();
  float lsum = 0.f;
  for (int r = tid; r < 980; r += 256) { const float w = expf(m[r*PP + p] - bmax); wbuf[r] = w; lsum += w; }
  red[tid] = lsum; __syncthreads();
  for (int s = 128; s; s >>= 1) { if (tid < s) red[tid] += red[tid + s]; __syncthreads(); }
  const float invZ = 1.f / red[0]; __syncthreads();
  float vals[2];
#pragma unroll
  for (int ii = 0; ii < 2; ++ii) {
    const int d = tid + ii*256;
    float acc = 0.f;
    for (int r = 0; r < 980; ++r) acc = fmaf(wbuf[r], xout[(size_t)r*HD + d], acc);
    vals[ii] = acc * invZ;
  }
  red[tid] = vals[0]*vals[0] + vals[1]*vals[1]; __syncthreads();
  for (int s = 128; s; s >>= 1) { if (tid < s) red[tid] += red[tid + s]; __syncthreads(); }
  const float rn = 1.f / fmaxf(sqrtf(red[0]), 1e-12f);
  pn[p*HD + tid] = vals[0]*rn;
  pn[p*HD + tid + 256] = vals[1]*rn;
}

__global__ __launch_bounds__(256) void losses_kernel(const float* __restrict__ pn, float* __restrict__ out) {
  __shared__ float redc[256], redd[256];
  const int tid = threadIdx.x;
  float cpart = 0.f, dpart = 0.f;
  for (int d = tid; d < HD; d += 256) {
    float a[PP];
#pragma unroll
    for (int j = 0; j < PP; ++j) a[j] = pn[j*HD + d];
#pragma unroll
    for (int j = 0; j < PP; ++j) {
      if (d > j) {
#pragma unroll
        for (int i = 0; i < PP; ++i) {
          const float df = a[j] - a[i];
          const float t = 1.f - df*df;
          if (t > 0.f) dpart += t;
        }
      }
    }
#pragma unroll
    for (int j = 0; j < PP - 1; ++j) { const float df = a[j+1] - a[j]; cpart += df*df; }
  }
  redc[tid] = cpart; redd[tid] = dpart; __syncthreads();
  for (int s = 128; s; s >>= 1) {
    if (tid < s) { redc[tid] += redc[tid + s]; redd[tid] += redd[tid + s]; }
    __syncthreads();
  }
  if (tid == 0) {
    out[OUT_UPD + 1] = redc[0] / 9.f;
    out[OUT_UPD + 2] = redd[0] * (2.f / (90.f * 512.f));
  }
}

// per-qf-row: score -> softmax/argmax -> new_q (l2norm) -> fea partial (one wave per row)
__global__ __launch_bounds__(256) void rowk(const float* __restrict__ xout, const float* __restrict__ pn,
    float* __restrict__ newq, double* __restrict__ fea) {
  __shared__ float Ps[PP*HD];
  const int tid = threadIdx.x;
  for (int idx = tid; idx < PP*HD; idx += 256) Ps[idx] = pn[idx];
  __syncthreads();
  const int row = blockIdx.x*4 + (tid >> 6);
  const int lane = tid & 63;
  const float* x = xout + (size_t)(WAYS*SEQ + row)*HD;
  float xv[8];
#pragma unroll
  for (int i = 0; i < 8; ++i) xv[i] = x[i*64 + lane];
  float sc[PP];
#pragma unroll
  for (int p = 0; p < PP; ++p) {
    float s = 0.f;
#pragma unroll
    for (int i = 0; i < 8; ++i) s = fmaf(xv[i], Ps[p*HD + i*64 + lane], s);
    sc[p] = waveSum(s);
  }
  float mx = sc[0]; int am = 0;
#pragma unroll
  for (int p = 1; p < PP; ++p) if (sc[p] > mx) { mx = sc[p]; am = p; }
  float Z = 0.f; float sp[PP];
#pragma unroll
  for (int p = 0; p < PP; ++p) { const float e = expf(sc[p] - mx); sp[p] = e; Z += e; }
  const float rz = 1.f / Z;
  float nv[8]; float ss = 0.f;
#pragma unroll
  for (int i = 0; i < 8; ++i) {
    float a = 0.f;
#pragma unroll
    for (int p = 0; p < PP; ++p) a = fmaf(sp[p], Ps[p*HD + i*64 + lane], a);
    a *= rz; nv[i] = a; ss += a*a;
  }
  ss = waveSum(ss);
  const float rn = 1.f / fmaxf(sqrtf(ss), 1e-12f);
#pragma unroll
  for (int i = 0; i < 8; ++i) newq[(size_t)row*HD + i*64 + lane] = nv[i]*rn;
  float fp = 0.f;
#pragma unroll
  for (int i = 0; i < 8; ++i) { const float d = xv[i] - Ps[am*HD + i*64 + lane]; fp += d*d; }
  fp = waveSum(fp);
  if (lane == 0) atomicAdd(fea, (double)fp);
}

__global__ void fea_finalize(const double* __restrict__ fea, float* __restrict__ out) {
  out[OUT_UPD] = (float)(*fea / (double)(NQB*SEQ*HD));
}

// BN2 apply + relu + transpose [n,hw,o] -> [n,o,hw] + residual query
__global__ __launch_bounds__(256) void bn2_apply(const float* __restrict__ y2, const float* __restrict__ scale,
    const float* __restrict__ shift, const float* __restrict__ query, float* __restrict__ out) {
  __shared__ float tile[32][33];
  const int n = blockIdx.z, o0 = blockIdx.y*32, hw0 = blockIdx.x*32;
  const int tj = threadIdx.x & 31, ti = threadIdx.x >> 5;   // ti 0..7
#pragma unroll
  for (int it = 0; it < 4; ++it) {
    const int hw = hw0 + it*8 + ti;
    const int o = o0 + tj;
    float v = 0.f;
    if (hw < SEQ) v = fmaxf(fmaf(y2[((size_t)n*SEQ + hw)*FDIMC + o], scale[o], shift[o]), 0.f);
    tile[it*8 + ti][tj] = v;
  }
  __syncthreads();
#pragma unroll
  for (int it = 0; it < 4; ++it) {
    const int o = o0 + it*8 + ti;
    const int hw = hw0 + tj;
    if (hw < SEQ) {
      const size_t oi = ((size_t)n*FDIMC + o)*SEQ + hw;
      out[oi] = tile[tj][it*8 + ti] + query[oi];
    }
  }
}

extern "C" void kernel_launch(void* const* d_in, const int* in_sizes, int n_in,
                              void* d_out, int out_size, void* d_ws, size_t ws_size,
                              hipStream_t stream) {
  const float* key   = (const float*)d_in[0];
  const float* query = (const float*)d_in[1];
  const float* Wc    = (const float*)d_in[2];
  const float* bc    = (const float*)d_in[3];
  const float* g1    = (const float*)d_in[4];
  const float* b1    = (const float*)d_in[5];
  const float* Wq    = (const float*)d_in[6];
  const float* bq    = (const float*)d_in[7];
  const float* Wk    = (const float*)d_in[8];
  const float* bk    = (const float*)d_in[9];
  const float* Wv    = (const float*)d_in[10];
  const float* bv    = (const float*)d_in[11];
  const float* Wa    = (const float*)d_in[12];
  const float* ba    = (const float*)d_in[13];
  const float* ln_g  = (const float*)d_in[14];
  const float* ln_b  = (const float*)d_in[15];
  const float* Wm    = (const float*)d_in[16];
  const float* Wo    = (const float*)d_in[17];
  const float* bo    = (const float*)d_in[18];
  const float* g2    = (const float*)d_in[19];
  const float* b2    = (const float*)d_in[20];
  float* out = (float*)d_out;
  float* w = (float*)d_ws;

  float* y1   = w + OFF_R0;   // then y2
  float* xbuf = w + OFF_R1;   // then newq
  float* sraw = w + OFF_R2;
  float* qb   = w + OFF_R3;   // then tmp
  float* kb   = w + OFF_R4;   // then xout
  float* vb   = w + OFF_R5;
  float* ctx  = w + OFF_R6;
  float* y2   = y1;
  float* newq = xbuf;
  float* tmp  = qb;
  float* xout = kb;

  hipMemsetAsync(w, 0, ZERO_FLOATS*sizeof(float), stream);

  // conv1 + BN1 + relu -> sraw (support raw) / xbuf[5..79] (query feats)
  conv1_gemm<<<dim3(8, 4, NB), 256, 0, stream>>>(key, Wc, bc, y1);
  colsum<<<256, 256, 0, stream>>>(y1, M1, HD, w + OFF_CS1S, w + OFF_CS1Q);
  bn_finalize<<<2, 256, 0, stream>>>(w + OFF_CS1S, w + OFF_CS1Q, g1, b1, HD, 1.f/M1,
                                     w + OFF_ST1SC, w + OFF_ST1SH);
  bn1_apply<<<M1*HD/4/256, 256, 0, stream>>>(y1, w + OFF_ST1SC, w + OFF_ST1SH, sraw, xbuf);
  support_mean<<<WAYS*SEQ*HD/4/256, 256, 0, stream>>>(sraw, xbuf);

  // MHA over 80 batches
  gemm_nt<<<dim3(8, 245), 256, 0, stream>>>(xbuf, Wq, bq, qb, MMHA, HD, HD);
  gemm_nt<<<dim3(8, 245), 256, 0, stream>>>(xbuf, Wk, bk, kb, MMHA, HD, HD);
  gemm_nt<<<dim3(8, 245), 256, 0, stream>>>(xbuf, Wv, bv, vb, MMHA, HD, HD);
  attn<<<NMHA*8, 256, 0, stream>>>(qb, kb, vb, ctx);
  gemm_nt<<<dim3(8, 245), 256, 0, stream>>>(ctx, Wa, ba, tmp, MMHA, HD, HD);
  ln_kernel<<<MMHA/4, 256, 0, stream>>>(tmp, xbuf, ln_g, ln_b, xout);

  // prototypes + losses
  mw_kernel<<<245, 256, 0, stream>>>(xout, Wm, w + OFF_M);
  protos_kernel<<<PP, 256, 0, stream>>>(w + OFF_M, xout, w + OFF_PN);
  losses_kernel<<<1, 256, 0, stream>>>(w + OFF_PN, out);

  // per-row score/softmax/new_q/fea
  rowk<<<MQ/4, 256, 0, stream>>>(xout, w + OFF_PN, newq, (double*)(w + OFF_FEA));

  // conv2 + BN2 + relu + residual
  gemm_nt<<<dim3(10, 230), 256, 0, stream>>>(newq, Wo, bo, y2, MQ, FDIMC, HD);
  colsum<<<256, 256, 0, stream>>>(y2, MQ, FDIMC, w + OFF_CS2S, w + OFF_CS2Q);
  bn_finalize<<<3, 256, 0, stream>>>(w + OFF_CS2S, w + OFF_CS2Q, g2, b2, FDIMC, 1.f/MQ,
                                     w + OFF_ST2SC, w + OFF_ST2SH);
  fea_finalize<<<1, 1, 0, stream>>>((const double*)(w + OFF_FEA), out);
  bn2_apply<<<dim3(7, 20, NQB), 256, 0, stream>>>(y2, w + OFF_ST2SC, w + OFF_ST2SH, query, out);
}

// Round 2
// 683.178 us; speedup vs baseline: 2.5610x; 2.5610x over previous
//
#include <hip/hip_runtime.h>
#include <math.h>

// ---- problem constants ----
#define WAYS 5
#define SHOTS 5
#define PP 10
#define FDIMC 640
#define HD 512
#define SEQ 196
#define NB 100
#define NQB 75
#define NMHA 80
#define M1 (NB*SEQ)       // 19600
#define MMHA (NMHA*SEQ)   // 15680
#define MQ (NQB*SEQ)      // 14700
#define OUT_UPD (NQB*FDIMC*SEQ)  // 9,408,000

// ---- small stats block (float offsets inside region SM) ----
#define OFF_CS1S 0
#define OFF_CS1Q 512
#define OFF_CS2S 1024
#define OFF_CS2Q 1664
#define OFF_FEA  2304
#define ZERO_FLOATS 2306
#define OFF_ST1SC 2308
#define OFF_ST1SH 2820
#define OFF_ST2SC 3332
#define OFF_ST2SH 3972
#define OFF_M    4612
#define OFF_PN   14412

// ---- big regions (float offsets) ----
#define RB 20480                   /* y1 (10.0M) / P bf16 (15.44M) / y2 (9.4M) */
#define RC (RB + 15439360)         /* xbuf fp32 (8.03M) */
#define RD (RC + 8028160)          /* keyT bf16 -> qb bf16 -> tmp fp32 */
#define RE (RD + 8028160)          /* xbufh bf16 -> VT bf16 -> xout fp32 */
#define RF (RE + 8028160)          /* sraw fp32 -> kb bf16 -> newq bf16 */
#define RG (RF + 4014080)          /* vb bf16 -> ctx bf16 */
#define RH (RG + 4014080)          /* weights bf16 concat (851,968 floats) */

typedef __bf16 bf16x8 __attribute__((ext_vector_type(8)));
typedef float f32x4 __attribute__((ext_vector_type(4)));

__device__ __forceinline__ ushort f2bf(float f) {
  unsigned u = __float_as_uint(f);
  return (ushort)((u + 0x7fffu + ((u >> 16) & 1u)) >> 16);
}

__device__ __forceinline__ f32x4 mfma16(bf16x8 a, bf16x8 b, f32x4 c) {
  return __builtin_amdgcn_mfma_f32_16x16x32_bf16(a, b, c, 0, 0, 0);
}

__device__ __forceinline__ float waveSum(float v) {
#pragma unroll
  for (int o = 32; o; o >>= 1) v += __shfl_xor(v, o, 64);
  return v;
}

// ---------- transposes / converts ----------

__global__ __launch_bounds__(256) void key_transpose(const float* __restrict__ key,
                                                     ushort* __restrict__ keyT) {
  __shared__ float T[32][33];
  const int n = blockIdx.z, c0 = blockIdx.y*32, s0 = blockIdx.x*32;
  const int tj = threadIdx.x & 31, ti = threadIdx.x >> 5;
#pragma unroll
  for (int it = 0; it < 4; ++it) {
    const int cl = it*8 + ti;
    const int s = s0 + tj;
    T[cl][tj] = (s < SEQ) ? key[((size_t)n*FDIMC + c0 + cl)*SEQ + s] : 0.f;
  }
  __syncthreads();
#pragma unroll
  for (int it = 0; it < 4; ++it) {
    const int sl = it*8 + ti;
    const int s = s0 + sl;
    if (s < SEQ) keyT[((size_t)(n*SEQ + s))*FDIMC + c0 + tj] = f2bf(T[tj][sl]);
  }
}

__global__ void wconvert(const float* __restrict__ Wc, const float* __restrict__ Wq,
                         const float* __restrict__ Wk, const float* __restrict__ Wv,
                         const float* __restrict__ Wa, const float* __restrict__ Wo,
                         ushort* __restrict__ wh) {
  const int i = blockIdx.x*256 + threadIdx.x;
  float v;
  if (i < 327680) v = Wc[i];
  else if (i < 589824) v = Wq[i - 327680];
  else if (i < 851968) v = Wk[i - 589824];
  else if (i < 1114112) v = Wv[i - 851968];
  else if (i < 1376256) v = Wa[i - 1114112];
  else v = Wo[i - 1376256];
  wh[i] = f2bf(v);
}

// ---------- bf16 MFMA GEMM: C = A(MxK) . W(NxK)^T + bias ----------
// OM: 0 -> fp32 out, 1 -> bf16 out, 2 -> bf16 out scaled by 0.125
template<int OM>
__global__ __launch_bounds__(256) void gemm_bf(const ushort* __restrict__ A,
    const ushort* __restrict__ W, const float* __restrict__ bias,
    float* __restrict__ Cf, ushort* __restrict__ Ch, int M, int N, int K) {
  __shared__ ushort As[128*32];
  __shared__ ushort Bs[128*32];
  const int tid = threadIdx.x;
  const int m0 = blockIdx.y*128, n0 = blockIdx.x*128;
  const int w = tid >> 6, lane = tid & 63;
  const int wr = w >> 1, wc = w & 1;
  const int g = lane >> 4, c = lane & 15;

  // staging addresses: 2 chunks of 256 threads, each thread moves 16 B
  const int ch0 = tid, ch1 = 256 + tid;
  const int ar0 = ch0 >> 2, ar1 = ch1 >> 2;
  const int ak0 = (ch0 & 3) * 8, ak1 = (ch1 & 3) * 8;
  int gr0 = m0 + ar0; if (gr0 > M-1) gr0 = M-1;
  int gr1 = m0 + ar1; if (gr1 > M-1) gr1 = M-1;
  const ushort* Ap0 = A + (size_t)gr0*K + ak0;
  const ushort* Ap1 = A + (size_t)gr1*K + ak1;
  const ushort* Wp0 = W + (size_t)(n0 + ar0)*K + ak0;
  const ushort* Wp1 = W + (size_t)(n0 + ar1)*K + ak1;

  f32x4 acc[4][4];
#pragma unroll
  for (int i = 0; i < 4; ++i)
#pragma unroll
    for (int j = 0; j < 4; ++j) acc[i][j] = (f32x4)(0.0f);

  for (int k0 = 0; k0 < K; k0 += 32) {
    const uint4 a0 = *(const uint4*)(Ap0 + k0);
    const uint4 a1 = *(const uint4*)(Ap1 + k0);
    const uint4 b0 = *(const uint4*)(Wp0 + k0);
    const uint4 b1 = *(const uint4*)(Wp1 + k0);
    __syncthreads();
    *(uint4*)(&As[ch0*8]) = a0;
    *(uint4*)(&As[ch1*8]) = a1;
    *(uint4*)(&Bs[ch0*8]) = b0;
    *(uint4*)(&Bs[ch1*8]) = b1;
    __syncthreads();
    bf16x8 af[4], bfr[4];
#pragma unroll
    for (int mi = 0; mi < 4; ++mi)
      af[mi] = *(const bf16x8*)(&As[(wr*64 + mi*16 + c)*32 + g*8]);
#pragma unroll
    for (int ni = 0; ni < 4; ++ni)
      bfr[ni] = *(const bf16x8*)(&Bs[(wc*64 + ni*16 + c)*32 + g*8]);
#pragma unroll
    for (int mi = 0; mi < 4; ++mi)
#pragma unroll
      for (int ni = 0; ni < 4; ++ni)
        acc[mi][ni] = mfma16(af[mi], bfr[ni], acc[mi][ni]);
  }

#pragma unroll
  for (int ni = 0; ni < 4; ++ni) {
    const int col = n0 + wc*64 + ni*16 + c;
    const float bb = bias[col];
#pragma unroll
    for (int mi = 0; mi < 4; ++mi) {
#pragma unroll
      for (int q = 0; q < 4; ++q) {
        const int row = m0 + wr*64 + mi*16 + g*4 + q;
        if (row < M) {
          const float v = acc[mi][ni][q] + bb;
          if (OM == 0) Cf[(size_t)row*N + col] = v;
          else if (OM == 1) Ch[(size_t)row*N + col] = f2bf(v);
          else Ch[(size_t)row*N + col] = f2bf(v*0.125f);
        }
      }
    }
  }
}

// ---------- BN pieces ----------

__global__ __launch_bounds__(256) void colsum(const float* __restrict__ y, int M, int C,
    float* __restrict__ sums, float* __restrict__ sumsq) {
  float a[3] = {0.f,0.f,0.f}, q[3] = {0.f,0.f,0.f};
  for (int r = blockIdx.x; r < M; r += gridDim.x) {
    const float* row = y + (size_t)r*C;
#pragma unroll
    for (int cc = 0; cc < 3; ++cc) {
      const int c = threadIdx.x + cc*256;
      if (c < C) { const float v = row[c]; a[cc] += v; q[cc] += v*v; }
    }
  }
#pragma unroll
  for (int cc = 0; cc < 3; ++cc) {
    const int c = threadIdx.x + cc*256;
    if (c < C) { atomicAdd(&sums[c], a[cc]); atomicAdd(&sumsq[c], q[cc]); }
  }
}

__global__ void bn_finalize(const float* __restrict__ sums, const float* __restrict__ sumsq,
    const float* __restrict__ g, const float* __restrict__ b, int C, float invM,
    float* __restrict__ scale, float* __restrict__ shift) {
  const int c = blockIdx.x*256 + threadIdx.x;
  if (c >= C) return;
  const float mu = sums[c]*invM;
  const float var = sumsq[c]*invM - mu*mu;
  const float sc = rsqrtf(var + 1e-5f) * g[c];
  scale[c] = sc;
  shift[c] = b[c] - mu*sc;
}

__global__ __launch_bounds__(256) void bn1_apply(const float* __restrict__ y1,
    const float* __restrict__ scale, const float* __restrict__ shift,
    float* __restrict__ sraw, float* __restrict__ xbuf, ushort* __restrict__ xbufh) {
  const int i4 = blockIdx.x*256 + threadIdx.x;
  if (i4 >= M1*HD/4) return;
  const int e = i4 << 2;
  const int col = e & (HD - 1);
  float4 v = ((const float4*)y1)[i4];
  v.x = fmaxf(fmaf(v.x, scale[col],   shift[col]),   0.f);
  v.y = fmaxf(fmaf(v.y, scale[col+1], shift[col+1]), 0.f);
  v.z = fmaxf(fmaf(v.z, scale[col+2], shift[col+2]), 0.f);
  v.w = fmaxf(fmaf(v.w, scale[col+3], shift[col+3]), 0.f);
  if (e < 25*SEQ*HD) ((float4*)sraw)[i4] = v;
  else {
    const int o4 = i4 - (20*SEQ*HD/4);
    ((float4*)xbuf)[o4] = v;
    ushort4 hv = make_ushort4(f2bf(v.x), f2bf(v.y), f2bf(v.z), f2bf(v.w));
    *(ushort4*)(xbufh + (size_t)o4*4) = hv;
  }
}

__global__ void support_mean(const float* __restrict__ sraw, float* __restrict__ xbuf,
                             ushort* __restrict__ xbufh) {
  const int i4 = blockIdx.x*256 + threadIdx.x;
  if (i4 >= WAYS*SEQ*HD/4) return;
  const int e = i4 << 2;
  const int w = e / (SEQ*HD);
  const int rem = e - w*(SEQ*HD);
  float4 acc = make_float4(0.f,0.f,0.f,0.f);
#pragma unroll
  for (int s = 0; s < SHOTS; ++s) {
    const float4 v = *(const float4*)(sraw + (s*WAYS + w)*(SEQ*HD) + rem);
    acc.x += v.x; acc.y += v.y; acc.z += v.z; acc.w += v.w;
  }
  acc.x *= 0.2f; acc.y *= 0.2f; acc.z *= 0.2f; acc.w *= 0.2f;
  ((float4*)xbuf)[i4] = acc;
  ushort4 hv = make_ushort4(f2bf(acc.x), f2bf(acc.y), f2bf(acc.z), f2bf(acc.w));
  *(ushort4*)(xbufh + (size_t)i4*4) = hv;
}

// ---------- attention: QK^T + softmax -> P bf16 [bh][208][232] ----------
// qb is pre-scaled by 0.125. K staged in LDS [208][72] (2-way-free b128 frags).

__global__ __launch_bounds__(256) void attn_qk(const ushort* __restrict__ qb,
    const ushort* __restrict__ kb, ushort* __restrict__ P) {
  __shared__ ushort Ks[208*72];
  const int bh = blockIdx.x, b = bh >> 3, h = bh & 7;
  const int tid = threadIdx.x;
  for (int idx = tid; idx < 208*8; idx += 256) {
    const int row = idx >> 3, part = idx & 7;
    uint4 v = make_uint4(0u,0u,0u,0u);
    if (row < SEQ) v = *(const uint4*)(kb + ((size_t)(b*SEQ + row))*HD + h*64 + part*8);
    *(uint4*)(&Ks[row*72 + part*8]) = v;
  }
  __syncthreads();
  const int w = tid >> 6, lane = tid & 63, g = lane >> 4, c = lane & 15;
  for (int rt = w; rt < 13; rt += 4) {
    int qrow = b*SEQ + rt*16 + c; if (qrow > MMHA-1) qrow = MMHA-1;
    const bf16x8 aq0 = *(const bf16x8*)(qb + (size_t)qrow*HD + h*64 + g*8);
    const bf16x8 aq1 = *(const bf16x8*)(qb + (size_t)qrow*HD + h*64 + 32 + g*8);
    f32x4 acc[13];
#pragma unroll
    for (int ct = 0; ct < 13; ++ct) acc[ct] = (f32x4)(0.0f);
#pragma unroll
    for (int ct = 0; ct < 13; ++ct) {
      const bf16x8 b0 = *(const bf16x8*)(&Ks[(ct*16 + c)*72 + g*8]);
      const bf16x8 b1 = *(const bf16x8*)(&Ks[(ct*16 + c)*72 + 32 + g*8]);
      acc[ct] = mfma16(aq0, b0, acc[ct]);
      acc[ct] = mfma16(aq1, b1, acc[ct]);
    }
    // mask invalid cols of last tile (cols 196..207)
    if (c >= 4) acc[12] = (f32x4)(-1e30f);
    float mrow[4], Z[4];
#pragma unroll
    for (int q = 0; q < 4; ++q) {
      float mx = acc[0][q];
#pragma unroll
      for (int ct = 1; ct < 13; ++ct) mx = fmaxf(mx, acc[ct][q]);
      mrow[q] = mx;
    }
#pragma unroll
    for (int q = 0; q < 4; ++q) {
#pragma unroll
      for (int msk = 1; msk < 16; msk <<= 1)
        mrow[q] = fmaxf(mrow[q], __shfl_xor(mrow[q], msk, 64));
    }
#pragma unroll
    for (int q = 0; q < 4; ++q) Z[q] = 0.f;
#pragma unroll
    for (int ct = 0; ct < 13; ++ct)
#pragma unroll
      for (int q = 0; q < 4; ++q) {
        const float e = __expf(acc[ct][q] - mrow[q]);
        acc[ct][q] = e; Z[q] += e;
      }
#pragma unroll
    for (int q = 0; q < 4; ++q) {
#pragma unroll
      for (int msk = 1; msk < 16; msk <<= 1) Z[q] += __shfl_xor(Z[q], msk, 64);
      Z[q] = 1.f / Z[q];
    }
    const size_t pb = (size_t)bh*(208*232);
#pragma unroll
    for (int q = 0; q < 4; ++q) {
      ushort* pr = P + pb + (size_t)(rt*16 + g*4 + q)*232;
#pragma unroll
      for (int ct = 0; ct < 13; ++ct) pr[ct*16 + c] = f2bf(acc[ct][q]*Z[q]);
      pr[208 + c] = 0;
      if (c < 8) pr[224 + c] = 0;
    }
  }
}

// ---------- V transpose: vb bf16 [MMHA][512] -> VT [bh][64][224] (zero pad) ----------

__global__ __launch_bounds__(256) void v_transpose(const ushort* __restrict__ vb,
                                                   ushort* __restrict__ VT) {
  __shared__ ushort Vs[196*72];
  const int bh = blockIdx.x, b = bh >> 3, h = bh & 7;
  const int tid = threadIdx.x;
  for (int idx = tid; idx < 196*8; idx += 256) {
    const int row = idx >> 3, part = idx & 7;
    *(uint4*)(&Vs[row*72 + part*8]) =
        *(const uint4*)(vb + ((size_t)(b*SEQ + row))*HD + h*64 + part*8);
  }
  __syncthreads();
  ushort* o = VT + (size_t)bh*64*224;
  for (int idx = tid; idx < 64*224; idx += 256) {
    const int d = idx/224, s = idx - d*224;
    o[idx] = (s < SEQ) ? Vs[s*72 + d] : (ushort)0;
  }
}

// ---------- P.V : ctx bf16 [MMHA][512]; P staged in LDS, two halves ----------

__global__ __launch_bounds__(256) void attn_pv(const ushort* __restrict__ P,
    const ushort* __restrict__ VT, ushort* __restrict__ ctx) {
  __shared__ ushort Ps[112*232];
  const int bh = blockIdx.x, b = bh >> 3, h = bh & 7;
  const int tid = threadIdx.x, w = tid >> 6, lane = tid & 63, g = lane >> 4, c = lane & 15;
  bf16x8 bv[7];
  const ushort* vt = VT + (size_t)bh*64*224 + (size_t)(w*16 + c)*224;
#pragma unroll
  for (int ks = 0; ks < 7; ++ks) bv[ks] = *(const bf16x8*)(vt + ks*32 + g*8);
  const char* pg = (const char*)(P + (size_t)bh*(208*232));
#pragma unroll
  for (int half = 0; half < 2; ++half) {
    const int r0 = half ? 112 : 0;
    const int nbytes = half ? 96*464 : 112*464;
    __syncthreads();
    for (int byte = tid*16; byte < nbytes; byte += 4096)
      *(uint4*)((char*)Ps + byte) = *(const uint4*)(pg + r0*464 + byte);
    __syncthreads();
    const int rtlo = half ? 7 : 0, rthi = half ? 13 : 7;
    for (int rt = rtlo; rt < rthi; ++rt) {
      const int lrow = rt*16 - r0 + c;
      f32x4 acc = (f32x4)(0.0f);
#pragma unroll
      for (int ks = 0; ks < 7; ++ks) {
        const bf16x8 a = *(const bf16x8*)(&Ps[lrow*232 + ks*32 + g*8]);
        acc = mfma16(a, bv[ks], acc);
      }
#pragma unroll
      for (int q = 0; q < 4; ++q) {
        const int srow = rt*16 + g*4 + q;
        if (srow < SEQ)
          ctx[((size_t)(b*SEQ + srow))*HD + h*64 + w*16 + c] = f2bf(acc[q]);
      }
    }
  }
}

// ---------- LayerNorm + residual ----------

__global__ __launch_bounds__(256) void ln_kernel(const float* __restrict__ tmp,
    const float* __restrict__ xin, const float* __restrict__ g,
    const float* __restrict__ bta, float* __restrict__ out) {
  const int row = blockIdx.x*4 + (threadIdx.x >> 6);
  const int lane = threadIdx.x & 63;
  const float* t = tmp + (size_t)row*HD;
  const float* x = xin + (size_t)row*HD;
  float v[8]; float s = 0.f;
#pragma unroll
  for (int i = 0; i < 8; ++i) { const float val = t[i*64 + lane] + x[i*64 + lane]; v[i] = val; s += val; }
  s = waveSum(s);
  const float mu = s * (1.f/HD);
  float sq = 0.f;
#pragma unroll
  for (int i = 0; i < 8; ++i) { const float d = v[i] - mu; sq += d*d; }
  sq = waveSum(sq);
  const float istd = rsqrtf(sq*(1.f/HD) + 1e-5f);
#pragma unroll
  for (int i = 0; i < 8; ++i) {
    const int d = i*64 + lane;
    out[(size_t)row*HD + d] = (v[i] - mu)*istd*g[d] + bta[d];
  }
}

// ---------- prototypes / losses / per-row ----------

__global__ __launch_bounds__(256) void mw_kernel(const float* __restrict__ xout,
    const float* __restrict__ Wm, float* __restrict__ m) {
  const int row = blockIdx.x*4 + (threadIdx.x >> 6);
  const int lane = threadIdx.x & 63;
  const float* x = xout + (size_t)row*HD;
  float xv[8];
#pragma unroll
  for (int i = 0; i < 8; ++i) xv[i] = x[i*64 + lane];
#pragma unroll
  for (int p = 0; p < PP; ++p) {
    const float* wp = Wm + p*HD;
    float s = 0.f;
#pragma unroll
    for (int i = 0; i < 8; ++i) s = fmaf(xv[i], wp[i*64 + lane], s);
    s = waveSum(s);
    if (lane == 0) m[row*PP + p] = s;
  }
}

__global__ __launch_bounds__(256) void protos_kernel(const float* __restrict__ m,
    const float* __restrict__ xout, float* __restrict__ pn) {
  __shared__ float wbuf[980];
  __shared__ float red[256];
  const int p = blockIdx.x, tid = threadIdx.x;
  float lmax = -1e30f;
  for (int r = tid; r < 980; r += 256) lmax = fmaxf(lmax, m[r*PP + p]);
  red[tid] = lmax; __syncthreads();
  for (int s = 128; s; s >>= 1) { if (tid < s) red[tid] = fmaxf(red[tid], red[tid+s]); __syncthreads(); }
  const float bmax = red[0]; __syncthreads();
  float lsum = 0.f;
  for (int r = tid; r < 980; r += 256) { const float w = expf(m[r*PP + p] - bmax); wbuf[r] = w; lsum += w; }
  red[tid] = lsum; __syncthreads();
  for (int s = 128; s; s >>= 1) { if (tid < s) red[tid] += red[tid+s]; __syncthreads(); }
  const float invZ = 1.f / red[0]; __syncthreads();
  float vals[2];
#pragma unroll
  for (int ii = 0; ii < 2; ++ii) {
    const int d = tid + ii*256;
    float acc = 0.f;
    for (int r = 0; r < 980; ++r) acc = fmaf(wbuf[r], xout[(size_t)r*HD + d], acc);
    vals[ii] = acc * invZ;
  }
  red[tid] = vals[0]*vals[0] + vals[1]*vals[1]; __syncthreads();
  for (int s = 128; s; s >>= 1) { if (tid < s) red[tid] += red[tid+s]; __syncthreads(); }
  const float rn = 1.f / fmaxf(sqrtf(red[0]), 1e-12f);
  pn[p*HD + tid] = vals[0]*rn;
  pn[p*HD + tid + 256] = vals[1]*rn;
}

__global__ __launch_bounds__(256) void losses_kernel(const float* __restrict__ pn, float* __restrict__ out) {
  __shared__ float redc[256], redd[256];
  const int tid = threadIdx.x;
  float cpart = 0.f, dpart = 0.f;
  for (int d = tid; d < HD; d += 256) {
    float a[PP];
#pragma unroll
    for (int j = 0; j < PP; ++j) a[j] = pn[j*HD + d];
#pragma unroll
    for (int j = 0; j < PP; ++j) {
      if (d > j) {
#pragma unroll
        for (int i = 0; i < PP; ++i) {
          const float df = a[j] - a[i];
          const float t = 1.f - df*df;
          if (t > 0.f) dpart += t;
        }
      }
    }
#pragma unroll
    for (int j = 0; j < PP - 1; ++j) { const float df = a[j+1] - a[j]; cpart += df*df; }
  }
  redc[tid] = cpart; redd[tid] = dpart; __syncthreads();
  for (int s = 128; s; s >>= 1) {
    if (tid < s) { redc[tid] += redc[tid+s]; redd[tid] += redd[tid+s]; }
    __syncthreads();
  }
  if (tid == 0) {
    out[OUT_UPD + 1] = redc[0] / 9.f;
    out[OUT_UPD + 2] = redd[0] * (2.f / (90.f * 512.f));
  }
}

__global__ __launch_bounds__(256) void rowk(const float* __restrict__ xout, const float* __restrict__ pn,
    ushort* __restrict__ newq, double* __restrict__ fea) {
  __shared__ float Ps[PP*HD];
  const int tid = threadIdx.x;
  for (int idx = tid; idx < PP*HD; idx += 256) Ps[idx] = pn[idx];
  __syncthreads();
  const int row = blockIdx.x*4 + (tid >> 6);
  const int lane = tid & 63;
  const float* x = xout + (size_t)(WAYS*SEQ + row)*HD;
  float xv[8];
#pragma unroll
  for (int i = 0; i < 8; ++i) xv[i] = x[i*64 + lane];
  float sc[PP];
#pragma unroll
  for (int p = 0; p < PP; ++p) {
    float s = 0.f;
#pragma unroll
    for (int i = 0; i < 8; ++i) s = fmaf(xv[i], Ps[p*HD + i*64 + lane], s);
    sc[p] = waveSum(s);
  }
  float mx = sc[0]; int am = 0;
#pragma unroll
  for (int p = 1; p < PP; ++p) if (sc[p] > mx) { mx = sc[p]; am = p; }
  float Z = 0.f; float sp[PP];
#pragma unroll
  for (int p = 0; p < PP; ++p) { const float e = expf(sc[p] - mx); sp[p] = e; Z += e; }
  const float rz = 1.f / Z;
  float nv[8]; float ss = 0.f;
#pragma unroll
  for (int i = 0; i < 8; ++i) {
    float a = 0.f;
#pragma unroll
    for (int p = 0; p < PP; ++p) a = fmaf(sp[p], Ps[p*HD + i*64 + lane], a);
    a *= rz; nv[i] = a; ss += a*a;
  }
  ss = waveSum(ss);
  const float rn = 1.f / fmaxf(sqrtf(ss), 1e-12f);
#pragma unroll
  for (int i = 0; i < 8; ++i) newq[(size_t)row*HD + i*64 + lane] = f2bf(nv[i]*rn);
  float fp = 0.f;
#pragma unroll
  for (int i = 0; i < 8; ++i) { const float d = xv[i] - Ps[am*HD + i*64 + lane]; fp += d*d; }
  fp = waveSum(fp);
  if (lane == 0) atomicAdd(fea, (double)fp);
}

__global__ void fea_finalize(const double* __restrict__ fea, float* __restrict__ out) {
  out[OUT_UPD] = (float)(*fea / (double)(NQB*SEQ*HD));
}

__global__ __launch_bounds__(256) void bn2_apply(const float* __restrict__ y2, const float* __restrict__ scale,
    const float* __restrict__ shift, const float* __restrict__ query, float* __restrict__ out) {
  __shared__ float tile[32][33];
  const int n = blockIdx.z, o0 = blockIdx.y*32, hw0 = blockIdx.x*32;
  const int tj = threadIdx.x & 31, ti = threadIdx.x >> 5;
#pragma unroll
  for (int it = 0; it < 4; ++it) {
    const int hw = hw0 + it*8 + ti;
    const int o = o0 + tj;
    float v = 0.f;
    if (hw < SEQ) v = fmaxf(fmaf(y2[((size_t)n*SEQ + hw)*FDIMC + o], scale[o], shift[o]), 0.f);
    tile[it*8 + ti][tj] = v;
  }
  __syncthreads();
#pragma unroll
  for (int it = 0; it < 4; ++it) {
    const int o = o0 + it*8 + ti;
    const int hw = hw0 + tj;
    if (hw < SEQ) {
      const size_t oi = ((size_t)n*FDIMC + o)*SEQ + hw;
      out[oi] = tile[tj][it*8 + ti] + query[oi];
    }
  }
}

extern "C" void kernel_launch(void* const* d_in, const int* in_sizes, int n_in,
                              void* d_out, int out_size, void* d_ws, size_t ws_size,
                              hipStream_t stream) {
  const float* key   = (const float*)d_in[0];
  const float* query = (const float*)d_in[1];
  const float* Wc    = (const float*)d_in[2];
  const float* bc    = (const float*)d_in[3];
  const float* g1    = (const float*)d_in[4];
  const float* b1    = (const float*)d_in[5];
  const float* Wq    = (const float*)d_in[6];
  const float* bq    = (const float*)d_in[7];
  const float* Wk    = (const float*)d_in[8];
  const float* bk    = (const float*)d_in[9];
  const float* Wv    = (const float*)d_in[10];
  const float* bv    = (const float*)d_in[11];
  const float* Wa    = (const float*)d_in[12];
  const float* ba    = (const float*)d_in[13];
  const float* ln_g  = (const float*)d_in[14];
  const float* ln_b  = (const float*)d_in[15];
  const float* Wm    = (const float*)d_in[16];
  const float* Wo    = (const float*)d_in[17];
  const float* bo    = (const float*)d_in[18];
  const float* g2    = (const float*)d_in[19];
  const float* b2    = (const float*)d_in[20];
  float* out = (float*)d_out;
  float* w = (float*)d_ws;

  float*  y1    = w + RB;
  ushort* P     = (ushort*)(w + RB);
  float*  y2    = w + RB;
  float*  xbuf  = w + RC;
  ushort* keyT  = (ushort*)(w + RD);
  ushort* qb    = (ushort*)(w + RD);
  float*  tmp   = w + RD;
  ushort* xbufh = (ushort*)(w + RE);
  ushort* VT    = (ushort*)(w + RE);
  float*  xout  = w + RE;
  float*  sraw  = w + RF;
  ushort* kb    = (ushort*)(w + RF);
  ushort* newq  = (ushort*)(w + RF);
  ushort* vb    = (ushort*)(w + RG);
  ushort* ctx   = (ushort*)(w + RG);
  ushort* wh    = (ushort*)(w + RH);
  ushort* Wcb = wh;
  ushort* Wqb = wh + 327680;
  ushort* Wkb = wh + 589824;
  ushort* Wvb = wh + 851968;
  ushort* Wab = wh + 1114112;
  ushort* Wob = wh + 1376256;

  hipMemsetAsync(w, 0, ZERO_FLOATS*sizeof(float), stream);

  key_transpose<<<dim3(7, 20, NB), 256, 0, stream>>>(key, keyT);
  wconvert<<<6656, 256, 0, stream>>>(Wc, Wq, Wk, Wv, Wa, Wo, wh);

  // conv1 (bf16 MFMA) + BN1 + relu
  gemm_bf<0><<<dim3(4, 154), 256, 0, stream>>>(keyT, Wcb, bc, y1, nullptr, M1, HD, FDIMC);
  colsum<<<256, 256, 0, stream>>>(y1, M1, HD, w + OFF_CS1S, w + OFF_CS1Q);
  bn_finalize<<<2, 256, 0, stream>>>(w + OFF_CS1S, w + OFF_CS1Q, g1, b1, HD, 1.f/M1,
                                     w + OFF_ST1SC, w + OFF_ST1SH);
  bn1_apply<<<M1*HD/4/256, 256, 0, stream>>>(y1, w + OFF_ST1SC, w + OFF_ST1SH, sraw, xbuf, xbufh);
  support_mean<<<WAYS*SEQ*HD/4/256, 256, 0, stream>>>(sraw, xbuf, xbufh);

  // MHA projections (bf16 out; q pre-scaled by 1/8)
  gemm_bf<2><<<dim3(4, 123), 256, 0, stream>>>(xbufh, Wqb, bq, nullptr, qb, MMHA, HD, HD);
  gemm_bf<1><<<dim3(4, 123), 256, 0, stream>>>(xbufh, Wkb, bk, nullptr, kb, MMHA, HD, HD);
  gemm_bf<1><<<dim3(4, 123), 256, 0, stream>>>(xbufh, Wvb, bv, nullptr, vb, MMHA, HD, HD);

  v_transpose<<<NMHA*8, 256, 0, stream>>>(vb, VT);
  attn_qk<<<NMHA*8, 256, 0, stream>>>(qb, kb, P);
  attn_pv<<<NMHA*8, 256, 0, stream>>>(P, VT, ctx);

  gemm_bf<0><<<dim3(4, 123), 256, 0, stream>>>(ctx, Wab, ba, tmp, nullptr, MMHA, HD, HD);
  ln_kernel<<<MMHA/4, 256, 0, stream>>>(tmp, xbuf, ln_g, ln_b, xout);

  // prototypes + losses
  mw_kernel<<<245, 256, 0, stream>>>(xout, Wm, w + OFF_M);
  protos_kernel<<<PP, 256, 0, stream>>>(w + OFF_M, xout, w + OFF_PN);
  losses_kernel<<<1, 256, 0, stream>>>(w + OFF_PN, out);
  rowk<<<MQ/4, 256, 0, stream>>>(xout, w + OFF_PN, newq, (double*)(w + OFF_FEA));

  // conv2 (bf16 MFMA) + BN2 + relu + residual
  gemm_bf<0><<<dim3(5, 115), 256, 0, stream>>>(newq, Wob, bo, y2, nullptr, MQ, FDIMC, HD);
  colsum<<<256, 256, 0, stream>>>(y2, MQ, FDIMC, w + OFF_CS2S, w + OFF_CS2Q);
  bn_finalize<<<3, 256, 0, stream>>>(w + OFF_CS2S, w + OFF_CS2Q, g2, b2, FDIMC, 1.f/MQ,
                                     w + OFF_ST2SC, w + OFF_ST2SH);
  fea_finalize<<<1, 1, 0, stream>>>((const double*)(w + OFF_FEA), out);
  bn2_apply<<<dim3(7, 20, NQB), 256, 0, stream>>>(y2, w + OFF_ST2SC, w + OFF_ST2SH, query, out);
}

// Round 3
// 528.166 us; speedup vs baseline: 3.3127x; 1.2935x over previous
//
#include <hip/hip_runtime.h>
#include <math.h>

// ---- problem constants ----
#define WAYS 5
#define SHOTS 5
#define PP 10
#define FDIMC 640
#define HD 512
#define SEQ 196
#define NB 100
#define NQB 75
#define NMHA 80
#define M1 (NB*SEQ)       // 19600
#define MMHA (NMHA*SEQ)   // 15680
#define MQ (NQB*SEQ)      // 14700
#define NBLK_ROWK (MQ/4)  // 3675
#define OUT_UPD (NQB*FDIMC*SEQ)  // 9,408,000

// ---- small stats block (float offsets inside region SM) ----
#define OFF_CS1S 0
#define OFF_CS1Q 512
#define OFF_CS2S 1024
#define OFF_CS2Q 1664
#define ZERO_FLOATS 2306
#define OFF_ST1SC 2308
#define OFF_ST1SH 2820
#define OFF_ST2SC 3332
#define OFF_ST2SH 3972
#define OFF_M    4612
#define OFF_PN   14412

// ---- big regions (float offsets) ----
#define RB 20480                   /* y1 (10.0M) / P bf16 (15.44M) / y2 (9.4M) */
#define RC (RB + 15439360)         /* xbuf fp32 (8.03M) */
#define RD (RC + 8028160)          /* keyT bf16 -> qb bf16 -> tmp fp32 */
#define RE (RD + 8028160)          /* xbufh bf16 -> VT bf16 -> xout fp32 */
#define RF (RE + 8028160)          /* sraw fp32 -> kb bf16 -> newq bf16 + feapart */
#define RG (RF + 4014080)          /* vb bf16 -> ctx bf16 */
#define RH (RG + 4014080)          /* weights bf16 concat (851,968 floats) */
#define OFF_FEAP (RF + 3763200)    /* 3675 floats, after newq within RF */

typedef __bf16 bf16x8 __attribute__((ext_vector_type(8)));
typedef float f32x4 __attribute__((ext_vector_type(4)));

__device__ __forceinline__ ushort f2bf(float f) {
  unsigned u = __float_as_uint(f);
  return (ushort)((u + 0x7fffu + ((u >> 16) & 1u)) >> 16);
}

__device__ __forceinline__ f32x4 mfma16(bf16x8 a, bf16x8 b, f32x4 c) {
  return __builtin_amdgcn_mfma_f32_16x16x32_bf16(a, b, c, 0, 0, 0);
}

__device__ __forceinline__ float waveSum(float v) {
#pragma unroll
  for (int o = 32; o; o >>= 1) v += __shfl_xor(v, o, 64);
  return v;
}

// ---------- transposes / converts ----------

__global__ __launch_bounds__(256) void key_transpose(const float* __restrict__ key,
                                                     ushort* __restrict__ keyT) {
  __shared__ float T[32][33];
  const int n = blockIdx.z, c0 = blockIdx.y*32, s0 = blockIdx.x*32;
  const int tj = threadIdx.x & 31, ti = threadIdx.x >> 5;
#pragma unroll
  for (int it = 0; it < 4; ++it) {
    const int cl = it*8 + ti;
    const int s = s0 + tj;
    T[cl][tj] = (s < SEQ) ? key[((size_t)n*FDIMC + c0 + cl)*SEQ + s] : 0.f;
  }
  __syncthreads();
#pragma unroll
  for (int it = 0; it < 4; ++it) {
    const int sl = it*8 + ti;
    const int s = s0 + sl;
    if (s < SEQ) keyT[((size_t)(n*SEQ + s))*FDIMC + c0 + tj] = f2bf(T[tj][sl]);
  }
}

__global__ void wconvert(const float* __restrict__ Wc, const float* __restrict__ Wq,
                         const float* __restrict__ Wk, const float* __restrict__ Wv,
                         const float* __restrict__ Wa, const float* __restrict__ Wo,
                         ushort* __restrict__ wh) {
  const int i = blockIdx.x*256 + threadIdx.x;
  float v;
  if (i < 327680) v = Wc[i];
  else if (i < 589824) v = Wq[i - 327680];
  else if (i < 851968) v = Wk[i - 589824];
  else if (i < 1114112) v = Wv[i - 851968];
  else if (i < 1376256) v = Wa[i - 1114112];
  else v = Wo[i - 1376256];
  wh[i] = f2bf(v);
}

// ---------- bf16 MFMA GEMM: C = A(MxK) . W(NxK)^T + bias ----------
// OM: 0 -> fp32 out, 1 -> bf16 out, 2 -> bf16 out scaled by 0.125
template<int OM>
__global__ __launch_bounds__(256) void gemm_bf(const ushort* __restrict__ A,
    const ushort* __restrict__ W, const float* __restrict__ bias,
    float* __restrict__ Cf, ushort* __restrict__ Ch, int M, int N, int K) {
  __shared__ ushort As[128*32];
  __shared__ ushort Bs[128*32];
  const int tid = threadIdx.x;
  const int m0 = blockIdx.y*128, n0 = blockIdx.x*128;
  const int w = tid >> 6, lane = tid & 63;
  const int wr = w >> 1, wc = w & 1;
  const int g = lane >> 4, c = lane & 15;

  const int ch0 = tid, ch1 = 256 + tid;
  const int ar0 = ch0 >> 2, ar1 = ch1 >> 2;
  const int ak0 = (ch0 & 3) * 8, ak1 = (ch1 & 3) * 8;
  int gr0 = m0 + ar0; if (gr0 > M-1) gr0 = M-1;
  int gr1 = m0 + ar1; if (gr1 > M-1) gr1 = M-1;
  const ushort* Ap0 = A + (size_t)gr0*K + ak0;
  const ushort* Ap1 = A + (size_t)gr1*K + ak1;
  const ushort* Wp0 = W + (size_t)(n0 + ar0)*K + ak0;
  const ushort* Wp1 = W + (size_t)(n0 + ar1)*K + ak1;

  f32x4 acc[4][4];
#pragma unroll
  for (int i = 0; i < 4; ++i)
#pragma unroll
    for (int j = 0; j < 4; ++j) acc[i][j] = (f32x4)(0.0f);

  for (int k0 = 0; k0 < K; k0 += 32) {
    const uint4 a0 = *(const uint4*)(Ap0 + k0);
    const uint4 a1 = *(const uint4*)(Ap1 + k0);
    const uint4 b0 = *(const uint4*)(Wp0 + k0);
    const uint4 b1 = *(const uint4*)(Wp1 + k0);
    __syncthreads();
    *(uint4*)(&As[ch0*8]) = a0;
    *(uint4*)(&As[ch1*8]) = a1;
    *(uint4*)(&Bs[ch0*8]) = b0;
    *(uint4*)(&Bs[ch1*8]) = b1;
    __syncthreads();
    bf16x8 af[4], bfr[4];
#pragma unroll
    for (int mi = 0; mi < 4; ++mi)
      af[mi] = *(const bf16x8*)(&As[(wr*64 + mi*16 + c)*32 + g*8]);
#pragma unroll
    for (int ni = 0; ni < 4; ++ni)
      bfr[ni] = *(const bf16x8*)(&Bs[(wc*64 + ni*16 + c)*32 + g*8]);
#pragma unroll
    for (int mi = 0; mi < 4; ++mi)
#pragma unroll
      for (int ni = 0; ni < 4; ++ni)
        acc[mi][ni] = mfma16(af[mi], bfr[ni], acc[mi][ni]);
  }

#pragma unroll
  for (int ni = 0; ni < 4; ++ni) {
    const int col = n0 + wc*64 + ni*16 + c;
    const float bb = bias[col];
#pragma unroll
    for (int mi = 0; mi < 4; ++mi) {
#pragma unroll
      for (int q = 0; q < 4; ++q) {
        const int row = m0 + wr*64 + mi*16 + g*4 + q;
        if (row < M) {
          const float v = acc[mi][ni][q] + bb;
          if (OM == 0) Cf[(size_t)row*N + col] = v;
          else if (OM == 1) Ch[(size_t)row*N + col] = f2bf(v);
          else Ch[(size_t)row*N + col] = f2bf(v*0.125f);
        }
      }
    }
  }
}

// ---------- BN pieces ----------

__global__ __launch_bounds__(256) void colsum(const float* __restrict__ y, int M, int C,
    float* __restrict__ sums, float* __restrict__ sumsq) {
  float a[3] = {0.f,0.f,0.f}, q[3] = {0.f,0.f,0.f};
  for (int r = blockIdx.x; r < M; r += gridDim.x) {
    const float* row = y + (size_t)r*C;
#pragma unroll
    for (int cc = 0; cc < 3; ++cc) {
      const int c = threadIdx.x + cc*256;
      if (c < C) { const float v = row[c]; a[cc] += v; q[cc] += v*v; }
    }
  }
#pragma unroll
  for (int cc = 0; cc < 3; ++cc) {
    const int c = threadIdx.x + cc*256;
    if (c < C) { atomicAdd(&sums[c], a[cc]); atomicAdd(&sumsq[c], q[cc]); }
  }
}

__global__ void bn_finalize(const float* __restrict__ sums, const float* __restrict__ sumsq,
    const float* __restrict__ g, const float* __restrict__ b, int C, float invM,
    float* __restrict__ scale, float* __restrict__ shift) {
  const int c = blockIdx.x*256 + threadIdx.x;
  if (c >= C) return;
  const float mu = sums[c]*invM;
  const float var = sumsq[c]*invM - mu*mu;
  const float sc = rsqrtf(var + 1e-5f) * g[c];
  scale[c] = sc;
  shift[c] = b[c] - mu*sc;
}

__global__ __launch_bounds__(256) void bn1_apply(const float* __restrict__ y1,
    const float* __restrict__ scale, const float* __restrict__ shift,
    float* __restrict__ sraw, float* __restrict__ xbuf, ushort* __restrict__ xbufh) {
  const int i4 = blockIdx.x*256 + threadIdx.x;
  if (i4 >= M1*HD/4) return;
  const int e = i4 << 2;
  const int col = e & (HD - 1);
  float4 v = ((const float4*)y1)[i4];
  v.x = fmaxf(fmaf(v.x, scale[col],   shift[col]),   0.f);
  v.y = fmaxf(fmaf(v.y, scale[col+1], shift[col+1]), 0.f);
  v.z = fmaxf(fmaf(v.z, scale[col+2], shift[col+2]), 0.f);
  v.w = fmaxf(fmaf(v.w, scale[col+3], shift[col+3]), 0.f);
  if (e < 25*SEQ*HD) ((float4*)sraw)[i4] = v;
  else {
    const int o4 = i4 - (20*SEQ*HD/4);
    ((float4*)xbuf)[o4] = v;
    ushort4 hv = make_ushort4(f2bf(v.x), f2bf(v.y), f2bf(v.z), f2bf(v.w));
    *(ushort4*)(xbufh + (size_t)o4*4) = hv;
  }
}

__global__ void support_mean(const float* __restrict__ sraw, float* __restrict__ xbuf,
                             ushort* __restrict__ xbufh) {
  const int i4 = blockIdx.x*256 + threadIdx.x;
  if (i4 >= WAYS*SEQ*HD/4) return;
  const int e = i4 << 2;
  const int w = e / (SEQ*HD);
  const int rem = e - w*(SEQ*HD);
  float4 acc = make_float4(0.f,0.f,0.f,0.f);
#pragma unroll
  for (int s = 0; s < SHOTS; ++s) {
    const float4 v = *(const float4*)(sraw + (s*WAYS + w)*(SEQ*HD) + rem);
    acc.x += v.x; acc.y += v.y; acc.z += v.z; acc.w += v.w;
  }
  acc.x *= 0.2f; acc.y *= 0.2f; acc.z *= 0.2f; acc.w *= 0.2f;
  ((float4*)xbuf)[i4] = acc;
  ushort4 hv = make_ushort4(f2bf(acc.x), f2bf(acc.y), f2bf(acc.z), f2bf(acc.w));
  *(ushort4*)(xbufh + (size_t)i4*4) = hv;
}

// ---------- attention: QK^T + softmax -> P bf16 [bh][208][232] ----------

__global__ __launch_bounds__(256) void attn_qk(const ushort* __restrict__ qb,
    const ushort* __restrict__ kb, ushort* __restrict__ P) {
  __shared__ ushort Ks[208*72];
  const int bh = blockIdx.x, b = bh >> 3, h = bh & 7;
  const int tid = threadIdx.x;
  for (int idx = tid; idx < 208*8; idx += 256) {
    const int row = idx >> 3, part = idx & 7;
    uint4 v = make_uint4(0u,0u,0u,0u);
    if (row < SEQ) v = *(const uint4*)(kb + ((size_t)(b*SEQ + row))*HD + h*64 + part*8);
    *(uint4*)(&Ks[row*72 + part*8]) = v;
  }
  __syncthreads();
  const int w = tid >> 6, lane = tid & 63, g = lane >> 4, c = lane & 15;
  for (int rt = w; rt < 13; rt += 4) {
    int qrow = b*SEQ + rt*16 + c; if (qrow > MMHA-1) qrow = MMHA-1;
    const bf16x8 aq0 = *(const bf16x8*)(qb + (size_t)qrow*HD + h*64 + g*8);
    const bf16x8 aq1 = *(const bf16x8*)(qb + (size_t)qrow*HD + h*64 + 32 + g*8);
    f32x4 acc[13];
#pragma unroll
    for (int ct = 0; ct < 13; ++ct) acc[ct] = (f32x4)(0.0f);
#pragma unroll
    for (int ct = 0; ct < 13; ++ct) {
      const bf16x8 b0 = *(const bf16x8*)(&Ks[(ct*16 + c)*72 + g*8]);
      const bf16x8 b1 = *(const bf16x8*)(&Ks[(ct*16 + c)*72 + 32 + g*8]);
      acc[ct] = mfma16(aq0, b0, acc[ct]);
      acc[ct] = mfma16(aq1, b1, acc[ct]);
    }
    if (c >= 4) acc[12] = (f32x4)(-1e30f);
    float mrow[4], Z[4];
#pragma unroll
    for (int q = 0; q < 4; ++q) {
      float mx = acc[0][q];
#pragma unroll
      for (int ct = 1; ct < 13; ++ct) mx = fmaxf(mx, acc[ct][q]);
      mrow[q] = mx;
    }
#pragma unroll
    for (int q = 0; q < 4; ++q) {
#pragma unroll
      for (int msk = 1; msk < 16; msk <<= 1)
        mrow[q] = fmaxf(mrow[q], __shfl_xor(mrow[q], msk, 64));
    }
#pragma unroll
    for (int q = 0; q < 4; ++q) Z[q] = 0.f;
#pragma unroll
    for (int ct = 0; ct < 13; ++ct)
#pragma unroll
      for (int q = 0; q < 4; ++q) {
        const float e = __expf(acc[ct][q] - mrow[q]);
        acc[ct][q] = e; Z[q] += e;
      }
#pragma unroll
    for (int q = 0; q < 4; ++q) {
#pragma unroll
      for (int msk = 1; msk < 16; msk <<= 1) Z[q] += __shfl_xor(Z[q], msk, 64);
      Z[q] = 1.f / Z[q];
    }
    const size_t pb = (size_t)bh*(208*232);
#pragma unroll
    for (int q = 0; q < 4; ++q) {
      ushort* pr = P + pb + (size_t)(rt*16 + g*4 + q)*232;
#pragma unroll
      for (int ct = 0; ct < 13; ++ct) pr[ct*16 + c] = f2bf(acc[ct][q]*Z[q]);
      pr[208 + c] = 0;
      if (c < 8) pr[224 + c] = 0;
    }
  }
}

// ---------- V transpose ----------

__global__ __launch_bounds__(256) void v_transpose(const ushort* __restrict__ vb,
                                                   ushort* __restrict__ VT) {
  __shared__ ushort Vs[196*72];
  const int bh = blockIdx.x, b = bh >> 3, h = bh & 7;
  const int tid = threadIdx.x;
  for (int idx = tid; idx < 196*8; idx += 256) {
    const int row = idx >> 3, part = idx & 7;
    *(uint4*)(&Vs[row*72 + part*8]) =
        *(const uint4*)(vb + ((size_t)(b*SEQ + row))*HD + h*64 + part*8);
  }
  __syncthreads();
  ushort* o = VT + (size_t)bh*64*224;
  for (int idx = tid; idx < 64*224; idx += 256) {
    const int d = idx/224, s = idx - d*224;
    o[idx] = (s < SEQ) ? Vs[s*72 + d] : (ushort)0;
  }
}

// ---------- P.V ----------

__global__ __launch_bounds__(256) void attn_pv(const ushort* __restrict__ P,
    const ushort* __restrict__ VT, ushort* __restrict__ ctx) {
  __shared__ ushort Ps[112*232];
  const int bh = blockIdx.x, b = bh >> 3, h = bh & 7;
  const int tid = threadIdx.x, w = tid >> 6, lane = tid & 63, g = lane >> 4, c = lane & 15;
  bf16x8 bv[7];
  const ushort* vt = VT + (size_t)bh*64*224 + (size_t)(w*16 + c)*224;
#pragma unroll
  for (int ks = 0; ks < 7; ++ks) bv[ks] = *(const bf16x8*)(vt + ks*32 + g*8);
  const char* pg = (const char*)(P + (size_t)bh*(208*232));
#pragma unroll
  for (int half = 0; half < 2; ++half) {
    const int r0 = half ? 112 : 0;
    const int nbytes = half ? 96*464 : 112*464;
    __syncthreads();
    for (int byte = tid*16; byte < nbytes; byte += 4096)
      *(uint4*)((char*)Ps + byte) = *(const uint4*)(pg + r0*464 + byte);
    __syncthreads();
    const int rtlo = half ? 7 : 0, rthi = half ? 13 : 7;
    for (int rt = rtlo; rt < rthi; ++rt) {
      const int lrow = rt*16 - r0 + c;
      f32x4 acc = (f32x4)(0.0f);
#pragma unroll
      for (int ks = 0; ks < 7; ++ks) {
        const bf16x8 a = *(const bf16x8*)(&Ps[lrow*232 + ks*32 + g*8]);
        acc = mfma16(a, bv[ks], acc);
      }
#pragma unroll
      for (int q = 0; q < 4; ++q) {
        const int srow = rt*16 + g*4 + q;
        if (srow < SEQ)
          ctx[((size_t)(b*SEQ + srow))*HD + h*64 + w*16 + c] = f2bf(acc[q]);
      }
    }
  }
}

// ---------- LayerNorm + residual ----------

__global__ __launch_bounds__(256) void ln_kernel(const float* __restrict__ tmp,
    const float* __restrict__ xin, const float* __restrict__ g,
    const float* __restrict__ bta, float* __restrict__ out) {
  const int row = blockIdx.x*4 + (threadIdx.x >> 6);
  const int lane = threadIdx.x & 63;
  const float* t = tmp + (size_t)row*HD;
  const float* x = xin + (size_t)row*HD;
  float v[8]; float s = 0.f;
#pragma unroll
  for (int i = 0; i < 8; ++i) { const float val = t[i*64 + lane] + x[i*64 + lane]; v[i] = val; s += val; }
  s = waveSum(s);
  const float mu = s * (1.f/HD);
  float sq = 0.f;
#pragma unroll
  for (int i = 0; i < 8; ++i) { const float d = v[i] - mu; sq += d*d; }
  sq = waveSum(sq);
  const float istd = rsqrtf(sq*(1.f/HD) + 1e-5f);
#pragma unroll
  for (int i = 0; i < 8; ++i) {
    const int d = i*64 + lane;
    out[(size_t)row*HD + d] = (v[i] - mu)*istd*g[d] + bta[d];
  }
}

// ---------- prototypes / losses / per-row ----------

__global__ __launch_bounds__(256) void mw_kernel(const float* __restrict__ xout,
    const float* __restrict__ Wm, float* __restrict__ m) {
  const int row = blockIdx.x*4 + (threadIdx.x >> 6);
  const int lane = threadIdx.x & 63;
  const float* x = xout + (size_t)row*HD;
  float xv[8];
#pragma unroll
  for (int i = 0; i < 8; ++i) xv[i] = x[i*64 + lane];
#pragma unroll
  for (int p = 0; p < PP; ++p) {
    const float* wp = Wm + p*HD;
    float s = 0.f;
#pragma unroll
    for (int i = 0; i < 8; ++i) s = fmaf(xv[i], wp[i*64 + lane], s);
    s = waveSum(s);
    if (lane == 0) m[row*PP + p] = s;
  }
}

__global__ __launch_bounds__(256) void protos_kernel(const float* __restrict__ m,
    const float* __restrict__ xout, float* __restrict__ pn) {
  __shared__ float wbuf[980];
  __shared__ float red[256];
  const int p = blockIdx.x, tid = threadIdx.x;
  float lmax = -1e30f;
  for (int r = tid; r < 980; r += 256) lmax = fmaxf(lmax, m[r*PP + p]);
  red[tid] = lmax; __syncthreads();
  for (int s = 128; s; s >>= 1) { if (tid < s) red[tid] = fmaxf(red[tid], red[tid+s]); __syncthreads(); }
  const float bmax = red[0]; __syncthreads();
  float lsum = 0.f;
  for (int r = tid; r < 980; r += 256) { const float w = expf(m[r*PP + p] - bmax); wbuf[r] = w; lsum += w; }
  red[tid] = lsum; __syncthreads();
  for (int s = 128; s; s >>= 1) { if (tid < s) red[tid] += red[tid+s]; __syncthreads(); }
  const float invZ = 1.f / red[0]; __syncthreads();
  float vals[2];
#pragma unroll
  for (int ii = 0; ii < 2; ++ii) {
    const int d = tid + ii*256;
    float acc = 0.f;
    for (int r = 0; r < 980; ++r) acc = fmaf(wbuf[r], xout[(size_t)r*HD + d], acc);
    vals[ii] = acc * invZ;
  }
  red[tid] = vals[0]*vals[0] + vals[1]*vals[1]; __syncthreads();
  for (int s = 128; s; s >>= 1) { if (tid < s) red[tid] += red[tid+s]; __syncthreads(); }
  const float rn = 1.f / fmaxf(sqrtf(red[0]), 1e-12f);
  pn[p*HD + tid] = vals[0]*rn;
  pn[p*HD + tid + 256] = vals[1]*rn;
}

__global__ __launch_bounds__(256) void losses_kernel(const float* __restrict__ pn, float* __restrict__ out) {
  __shared__ float redc[256], redd[256];
  const int tid = threadIdx.x;
  float cpart = 0.f, dpart = 0.f;
  for (int d = tid; d < HD; d += 256) {
    float a[PP];
#pragma unroll
    for (int j = 0; j < PP; ++j) a[j] = pn[j*HD + d];
#pragma unroll
    for (int j = 0; j < PP; ++j) {
      if (d > j) {
#pragma unroll
        for (int i = 0; i < PP; ++i) {
          const float df = a[j] - a[i];
          const float t = 1.f - df*df;
          if (t > 0.f) dpart += t;
        }
      }
    }
#pragma unroll
    for (int j = 0; j < PP - 1; ++j) { const float df = a[j+1] - a[j]; cpart += df*df; }
  }
  redc[tid] = cpart; redd[tid] = dpart; __syncthreads();
  for (int s = 128; s; s >>= 1) {
    if (tid < s) { redc[tid] += redc[tid+s]; redd[tid] += redd[tid+s]; }
    __syncthreads();
  }
  if (tid == 0) {
    out[OUT_UPD + 1] = redc[0] / 9.f;
    out[OUT_UPD + 2] = redd[0] * (2.f / (90.f * 512.f));
  }
}

// per-row score/softmax/new_q; fea via per-block partials (NO same-address atomics)
__global__ __launch_bounds__(256) void rowk(const float* __restrict__ xout, const float* __restrict__ pn,
    ushort* __restrict__ newq, float* __restrict__ feapart) {
  __shared__ float Ps[PP*HD];
  __shared__ float fred[4];
  const int tid = threadIdx.x;
  for (int idx = tid; idx < PP*HD; idx += 256) Ps[idx] = pn[idx];
  __syncthreads();
  const int row = blockIdx.x*4 + (tid >> 6);
  const int lane = tid & 63;
  const float* x = xout + (size_t)(WAYS*SEQ + row)*HD;
  float xv[8];
#pragma unroll
  for (int i = 0; i < 8; ++i) xv[i] = x[i*64 + lane];
  float sc[PP];
#pragma unroll
  for (int p = 0; p < PP; ++p) {
    float s = 0.f;
#pragma unroll
    for (int i = 0; i < 8; ++i) s = fmaf(xv[i], Ps[p*HD + i*64 + lane], s);
    sc[p] = waveSum(s);
  }
  float mx = sc[0]; int am = 0;
#pragma unroll
  for (int p = 1; p < PP; ++p) if (sc[p] > mx) { mx = sc[p]; am = p; }
  float Z = 0.f; float sp[PP];
#pragma unroll
  for (int p = 0; p < PP; ++p) { const float e = expf(sc[p] - mx); sp[p] = e; Z += e; }
  const float rz = 1.f / Z;
  float nv[8]; float ss = 0.f;
#pragma unroll
  for (int i = 0; i < 8; ++i) {
    float a = 0.f;
#pragma unroll
    for (int p = 0; p < PP; ++p) a = fmaf(sp[p], Ps[p*HD + i*64 + lane], a);
    a *= rz; nv[i] = a; ss += a*a;
  }
  ss = waveSum(ss);
  const float rn = 1.f / fmaxf(sqrtf(ss), 1e-12f);
#pragma unroll
  for (int i = 0; i < 8; ++i) newq[(size_t)row*HD + i*64 + lane] = f2bf(nv[i]*rn);
  float fp = 0.f;
#pragma unroll
  for (int i = 0; i < 8; ++i) { const float d = xv[i] - Ps[am*HD + i*64 + lane]; fp += d*d; }
  fp = waveSum(fp);
  if (lane == 0) fred[tid >> 6] = fp;
  __syncthreads();
  if (tid == 0) feapart[blockIdx.x] = fred[0] + fred[1] + fred[2] + fred[3];
}

__global__ __launch_bounds__(256) void fea_finalize(const float* __restrict__ feapart,
                                                    float* __restrict__ out) {
  __shared__ float red[256];
  float s = 0.f;
  for (int i = threadIdx.x; i < NBLK_ROWK; i += 256) s += feapart[i];
  red[threadIdx.x] = s; __syncthreads();
  for (int st = 128; st; st >>= 1) {
    if (threadIdx.x < st) red[threadIdx.x] += red[threadIdx.x + st];
    __syncthreads();
  }
  if (threadIdx.x == 0) out[OUT_UPD] = red[0] / (float)((size_t)NQB*SEQ*HD);
}

__global__ __launch_bounds__(256) void bn2_apply(const float* __restrict__ y2, const float* __restrict__ scale,
    const float* __restrict__ shift, const float* __restrict__ query, float* __restrict__ out) {
  __shared__ float tile[32][33];
  const int n = blockIdx.z, o0 = blockIdx.y*32, hw0 = blockIdx.x*32;
  const int tj = threadIdx.x & 31, ti = threadIdx.x >> 5;
#pragma unroll
  for (int it = 0; it < 4; ++it) {
    const int hw = hw0 + it*8 + ti;
    const int o = o0 + tj;
    float v = 0.f;
    if (hw < SEQ) v = fmaxf(fmaf(y2[((size_t)n*SEQ + hw)*FDIMC + o], scale[o], shift[o]), 0.f);
    tile[it*8 + ti][tj] = v;
  }
  __syncthreads();
#pragma unroll
  for (int it = 0; it < 4; ++it) {
    const int o = o0 + it*8 + ti;
    const int hw = hw0 + tj;
    if (hw < SEQ) {
      const size_t oi = ((size_t)n*FDIMC + o)*SEQ + hw;
      out[oi] = tile[tj][it*8 + ti] + query[oi];
    }
  }
}

extern "C" void kernel_launch(void* const* d_in, const int* in_sizes, int n_in,
                              void* d_out, int out_size, void* d_ws, size_t ws_size,
                              hipStream_t stream) {
  const float* key   = (const float*)d_in[0];
  const float* query = (const float*)d_in[1];
  const float* Wc    = (const float*)d_in[2];
  const float* bc    = (const float*)d_in[3];
  const float* g1    = (const float*)d_in[4];
  const float* b1    = (const float*)d_in[5];
  const float* Wq    = (const float*)d_in[6];
  const float* bq    = (const float*)d_in[7];
  const float* Wk    = (const float*)d_in[8];
  const float* bk    = (const float*)d_in[9];
  const float* Wv    = (const float*)d_in[10];
  const float* bv    = (const float*)d_in[11];
  const float* Wa    = (const float*)d_in[12];
  const float* ba    = (const float*)d_in[13];
  const float* ln_g  = (const float*)d_in[14];
  const float* ln_b  = (const float*)d_in[15];
  const float* Wm    = (const float*)d_in[16];
  const float* Wo    = (const float*)d_in[17];
  const float* bo    = (const float*)d_in[18];
  const float* g2    = (const float*)d_in[19];
  const float* b2    = (const float*)d_in[20];
  float* out = (float*)d_out;
  float* w = (float*)d_ws;

  float*  y1    = w + RB;
  ushort* P     = (ushort*)(w + RB);
  float*  y2    = w + RB;
  float*  xbuf  = w + RC;
  ushort* keyT  = (ushort*)(w + RD);
  ushort* qb    = (ushort*)(w + RD);
  float*  tmp   = w + RD;
  ushort* xbufh = (ushort*)(w + RE);
  ushort* VT    = (ushort*)(w + RE);
  float*  xout  = w + RE;
  float*  sraw  = w + RF;
  ushort* kb    = (ushort*)(w + RF);
  ushort* newq  = (ushort*)(w + RF);
  ushort* vb    = (ushort*)(w + RG);
  ushort* ctx   = (ushort*)(w + RG);
  ushort* wh    = (ushort*)(w + RH);
  float*  feapart = w + OFF_FEAP;
  ushort* Wcb = wh;
  ushort* Wqb = wh + 327680;
  ushort* Wkb = wh + 589824;
  ushort* Wvb = wh + 851968;
  ushort* Wab = wh + 1114112;
  ushort* Wob = wh + 1376256;

  hipMemsetAsync(w, 0, ZERO_FLOATS*sizeof(float), stream);

  key_transpose<<<dim3(7, 20, NB), 256, 0, stream>>>(key, keyT);
  wconvert<<<6656, 256, 0, stream>>>(Wc, Wq, Wk, Wv, Wa, Wo, wh);

  // conv1 (bf16 MFMA) + BN1 + relu
  gemm_bf<0><<<dim3(4, 154), 256, 0, stream>>>(keyT, Wcb, bc, y1, nullptr, M1, HD, FDIMC);
  colsum<<<256, 256, 0, stream>>>(y1, M1, HD, w + OFF_CS1S, w + OFF_CS1Q);
  bn_finalize<<<2, 256, 0, stream>>>(w + OFF_CS1S, w + OFF_CS1Q, g1, b1, HD, 1.f/M1,
                                     w + OFF_ST1SC, w + OFF_ST1SH);
  bn1_apply<<<M1*HD/4/256, 256, 0, stream>>>(y1, w + OFF_ST1SC, w + OFF_ST1SH, sraw, xbuf, xbufh);
  support_mean<<<WAYS*SEQ*HD/4/256, 256, 0, stream>>>(sraw, xbuf, xbufh);

  // MHA projections (bf16 out; q pre-scaled by 1/8)
  gemm_bf<2><<<dim3(4, 123), 256, 0, stream>>>(xbufh, Wqb, bq, nullptr, qb, MMHA, HD, HD);
  gemm_bf<1><<<dim3(4, 123), 256, 0, stream>>>(xbufh, Wkb, bk, nullptr, kb, MMHA, HD, HD);
  gemm_bf<1><<<dim3(4, 123), 256, 0, stream>>>(xbufh, Wvb, bv, nullptr, vb, MMHA, HD, HD);

  v_transpose<<<NMHA*8, 256, 0, stream>>>(vb, VT);
  attn_qk<<<NMHA*8, 256, 0, stream>>>(qb, kb, P);
  attn_pv<<<NMHA*8, 256, 0, stream>>>(P, VT, ctx);

  gemm_bf<0><<<dim3(4, 123), 256, 0, stream>>>(ctx, Wab, ba, tmp, nullptr, MMHA, HD, HD);
  ln_kernel<<<MMHA/4, 256, 0, stream>>>(tmp, xbuf, ln_g, ln_b, xout);

  // prototypes + losses
  mw_kernel<<<245, 256, 0, stream>>>(xout, Wm, w + OFF_M);
  protos_kernel<<<PP, 256, 0, stream>>>(w + OFF_M, xout, w + OFF_PN);
  losses_kernel<<<1, 256, 0, stream>>>(w + OFF_PN, out);
  rowk<<<NBLK_ROWK, 256, 0, stream>>>(xout, w + OFF_PN, newq, feapart);

  // conv2 (bf16 MFMA) + BN2 + relu + residual
  gemm_bf<0><<<dim3(5, 115), 256, 0, stream>>>(newq, Wob, bo, y2, nullptr, MQ, FDIMC, HD);
  colsum<<<256, 256, 0, stream>>>(y2, MQ, FDIMC, w + OFF_CS2S, w + OFF_CS2Q);
  bn_finalize<<<3, 256, 0, stream>>>(w + OFF_CS2S, w + OFF_CS2Q, g2, b2, FDIMC, 1.f/MQ,
                                     w + OFF_ST2SC, w + OFF_ST2SH);
  fea_finalize<<<1, 256, 0, stream>>>(feapart, out);
  bn2_apply<<<dim3(7, 20, NQB), 256, 0, stream>>>(y2, w + OFF_ST2SC, w + OFF_ST2SH, query, out);
}

// Round 4
// 479.203 us; speedup vs baseline: 3.6512x; 1.1022x over previous
//
#include <hip/hip_runtime.h>
#include <math.h>

// ---- problem constants ----
#define WAYS 5
#define SHOTS 5
#define PP 10
#define FDIMC 640
#define HD 512
#define SEQ 196
#define NB 100
#define NQB 75
#define NMHA 80
#define M1 (NB*SEQ)       // 19600
#define MMHA (NMHA*SEQ)   // 15680
#define MQ (NQB*SEQ)      // 14700
#define NBLK_ROWK (MQ/4)  // 3675
#define OUT_UPD (NQB*FDIMC*SEQ)  // 9,408,000

// ---- small stats block (float offsets inside region SM) ----
#define OFF_CS1S 0
#define OFF_CS1Q 512
#define OFF_CS2S 1024
#define OFF_CS2Q 1664
#define ZERO_FLOATS 2306
#define OFF_ST1SC 2308
#define OFF_ST1SH 2820
#define OFF_ST2SC 3332
#define OFF_ST2SH 3972
#define OFF_M    4612
#define OFF_PN   14412

// ---- big regions (float offsets) ----
#define RB 20480                   /* y1 / P bf16 / (wsm+protos partials) / y2 */
#define RC (RB + 15439360)         /* xbuf fp32 (8.03M) */
#define RD (RC + 8028160)          /* keyT bf16 -> qb bf16 -> tmp fp32 */
#define RE (RD + 8028160)          /* xbufh bf16 -> VT bf16 -> xout fp32 */
#define RF (RE + 8028160)          /* sraw fp32 -> kb bf16 -> newq bf16 + feapart */
#define RG (RF + 4014080)          /* vb bf16 -> ctx bf16 */
#define RH (RG + 4014080)          /* weights bf16 concat */
#define OFF_FEAP (RF + 3763200)    /* 3675 floats, after newq within RF */
#define OFF_WSM  RB                /* 10*980 floats (P region is dead here) */
#define OFF_PPART (RB + 16384)     /* 20*10*512 floats */

typedef __bf16 bf16x8 __attribute__((ext_vector_type(8)));
typedef float f32x4 __attribute__((ext_vector_type(4)));

__device__ __forceinline__ ushort f2bf(float f) {
  unsigned u = __float_as_uint(f);
  return (ushort)((u + 0x7fffu + ((u >> 16) & 1u)) >> 16);
}

__device__ __forceinline__ f32x4 mfma16(bf16x8 a, bf16x8 b, f32x4 c) {
  return __builtin_amdgcn_mfma_f32_16x16x32_bf16(a, b, c, 0, 0, 0);
}

__device__ __forceinline__ float waveSum(float v) {
#pragma unroll
  for (int o = 32; o; o >>= 1) v += __shfl_xor(v, o, 64);
  return v;
}

// ---------- transposes / converts ----------

__global__ __launch_bounds__(256) void key_transpose(const float* __restrict__ key,
                                                     ushort* __restrict__ keyT) {
  __shared__ float T[32][33];
  const int n = blockIdx.z, c0 = blockIdx.y*32, s0 = blockIdx.x*32;
  const int tj = threadIdx.x & 31, ti = threadIdx.x >> 5;
#pragma unroll
  for (int it = 0; it < 4; ++it) {
    const int cl = it*8 + ti;
    const int s = s0 + tj;
    T[cl][tj] = (s < SEQ) ? key[((size_t)n*FDIMC + c0 + cl)*SEQ + s] : 0.f;
  }
  __syncthreads();
#pragma unroll
  for (int it = 0; it < 4; ++it) {
    const int sl = it*8 + ti;
    const int s = s0 + sl;
    if (s < SEQ) keyT[((size_t)(n*SEQ + s))*FDIMC + c0 + tj] = f2bf(T[tj][sl]);
  }
}

__global__ void wconvert(const float* __restrict__ Wc, const float* __restrict__ Wq,
                         const float* __restrict__ Wk, const float* __restrict__ Wv,
                         const float* __restrict__ Wa, const float* __restrict__ Wo,
                         ushort* __restrict__ wh) {
  const int i = blockIdx.x*256 + threadIdx.x;
  float v;
  if (i < 327680) v = Wc[i];
  else if (i < 589824) v = Wq[i - 327680];
  else if (i < 851968) v = Wk[i - 589824];
  else if (i < 1114112) v = Wv[i - 851968];
  else if (i < 1376256) v = Wa[i - 1114112];
  else v = Wo[i - 1376256];
  wh[i] = f2bf(v);
}

// ---------- bf16 MFMA GEMM: C = A(MxK) . W(NxK)^T + bias ----------
template<int OM>
__global__ __launch_bounds__(256) void gemm_bf(const ushort* __restrict__ A,
    const ushort* __restrict__ W, const float* __restrict__ bias,
    float* __restrict__ Cf, ushort* __restrict__ Ch, int M, int N, int K) {
  __shared__ ushort As[128*32];
  __shared__ ushort Bs[128*32];
  const int tid = threadIdx.x;
  const int m0 = blockIdx.y*128, n0 = blockIdx.x*128;
  const int w = tid >> 6, lane = tid & 63;
  const int wr = w >> 1, wc = w & 1;
  const int g = lane >> 4, c = lane & 15;

  const int ch0 = tid, ch1 = 256 + tid;
  const int ar0 = ch0 >> 2, ar1 = ch1 >> 2;
  const int ak0 = (ch0 & 3) * 8, ak1 = (ch1 & 3) * 8;
  int gr0 = m0 + ar0; if (gr0 > M-1) gr0 = M-1;
  int gr1 = m0 + ar1; if (gr1 > M-1) gr1 = M-1;
  const ushort* Ap0 = A + (size_t)gr0*K + ak0;
  const ushort* Ap1 = A + (size_t)gr1*K + ak1;
  const ushort* Wp0 = W + (size_t)(n0 + ar0)*K + ak0;
  const ushort* Wp1 = W + (size_t)(n0 + ar1)*K + ak1;

  f32x4 acc[4][4];
#pragma unroll
  for (int i = 0; i < 4; ++i)
#pragma unroll
    for (int j = 0; j < 4; ++j) acc[i][j] = (f32x4)(0.0f);

  for (int k0 = 0; k0 < K; k0 += 32) {
    const uint4 a0 = *(const uint4*)(Ap0 + k0);
    const uint4 a1 = *(const uint4*)(Ap1 + k0);
    const uint4 b0 = *(const uint4*)(Wp0 + k0);
    const uint4 b1 = *(const uint4*)(Wp1 + k0);
    __syncthreads();
    *(uint4*)(&As[ch0*8]) = a0;
    *(uint4*)(&As[ch1*8]) = a1;
    *(uint4*)(&Bs[ch0*8]) = b0;
    *(uint4*)(&Bs[ch1*8]) = b1;
    __syncthreads();
    bf16x8 af[4], bfr[4];
#pragma unroll
    for (int mi = 0; mi < 4; ++mi)
      af[mi] = *(const bf16x8*)(&As[(wr*64 + mi*16 + c)*32 + g*8]);
#pragma unroll
    for (int ni = 0; ni < 4; ++ni)
      bfr[ni] = *(const bf16x8*)(&Bs[(wc*64 + ni*16 + c)*32 + g*8]);
#pragma unroll
    for (int mi = 0; mi < 4; ++mi)
#pragma unroll
      for (int ni = 0; ni < 4; ++ni)
        acc[mi][ni] = mfma16(af[mi], bfr[ni], acc[mi][ni]);
  }

#pragma unroll
  for (int ni = 0; ni < 4; ++ni) {
    const int col = n0 + wc*64 + ni*16 + c;
    const float bb = bias[col];
#pragma unroll
    for (int mi = 0; mi < 4; ++mi) {
#pragma unroll
      for (int q = 0; q < 4; ++q) {
        const int row = m0 + wr*64 + mi*16 + g*4 + q;
        if (row < M) {
          const float v = acc[mi][ni][q] + bb;
          if (OM == 0) Cf[(size_t)row*N + col] = v;
          else if (OM == 1) Ch[(size_t)row*N + col] = f2bf(v);
          else Ch[(size_t)row*N + col] = f2bf(v*0.125f);
        }
      }
    }
  }
}

// ---------- BN pieces ----------

__global__ __launch_bounds__(256) void colsum(const float* __restrict__ y, int M, int C,
    float* __restrict__ sums, float* __restrict__ sumsq) {
  float a[3] = {0.f,0.f,0.f}, q[3] = {0.f,0.f,0.f};
  for (int r = blockIdx.x; r < M; r += gridDim.x) {
    const float* row = y + (size_t)r*C;
#pragma unroll
    for (int cc = 0; cc < 3; ++cc) {
      const int c = threadIdx.x + cc*256;
      if (c < C) { const float v = row[c]; a[cc] += v; q[cc] += v*v; }
    }
  }
#pragma unroll
  for (int cc = 0; cc < 3; ++cc) {
    const int c = threadIdx.x + cc*256;
    if (c < C) { atomicAdd(&sums[c], a[cc]); atomicAdd(&sumsq[c], q[cc]); }
  }
}

__global__ void bn_finalize(const float* __restrict__ sums, const float* __restrict__ sumsq,
    const float* __restrict__ g, const float* __restrict__ b, int C, float invM,
    float* __restrict__ scale, float* __restrict__ shift) {
  const int c = blockIdx.x*256 + threadIdx.x;
  if (c >= C) return;
  const float mu = sums[c]*invM;
  const float var = sumsq[c]*invM - mu*mu;
  const float sc = rsqrtf(var + 1e-5f) * g[c];
  scale[c] = sc;
  shift[c] = b[c] - mu*sc;
}

__global__ __launch_bounds__(256) void bn1_apply(const float* __restrict__ y1,
    const float* __restrict__ scale, const float* __restrict__ shift,
    float* __restrict__ sraw, float* __restrict__ xbuf, ushort* __restrict__ xbufh) {
  const int i4 = blockIdx.x*256 + threadIdx.x;
  if (i4 >= M1*HD/4) return;
  const int e = i4 << 2;
  const int col = e & (HD - 1);
  float4 v = ((const float4*)y1)[i4];
  v.x = fmaxf(fmaf(v.x, scale[col],   shift[col]),   0.f);
  v.y = fmaxf(fmaf(v.y, scale[col+1], shift[col+1]), 0.f);
  v.z = fmaxf(fmaf(v.z, scale[col+2], shift[col+2]), 0.f);
  v.w = fmaxf(fmaf(v.w, scale[col+3], shift[col+3]), 0.f);
  if (e < 25*SEQ*HD) ((float4*)sraw)[i4] = v;
  else {
    const int o4 = i4 - (20*SEQ*HD/4);
    ((float4*)xbuf)[o4] = v;
    ushort4 hv = make_ushort4(f2bf(v.x), f2bf(v.y), f2bf(v.z), f2bf(v.w));
    *(ushort4*)(xbufh + (size_t)o4*4) = hv;
  }
}

__global__ void support_mean(const float* __restrict__ sraw, float* __restrict__ xbuf,
                             ushort* __restrict__ xbufh) {
  const int i4 = blockIdx.x*256 + threadIdx.x;
  if (i4 >= WAYS*SEQ*HD/4) return;
  const int e = i4 << 2;
  const int w = e / (SEQ*HD);
  const int rem = e - w*(SEQ*HD);
  float4 acc = make_float4(0.f,0.f,0.f,0.f);
#pragma unroll
  for (int s = 0; s < SHOTS; ++s) {
    const float4 v = *(const float4*)(sraw + (s*WAYS + w)*(SEQ*HD) + rem);
    acc.x += v.x; acc.y += v.y; acc.z += v.z; acc.w += v.w;
  }
  acc.x *= 0.2f; acc.y *= 0.2f; acc.z *= 0.2f; acc.w *= 0.2f;
  ((float4*)xbuf)[i4] = acc;
  ushort4 hv = make_ushort4(f2bf(acc.x), f2bf(acc.y), f2bf(acc.z), f2bf(acc.w));
  *(ushort4*)(xbufh + (size_t)i4*4) = hv;
}

// ---------- attention: QK^T + softmax -> P bf16 [bh][208][232] ----------

__global__ __launch_bounds__(256) void attn_qk(const ushort* __restrict__ qb,
    const ushort* __restrict__ kb, ushort* __restrict__ P) {
  __shared__ ushort Ks[208*72];
  const int bh = blockIdx.x, b = bh >> 3, h = bh & 7;
  const int tid = threadIdx.x;
  for (int idx = tid; idx < 208*8; idx += 256) {
    const int row = idx >> 3, part = idx & 7;
    uint4 v = make_uint4(0u,0u,0u,0u);
    if (row < SEQ) v = *(const uint4*)(kb + ((size_t)(b*SEQ + row))*HD + h*64 + part*8);
    *(uint4*)(&Ks[row*72 + part*8]) = v;
  }
  __syncthreads();
  const int w = tid >> 6, lane = tid & 63, g = lane >> 4, c = lane & 15;
  for (int rt = w; rt < 13; rt += 4) {
    int qrow = b*SEQ + rt*16 + c; if (qrow > MMHA-1) qrow = MMHA-1;
    const bf16x8 aq0 = *(const bf16x8*)(qb + (size_t)qrow*HD + h*64 + g*8);
    const bf16x8 aq1 = *(const bf16x8*)(qb + (size_t)qrow*HD + h*64 + 32 + g*8);
    f32x4 acc[13];
#pragma unroll
    for (int ct = 0; ct < 13; ++ct) acc[ct] = (f32x4)(0.0f);
#pragma unroll
    for (int ct = 0; ct < 13; ++ct) {
      const bf16x8 b0 = *(const bf16x8*)(&Ks[(ct*16 + c)*72 + g*8]);
      const bf16x8 b1 = *(const bf16x8*)(&Ks[(ct*16 + c)*72 + 32 + g*8]);
      acc[ct] = mfma16(aq0, b0, acc[ct]);
      acc[ct] = mfma16(aq1, b1, acc[ct]);
    }
    if (c >= 4) acc[12] = (f32x4)(-1e30f);
    float mrow[4], Z[4];
#pragma unroll
    for (int q = 0; q < 4; ++q) {
      float mx = acc[0][q];
#pragma unroll
      for (int ct = 1; ct < 13; ++ct) mx = fmaxf(mx, acc[ct][q]);
      mrow[q] = mx;
    }
#pragma unroll
    for (int q = 0; q < 4; ++q) {
#pragma unroll
      for (int msk = 1; msk < 16; msk <<= 1)
        mrow[q] = fmaxf(mrow[q], __shfl_xor(mrow[q], msk, 64));
    }
#pragma unroll
    for (int q = 0; q < 4; ++q) Z[q] = 0.f;
#pragma unroll
    for (int ct = 0; ct < 13; ++ct)
#pragma unroll
      for (int q = 0; q < 4; ++q) {
        const float e = __expf(acc[ct][q] - mrow[q]);
        acc[ct][q] = e; Z[q] += e;
      }
#pragma unroll
    for (int q = 0; q < 4; ++q) {
#pragma unroll
      for (int msk = 1; msk < 16; msk <<= 1) Z[q] += __shfl_xor(Z[q], msk, 64);
      Z[q] = 1.f / Z[q];
    }
    const size_t pb = (size_t)bh*(208*232);
#pragma unroll
    for (int q = 0; q < 4; ++q) {
      ushort* pr = P + pb + (size_t)(rt*16 + g*4 + q)*232;
#pragma unroll
      for (int ct = 0; ct < 13; ++ct) pr[ct*16 + c] = f2bf(acc[ct][q]*Z[q]);
      pr[208 + c] = 0;
      if (c < 8) pr[224 + c] = 0;
    }
  }
}

// ---------- V transpose ----------

__global__ __launch_bounds__(256) void v_transpose(const ushort* __restrict__ vb,
                                                   ushort* __restrict__ VT) {
  __shared__ ushort Vs[196*72];
  const int bh = blockIdx.x, b = bh >> 3, h = bh & 7;
  const int tid = threadIdx.x;
  for (int idx = tid; idx < 196*8; idx += 256) {
    const int row = idx >> 3, part = idx & 7;
    *(uint4*)(&Vs[row*72 + part*8]) =
        *(const uint4*)(vb + ((size_t)(b*SEQ + row))*HD + h*64 + part*8);
  }
  __syncthreads();
  ushort* o = VT + (size_t)bh*64*224;
  for (int idx = tid; idx < 64*224; idx += 256) {
    const int d = idx/224, s = idx - d*224;
    o[idx] = (s < SEQ) ? Vs[s*72 + d] : (ushort)0;
  }
}

// ---------- P.V ----------

__global__ __launch_bounds__(256) void attn_pv(const ushort* __restrict__ P,
    const ushort* __restrict__ VT, ushort* __restrict__ ctx) {
  __shared__ ushort Ps[112*232];
  const int bh = blockIdx.x, b = bh >> 3, h = bh & 7;
  const int tid = threadIdx.x, w = tid >> 6, lane = tid & 63, g = lane >> 4, c = lane & 15;
  bf16x8 bv[7];
  const ushort* vt = VT + (size_t)bh*64*224 + (size_t)(w*16 + c)*224;
#pragma unroll
  for (int ks = 0; ks < 7; ++ks) bv[ks] = *(const bf16x8*)(vt + ks*32 + g*8);
  const char* pg = (const char*)(P + (size_t)bh*(208*232));
#pragma unroll
  for (int half = 0; half < 2; ++half) {
    const int r0 = half ? 112 : 0;
    const int nbytes = half ? 96*464 : 112*464;
    __syncthreads();
    for (int byte = tid*16; byte < nbytes; byte += 4096)
      *(uint4*)((char*)Ps + byte) = *(const uint4*)(pg + r0*464 + byte);
    __syncthreads();
    const int rtlo = half ? 7 : 0, rthi = half ? 13 : 7;
    for (int rt = rtlo; rt < rthi; ++rt) {
      const int lrow = rt*16 - r0 + c;
      f32x4 acc = (f32x4)(0.0f);
#pragma unroll
      for (int ks = 0; ks < 7; ++ks) {
        const bf16x8 a = *(const bf16x8*)(&Ps[lrow*232 + ks*32 + g*8]);
        acc = mfma16(a, bv[ks], acc);
      }
#pragma unroll
      for (int q = 0; q < 4; ++q) {
        const int srow = rt*16 + g*4 + q;
        if (srow < SEQ)
          ctx[((size_t)(b*SEQ + srow))*HD + h*64 + w*16 + c] = f2bf(acc[q]);
      }
    }
  }
}

// ---------- LayerNorm + residual ----------

__global__ __launch_bounds__(256) void ln_kernel(const float* __restrict__ tmp,
    const float* __restrict__ xin, const float* __restrict__ g,
    const float* __restrict__ bta, float* __restrict__ out) {
  const int row = blockIdx.x*4 + (threadIdx.x >> 6);
  const int lane = threadIdx.x & 63;
  const float* t = tmp + (size_t)row*HD;
  const float* x = xin + (size_t)row*HD;
  float v[8]; float s = 0.f;
#pragma unroll
  for (int i = 0; i < 8; ++i) { const float val = t[i*64 + lane] + x[i*64 + lane]; v[i] = val; s += val; }
  s = waveSum(s);
  const float mu = s * (1.f/HD);
  float sq = 0.f;
#pragma unroll
  for (int i = 0; i < 8; ++i) { const float d = v[i] - mu; sq += d*d; }
  sq = waveSum(sq);
  const float istd = rsqrtf(sq*(1.f/HD) + 1e-5f);
#pragma unroll
  for (int i = 0; i < 8; ++i) {
    const int d = i*64 + lane;
    out[(size_t)row*HD + d] = (v[i] - mu)*istd*g[d] + bta[d];
  }
}

// ---------- prototypes / losses / per-row ----------

__global__ __launch_bounds__(256) void mw_kernel(const float* __restrict__ xout,
    const float* __restrict__ Wm, float* __restrict__ m) {
  const int row = blockIdx.x*4 + (threadIdx.x >> 6);
  const int lane = threadIdx.x & 63;
  const float* x = xout + (size_t)row*HD;
  float xv[8];
#pragma unroll
  for (int i = 0; i < 8; ++i) xv[i] = x[i*64 + lane];
#pragma unroll
  for (int p = 0; p < PP; ++p) {
    const float* wp = Wm + p*HD;
    float s = 0.f;
#pragma unroll
    for (int i = 0; i < 8; ++i) s = fmaf(xv[i], wp[i*64 + lane], s);
    s = waveSum(s);
    if (lane == 0) m[row*PP + p] = s;
  }
}

// stage 1: per-p softmax over 980 rows -> normalized weights wsm[p*980+r]
__global__ __launch_bounds__(256) void wsm_kernel(const float* __restrict__ m,
                                                  float* __restrict__ wsm) {
  __shared__ float red[256];
  const int p = blockIdx.x, tid = threadIdx.x;
  float lmax = -1e30f;
  for (int r = tid; r < 980; r += 256) lmax = fmaxf(lmax, m[r*PP + p]);
  red[tid] = lmax; __syncthreads();
  for (int s = 128; s; s >>= 1) { if (tid < s) red[tid] = fmaxf(red[tid], red[tid+s]); __syncthreads(); }
  const float bmax = red[0]; __syncthreads();
  float lsum = 0.f;
  for (int r = tid; r < 980; r += 256) {
    const float e = __expf(m[r*PP + p] - bmax);
    wsm[p*980 + r] = e; lsum += e;
  }
  red[tid] = lsum; __syncthreads();
  for (int s = 128; s; s >>= 1) { if (tid < s) red[tid] += red[tid+s]; __syncthreads(); }
  const float invZ = 1.f / red[0];
  for (int r = tid; r < 980; r += 256) wsm[p*980 + r] *= invZ;
}

// stage 2: split-K weighted pool: part[(p*20+chunk)][512]
__global__ __launch_bounds__(256) void protos_part(const float* __restrict__ wsm,
    const float* __restrict__ xout, float* __restrict__ part) {
  const int p = blockIdx.y, chunk = blockIdx.x, tid = threadIdx.x;
  const int r0 = chunk*49;
  float a0 = 0.f, a1 = 0.f;
  for (int r = r0; r < r0 + 49; ++r) {
    const float w = wsm[p*980 + r];
    a0 = fmaf(w, xout[(size_t)r*HD + tid], a0);
    a1 = fmaf(w, xout[(size_t)r*HD + tid + 256], a1);
  }
  float* o = part + (((size_t)p*20 + chunk) << 9);
  o[tid] = a0;
  o[tid + 256] = a1;
}

// stage 3: reduce 20 partials, l2-normalize -> pn
__global__ __launch_bounds__(256) void protos_fin(const float* __restrict__ part,
                                                  float* __restrict__ pn) {
  __shared__ float red[256];
  const int p = blockIdx.x, tid = threadIdx.x;
  float a0 = 0.f, a1 = 0.f;
  for (int cch = 0; cch < 20; ++cch) {
    const float* o = part + (((size_t)p*20 + cch) << 9);
    a0 += o[tid];
    a1 += o[tid + 256];
  }
  red[tid] = a0*a0 + a1*a1; __syncthreads();
  for (int s = 128; s; s >>= 1) { if (tid < s) red[tid] += red[tid+s]; __syncthreads(); }
  const float rn = 1.f / fmaxf(sqrtf(red[0]), 1e-12f);
  pn[p*HD + tid] = a0*rn;
  pn[p*HD + tid + 256] = a1*rn;
}

__global__ __launch_bounds__(256) void losses_kernel(const float* __restrict__ pn, float* __restrict__ out) {
  __shared__ float redc[256], redd[256];
  const int tid = threadIdx.x;
  float cpart = 0.f, dpart = 0.f;
  for (int d = tid; d < HD; d += 256) {
    float a[PP];
#pragma unroll
    for (int j = 0; j < PP; ++j) a[j] = pn[j*HD + d];
#pragma unroll
    for (int j = 0; j < PP; ++j) {
      if (d > j) {
#pragma unroll
        for (int i = 0; i < PP; ++i) {
          const float df = a[j] - a[i];
          const float t = 1.f - df*df;
          if (t > 0.f) dpart += t;
        }
      }
    }
#pragma unroll
    for (int j = 0; j < PP - 1; ++j) { const float df = a[j+1] - a[j]; cpart += df*df; }
  }
  redc[tid] = cpart; redd[tid] = dpart; __syncthreads();
  for (int s = 128; s; s >>= 1) {
    if (tid < s) { redc[tid] += redc[tid+s]; redd[tid] += redd[tid+s]; }
    __syncthreads();
  }
  if (tid == 0) {
    out[OUT_UPD + 1] = redc[0] / 9.f;
    out[OUT_UPD + 2] = redd[0] * (2.f / (90.f * 512.f));
  }
}

__global__ __launch_bounds__(256) void rowk(const float* __restrict__ xout, const float* __restrict__ pn,
    ushort* __restrict__ newq, float* __restrict__ feapart) {
  __shared__ float Ps[PP*HD];
  __shared__ float fred[4];
  const int tid = threadIdx.x;
  for (int idx = tid; idx < PP*HD; idx += 256) Ps[idx] = pn[idx];
  __syncthreads();
  const int row = blockIdx.x*4 + (tid >> 6);
  const int lane = tid & 63;
  const float* x = xout + (size_t)(WAYS*SEQ + row)*HD;
  float xv[8];
#pragma unroll
  for (int i = 0; i < 8; ++i) xv[i] = x[i*64 + lane];
  float sc[PP];
#pragma unroll
  for (int p = 0; p < PP; ++p) {
    float s = 0.f;
#pragma unroll
    for (int i = 0; i < 8; ++i) s = fmaf(xv[i], Ps[p*HD + i*64 + lane], s);
    sc[p] = waveSum(s);
  }
  float mx = sc[0]; int am = 0;
#pragma unroll
  for (int p = 1; p < PP; ++p) if (sc[p] > mx) { mx = sc[p]; am = p; }
  float Z = 0.f; float sp[PP];
#pragma unroll
  for (int p = 0; p < PP; ++p) { const float e = expf(sc[p] - mx); sp[p] = e; Z += e; }
  const float rz = 1.f / Z;
  float nv[8]; float ss = 0.f;
#pragma unroll
  for (int i = 0; i < 8; ++i) {
    float a = 0.f;
#pragma unroll
    for (int p = 0; p < PP; ++p) a = fmaf(sp[p], Ps[p*HD + i*64 + lane], a);
    a *= rz; nv[i] = a; ss += a*a;
  }
  ss = waveSum(ss);
  const float rn = 1.f / fmaxf(sqrtf(ss), 1e-12f);
#pragma unroll
  for (int i = 0; i < 8; ++i) newq[(size_t)row*HD + i*64 + lane] = f2bf(nv[i]*rn);
  float fp = 0.f;
#pragma unroll
  for (int i = 0; i < 8; ++i) { const float d = xv[i] - Ps[am*HD + i*64 + lane]; fp += d*d; }
  fp = waveSum(fp);
  if (lane == 0) fred[tid >> 6] = fp;
  __syncthreads();
  if (tid == 0) feapart[blockIdx.x] = fred[0] + fred[1] + fred[2] + fred[3];
}

__global__ __launch_bounds__(256) void fea_finalize(const float* __restrict__ feapart,
                                                    float* __restrict__ out) {
  __shared__ float red[256];
  float s = 0.f;
  for (int i = threadIdx.x; i < NBLK_ROWK; i += 256) s += feapart[i];
  red[threadIdx.x] = s; __syncthreads();
  for (int st = 128; st; st >>= 1) {
    if (threadIdx.x < st) red[threadIdx.x] += red[threadIdx.x + st];
    __syncthreads();
  }
  if (threadIdx.x == 0) out[OUT_UPD] = red[0] / (float)((size_t)NQB*SEQ*HD);
}

__global__ __launch_bounds__(256) void bn2_apply(const float* __restrict__ y2, const float* __restrict__ scale,
    const float* __restrict__ shift, const float* __restrict__ query, float* __restrict__ out) {
  __shared__ float tile[32][33];
  const int n = blockIdx.z, o0 = blockIdx.y*32, hw0 = blockIdx.x*32;
  const int tj = threadIdx.x & 31, ti = threadIdx.x >> 5;
#pragma unroll
  for (int it = 0; it < 4; ++it) {
    const int hw = hw0 + it*8 + ti;
    const int o = o0 + tj;
    float v = 0.f;
    if (hw < SEQ) v = fmaxf(fmaf(y2[((size_t)n*SEQ + hw)*FDIMC + o], scale[o], shift[o]), 0.f);
    tile[it*8 + ti][tj] = v;
  }
  __syncthreads();
#pragma unroll
  for (int it = 0; it < 4; ++it) {
    const int o = o0 + it*8 + ti;
    const int hw = hw0 + tj;
    if (hw < SEQ) {
      const size_t oi = ((size_t)n*FDIMC + o)*SEQ + hw;
      out[oi] = tile[tj][it*8 + ti] + query[oi];
    }
  }
}

extern "C" void kernel_launch(void* const* d_in, const int* in_sizes, int n_in,
                              void* d_out, int out_size, void* d_ws, size_t ws_size,
                              hipStream_t stream) {
  const float* key   = (const float*)d_in[0];
  const float* query = (const float*)d_in[1];
  const float* Wc    = (const float*)d_in[2];
  const float* bc    = (const float*)d_in[3];
  const float* g1    = (const float*)d_in[4];
  const float* b1    = (const float*)d_in[5];
  const float* Wq    = (const float*)d_in[6];
  const float* bq    = (const float*)d_in[7];
  const float* Wk    = (const float*)d_in[8];
  const float* bk    = (const float*)d_in[9];
  const float* Wv    = (const float*)d_in[10];
  const float* bv    = (const float*)d_in[11];
  const float* Wa    = (const float*)d_in[12];
  const float* ba    = (const float*)d_in[13];
  const float* ln_g  = (const float*)d_in[14];
  const float* ln_b  = (const float*)d_in[15];
  const float* Wm    = (const float*)d_in[16];
  const float* Wo    = (const float*)d_in[17];
  const float* bo    = (const float*)d_in[18];
  const float* g2    = (const float*)d_in[19];
  const float* b2    = (const float*)d_in[20];
  float* out = (float*)d_out;
  float* w = (float*)d_ws;

  float*  y1    = w + RB;
  ushort* P     = (ushort*)(w + RB);
  float*  y2    = w + RB;
  float*  xbuf  = w + RC;
  ushort* keyT  = (ushort*)(w + RD);
  ushort* qb    = (ushort*)(w + RD);
  float*  tmp   = w + RD;
  ushort* xbufh = (ushort*)(w + RE);
  ushort* VT    = (ushort*)(w + RE);
  float*  xout  = w + RE;
  float*  sraw  = w + RF;
  ushort* kb    = (ushort*)(w + RF);
  ushort* newq  = (ushort*)(w + RF);
  ushort* vb    = (ushort*)(w + RG);
  ushort* ctx   = (ushort*)(w + RG);
  ushort* wh    = (ushort*)(w + RH);
  float*  feapart = w + OFF_FEAP;
  float*  wsm   = w + OFF_WSM;
  float*  ppart = w + OFF_PPART;
  ushort* Wcb = wh;
  ushort* Wqb = wh + 327680;
  ushort* Wkb = wh + 589824;
  ushort* Wvb = wh + 851968;
  ushort* Wab = wh + 1114112;
  ushort* Wob = wh + 1376256;

  hipMemsetAsync(w, 0, ZERO_FLOATS*sizeof(float), stream);

  key_transpose<<<dim3(7, 20, NB), 256, 0, stream>>>(key, keyT);
  wconvert<<<6656, 256, 0, stream>>>(Wc, Wq, Wk, Wv, Wa, Wo, wh);

  // conv1 (bf16 MFMA) + BN1 + relu
  gemm_bf<0><<<dim3(4, 154), 256, 0, stream>>>(keyT, Wcb, bc, y1, nullptr, M1, HD, FDIMC);
  colsum<<<256, 256, 0, stream>>>(y1, M1, HD, w + OFF_CS1S, w + OFF_CS1Q);
  bn_finalize<<<2, 256, 0, stream>>>(w + OFF_CS1S, w + OFF_CS1Q, g1, b1, HD, 1.f/M1,
                                     w + OFF_ST1SC, w + OFF_ST1SH);
  bn1_apply<<<M1*HD/4/256, 256, 0, stream>>>(y1, w + OFF_ST1SC, w + OFF_ST1SH, sraw, xbuf, xbufh);
  support_mean<<<WAYS*SEQ*HD/4/256, 256, 0, stream>>>(sraw, xbuf, xbufh);

  // MHA projections (bf16 out; q pre-scaled by 1/8)
  gemm_bf<2><<<dim3(4, 123), 256, 0, stream>>>(xbufh, Wqb, bq, nullptr, qb, MMHA, HD, HD);
  gemm_bf<1><<<dim3(4, 123), 256, 0, stream>>>(xbufh, Wkb, bk, nullptr, kb, MMHA, HD, HD);
  gemm_bf<1><<<dim3(4, 123), 256, 0, stream>>>(xbufh, Wvb, bv, nullptr, vb, MMHA, HD, HD);

  v_transpose<<<NMHA*8, 256, 0, stream>>>(vb, VT);
  attn_qk<<<NMHA*8, 256, 0, stream>>>(qb, kb, P);
  attn_pv<<<NMHA*8, 256, 0, stream>>>(P, VT, ctx);

  gemm_bf<0><<<dim3(4, 123), 256, 0, stream>>>(ctx, Wab, ba, tmp, nullptr, MMHA, HD, HD);
  ln_kernel<<<MMHA/4, 256, 0, stream>>>(tmp, xbuf, ln_g, ln_b, xout);

  // prototypes + losses (parallel 3-stage pooling)
  mw_kernel<<<245, 256, 0, stream>>>(xout, Wm, w + OFF_M);
  wsm_kernel<<<PP, 256, 0, stream>>>(w + OFF_M, wsm);
  protos_part<<<dim3(20, PP), 256, 0, stream>>>(wsm, xout, ppart);
  protos_fin<<<PP, 256, 0, stream>>>(ppart, w + OFF_PN);
  losses_kernel<<<1, 256, 0, stream>>>(w + OFF_PN, out);
  rowk<<<NBLK_ROWK, 256, 0, stream>>>(xout, w + OFF_PN, newq, feapart);

  // conv2 (bf16 MFMA) + BN2 + relu + residual
  gemm_bf<0><<<dim3(5, 115), 256, 0, stream>>>(newq, Wob, bo, y2, nullptr, MQ, FDIMC, HD);
  colsum<<<256, 256, 0, stream>>>(y2, MQ, FDIMC, w + OFF_CS2S, w + OFF_CS2Q);
  bn_finalize<<<3, 256, 0, stream>>>(w + OFF_CS2S, w + OFF_CS2Q, g2, b2, FDIMC, 1.f/MQ,
                                     w + OFF_ST2SC, w + OFF_ST2SH);
  fea_finalize<<<1, 256, 0, stream>>>(feapart, out);
  bn2_apply<<<dim3(7, 20, NQB), 256, 0, stream>>>(y2, w + OFF_ST2SC, w + OFF_ST2SH, query, out);
}

// Round 5
// 393.030 us; speedup vs baseline: 4.4517x; 1.2193x over previous
//
#include <hip/hip_runtime.h>
#include <math.h>

// ---- problem constants ----
#define WAYS 5
#define SHOTS 5
#define PP 10
#define FDIMC 640
#define HD 512
#define SEQ 196
#define NB 100
#define NQB 75
#define NMHA 80
#define M1 (NB*SEQ)       // 19600
#define MMHA (NMHA*SEQ)   // 15680
#define MQ (NQB*SEQ)      // 14700
#define NBLK_ROWK (MQ/4)  // 3675
#define OUT_UPD (NQB*FDIMC*SEQ)  // 9,408,000

// ---- small stats block (float offsets inside region SM) ----
#define OFF_CS1S 0
#define OFF_CS1Q 512
#define OFF_CS2S 1024
#define OFF_CS2Q 1664
#define ZERO_FLOATS 2306
#define OFF_ST1SC 2308
#define OFF_ST1SH 2820
#define OFF_ST2SC 3332
#define OFF_ST2SH 3972
#define OFF_M    4612
#define OFF_PN   14412

// ---- big regions (float offsets) ----
#define RB 20480                   /* y1 / P bf16 / (wsm+protos partials) / y2 */
#define RC (RB + 15439360)         /* xbuf fp32 (8.03M) */
#define RD (RC + 8028160)          /* keyT bf16 -> qb bf16 -> tmp fp32 */
#define RE (RD + 8028160)          /* xbufh bf16 -> VT bf16 -> xout fp32 */
#define RF (RE + 8028160)          /* sraw fp32 -> kb bf16 -> newq bf16 + feapart */
#define RG (RF + 4014080)          /* vb bf16 -> ctx bf16 */
#define RH (RG + 4014080)          /* weights bf16 concat */
#define OFF_FEAP (RF + 3763200)    /* 3675 floats, after newq within RF */
#define OFF_WSM  RB                /* 10*980 floats (P region is dead here) */
#define OFF_PPART (RB + 16384)     /* 20*10*512 floats */

typedef __bf16 bf16x8 __attribute__((ext_vector_type(8)));
typedef float f32x4 __attribute__((ext_vector_type(4)));

__device__ __forceinline__ ushort f2bf(float f) {
  unsigned u = __float_as_uint(f);
  return (ushort)((u + 0x7fffu + ((u >> 16) & 1u)) >> 16);
}

__device__ __forceinline__ f32x4 mfma16(bf16x8 a, bf16x8 b, f32x4 c) {
  return __builtin_amdgcn_mfma_f32_16x16x32_bf16(a, b, c, 0, 0, 0);
}

__device__ __forceinline__ float waveSum(float v) {
#pragma unroll
  for (int o = 32; o; o >>= 1) v += __shfl_xor(v, o, 64);
  return v;
}

// ---------- transposes / converts ----------

__global__ __launch_bounds__(256) void key_transpose(const float* __restrict__ key,
                                                     ushort* __restrict__ keyT) {
  __shared__ float T[32][33];
  const int n = blockIdx.z, c0 = blockIdx.y*32, s0 = blockIdx.x*32;
  const int tj = threadIdx.x & 31, ti = threadIdx.x >> 5;
#pragma unroll
  for (int it = 0; it < 4; ++it) {
    const int cl = it*8 + ti;
    const int s = s0 + tj;
    T[cl][tj] = (s < SEQ) ? key[((size_t)n*FDIMC + c0 + cl)*SEQ + s] : 0.f;
  }
  __syncthreads();
#pragma unroll
  for (int it = 0; it < 4; ++it) {
    const int sl = it*8 + ti;
    const int s = s0 + sl;
    if (s < SEQ) keyT[((size_t)(n*SEQ + s))*FDIMC + c0 + tj] = f2bf(T[tj][sl]);
  }
}

__global__ void wconvert(const float* __restrict__ Wc, const float* __restrict__ Wq,
                         const float* __restrict__ Wk, const float* __restrict__ Wv,
                         const float* __restrict__ Wa, const float* __restrict__ Wo,
                         ushort* __restrict__ wh) {
  const int i = blockIdx.x*256 + threadIdx.x;
  float v;
  if (i < 327680) v = Wc[i];
  else if (i < 589824) v = Wq[i - 327680];
  else if (i < 851968) v = Wk[i - 589824];
  else if (i < 1114112) v = Wv[i - 851968];
  else if (i < 1376256) v = Wa[i - 1114112];
  else v = Wo[i - 1376256];
  wh[i] = f2bf(v);
}

// ---------- bf16 MFMA GEMM: C = A(MxK) . W(NxK)^T + bias ----------
// OM: 0 -> fp32 out, 1 -> bf16 out, 2 -> bf16 out scaled by 0.125
// CS: 1 -> accumulate per-column sum/sumsq of the fp32 output into gsum/gsq
template<int OM, int CS>
__global__ __launch_bounds__(256) void gemm_bf(const ushort* __restrict__ A,
    const ushort* __restrict__ W, const float* __restrict__ bias,
    float* __restrict__ Cf, ushort* __restrict__ Ch, int M, int N, int K,
    float* __restrict__ gsum, float* __restrict__ gsq) {
  __shared__ ushort As[128*32];
  __shared__ ushort Bs[128*32];
  __shared__ float csum[128], csq[128];
  const int tid = threadIdx.x;
  const int m0 = blockIdx.y*128, n0 = blockIdx.x*128;
  const int w = tid >> 6, lane = tid & 63;
  const int wr = w >> 1, wc = w & 1;
  const int g = lane >> 4, c = lane & 15;

  const int ch0 = tid, ch1 = 256 + tid;
  const int ar0 = ch0 >> 2, ar1 = ch1 >> 2;
  const int ak0 = (ch0 & 3) * 8, ak1 = (ch1 & 3) * 8;
  int gr0 = m0 + ar0; if (gr0 > M-1) gr0 = M-1;
  int gr1 = m0 + ar1; if (gr1 > M-1) gr1 = M-1;
  const ushort* Ap0 = A + (size_t)gr0*K + ak0;
  const ushort* Ap1 = A + (size_t)gr1*K + ak1;
  const ushort* Wp0 = W + (size_t)(n0 + ar0)*K + ak0;
  const ushort* Wp1 = W + (size_t)(n0 + ar1)*K + ak1;

  f32x4 acc[4][4];
#pragma unroll
  for (int i = 0; i < 4; ++i)
#pragma unroll
    for (int j = 0; j < 4; ++j) acc[i][j] = (f32x4)(0.0f);

  for (int k0 = 0; k0 < K; k0 += 32) {
    const uint4 a0 = *(const uint4*)(Ap0 + k0);
    const uint4 a1 = *(const uint4*)(Ap1 + k0);
    const uint4 b0 = *(const uint4*)(Wp0 + k0);
    const uint4 b1 = *(const uint4*)(Wp1 + k0);
    __syncthreads();
    *(uint4*)(&As[ch0*8]) = a0;
    *(uint4*)(&As[ch1*8]) = a1;
    *(uint4*)(&Bs[ch0*8]) = b0;
    *(uint4*)(&Bs[ch1*8]) = b1;
    __syncthreads();
    bf16x8 af[4], bfr[4];
#pragma unroll
    for (int mi = 0; mi < 4; ++mi)
      af[mi] = *(const bf16x8*)(&As[(wr*64 + mi*16 + c)*32 + g*8]);
#pragma unroll
    for (int ni = 0; ni < 4; ++ni)
      bfr[ni] = *(const bf16x8*)(&Bs[(wc*64 + ni*16 + c)*32 + g*8]);
#pragma unroll
    for (int mi = 0; mi < 4; ++mi)
#pragma unroll
      for (int ni = 0; ni < 4; ++ni)
        acc[mi][ni] = mfma16(af[mi], bfr[ni], acc[mi][ni]);
  }

  if (CS) {
    __syncthreads();
    if (tid < 128) { csum[tid] = 0.f; csq[tid] = 0.f; }
    __syncthreads();
  }

#pragma unroll
  for (int ni = 0; ni < 4; ++ni) {
    const int col = n0 + wc*64 + ni*16 + c;
    const float bb = bias[col];
    float ls = 0.f, lq = 0.f;
#pragma unroll
    for (int mi = 0; mi < 4; ++mi) {
#pragma unroll
      for (int q = 0; q < 4; ++q) {
        const int row = m0 + wr*64 + mi*16 + g*4 + q;
        if (row < M) {
          const float v = acc[mi][ni][q] + bb;
          if (OM == 0) Cf[(size_t)row*N + col] = v;
          else if (OM == 1) Ch[(size_t)row*N + col] = f2bf(v);
          else Ch[(size_t)row*N + col] = f2bf(v*0.125f);
          if (CS) { ls += v; lq += v*v; }
        }
      }
    }
    if (CS) {
      const int lcol = wc*64 + ni*16 + c;
      atomicAdd(&csum[lcol], ls);
      atomicAdd(&csq[lcol], lq);
    }
  }
  if (CS) {
    __syncthreads();
    if (tid < 128) {
      atomicAdd(&gsum[n0 + tid], csum[tid]);
      atomicAdd(&gsq[n0 + tid], csq[tid]);
    }
  }
}

// ---------- BN pieces ----------

__global__ void bn_finalize(const float* __restrict__ sums, const float* __restrict__ sumsq,
    const float* __restrict__ g, const float* __restrict__ b, int C, float invM,
    float* __restrict__ scale, float* __restrict__ shift) {
  const int c = blockIdx.x*256 + threadIdx.x;
  if (c >= C) return;
  const float mu = sums[c]*invM;
  const float var = sumsq[c]*invM - mu*mu;
  const float sc = rsqrtf(var + 1e-5f) * g[c];
  scale[c] = sc;
  shift[c] = b[c] - mu*sc;
}

__global__ __launch_bounds__(256) void bn1_apply(const float* __restrict__ y1,
    const float* __restrict__ scale, const float* __restrict__ shift,
    float* __restrict__ sraw, float* __restrict__ xbuf, ushort* __restrict__ xbufh) {
  const int i4 = blockIdx.x*256 + threadIdx.x;
  if (i4 >= M1*HD/4) return;
  const int e = i4 << 2;
  const int col = e & (HD - 1);
  float4 v = ((const float4*)y1)[i4];
  v.x = fmaxf(fmaf(v.x, scale[col],   shift[col]),   0.f);
  v.y = fmaxf(fmaf(v.y, scale[col+1], shift[col+1]), 0.f);
  v.z = fmaxf(fmaf(v.z, scale[col+2], shift[col+2]), 0.f);
  v.w = fmaxf(fmaf(v.w, scale[col+3], shift[col+3]), 0.f);
  if (e < 25*SEQ*HD) ((float4*)sraw)[i4] = v;
  else {
    const int o4 = i4 - (20*SEQ*HD/4);
    ((float4*)xbuf)[o4] = v;
    ushort4 hv = make_ushort4(f2bf(v.x), f2bf(v.y), f2bf(v.z), f2bf(v.w));
    *(ushort4*)(xbufh + (size_t)o4*4) = hv;
  }
}

__global__ void support_mean(const float* __restrict__ sraw, float* __restrict__ xbuf,
                             ushort* __restrict__ xbufh) {
  const int i4 = blockIdx.x*256 + threadIdx.x;
  if (i4 >= WAYS*SEQ*HD/4) return;
  const int e = i4 << 2;
  const int w = e / (SEQ*HD);
  const int rem = e - w*(SEQ*HD);
  float4 acc = make_float4(0.f,0.f,0.f,0.f);
#pragma unroll
  for (int s = 0; s < SHOTS; ++s) {
    const float4 v = *(const float4*)(sraw + (s*WAYS + w)*(SEQ*HD) + rem);
    acc.x += v.x; acc.y += v.y; acc.z += v.z; acc.w += v.w;
  }
  acc.x *= 0.2f; acc.y *= 0.2f; acc.z *= 0.2f; acc.w *= 0.2f;
  ((float4*)xbuf)[i4] = acc;
  ushort4 hv = make_ushort4(f2bf(acc.x), f2bf(acc.y), f2bf(acc.z), f2bf(acc.w));
  *(ushort4*)(xbufh + (size_t)i4*4) = hv;
}

// ---------- attention: QK^T + softmax -> P bf16 [bh][208][232] ----------

__global__ __launch_bounds__(256) void attn_qk(const ushort* __restrict__ qb,
    const ushort* __restrict__ kb, ushort* __restrict__ P) {
  __shared__ ushort Ks[208*72];
  const int bh = blockIdx.x, b = bh >> 3, h = bh & 7;
  const int tid = threadIdx.x;
  for (int idx = tid; idx < 208*8; idx += 256) {
    const int row = idx >> 3, part = idx & 7;
    uint4 v = make_uint4(0u,0u,0u,0u);
    if (row < SEQ) v = *(const uint4*)(kb + ((size_t)(b*SEQ + row))*HD + h*64 + part*8);
    *(uint4*)(&Ks[row*72 + part*8]) = v;
  }
  __syncthreads();
  const int w = tid >> 6, lane = tid & 63, g = lane >> 4, c = lane & 15;
  for (int rt = w; rt < 13; rt += 4) {
    int qrow = b*SEQ + rt*16 + c; if (qrow > MMHA-1) qrow = MMHA-1;
    const bf16x8 aq0 = *(const bf16x8*)(qb + (size_t)qrow*HD + h*64 + g*8);
    const bf16x8 aq1 = *(const bf16x8*)(qb + (size_t)qrow*HD + h*64 + 32 + g*8);
    f32x4 acc[13];
#pragma unroll
    for (int ct = 0; ct < 13; ++ct) acc[ct] = (f32x4)(0.0f);
#pragma unroll
    for (int ct = 0; ct < 13; ++ct) {
      const bf16x8 b0 = *(const bf16x8*)(&Ks[(ct*16 + c)*72 + g*8]);
      const bf16x8 b1 = *(const bf16x8*)(&Ks[(ct*16 + c)*72 + 32 + g*8]);
      acc[ct] = mfma16(aq0, b0, acc[ct]);
      acc[ct] = mfma16(aq1, b1, acc[ct]);
    }
    if (c >= 4) acc[12] = (f32x4)(-1e30f);
    float mrow[4], Z[4];
#pragma unroll
    for (int q = 0; q < 4; ++q) {
      float mx = acc[0][q];
#pragma unroll
      for (int ct = 1; ct < 13; ++ct) mx = fmaxf(mx, acc[ct][q]);
      mrow[q] = mx;
    }
#pragma unroll
    for (int q = 0; q < 4; ++q) {
#pragma unroll
      for (int msk = 1; msk < 16; msk <<= 1)
        mrow[q] = fmaxf(mrow[q], __shfl_xor(mrow[q], msk, 64));
    }
#pragma unroll
    for (int q = 0; q < 4; ++q) Z[q] = 0.f;
#pragma unroll
    for (int ct = 0; ct < 13; ++ct)
#pragma unroll
      for (int q = 0; q < 4; ++q) {
        const float e = __expf(acc[ct][q] - mrow[q]);
        acc[ct][q] = e; Z[q] += e;
      }
#pragma unroll
    for (int q = 0; q < 4; ++q) {
#pragma unroll
      for (int msk = 1; msk < 16; msk <<= 1) Z[q] += __shfl_xor(Z[q], msk, 64);
      Z[q] = 1.f / Z[q];
    }
    const size_t pb = (size_t)bh*(208*232);
#pragma unroll
    for (int q = 0; q < 4; ++q) {
      ushort* pr = P + pb + (size_t)(rt*16 + g*4 + q)*232;
#pragma unroll
      for (int ct = 0; ct < 13; ++ct) pr[ct*16 + c] = f2bf(acc[ct][q]*Z[q]);
      pr[208 + c] = 0;
      if (c < 8) pr[224 + c] = 0;
    }
  }
}

// ---------- V transpose ----------

__global__ __launch_bounds__(256) void v_transpose(const ushort* __restrict__ vb,
                                                   ushort* __restrict__ VT) {
  __shared__ ushort Vs[196*72];
  const int bh = blockIdx.x, b = bh >> 3, h = bh & 7;
  const int tid = threadIdx.x;
  for (int idx = tid; idx < 196*8; idx += 256) {
    const int row = idx >> 3, part = idx & 7;
    *(uint4*)(&Vs[row*72 + part*8]) =
        *(const uint4*)(vb + ((size_t)(b*SEQ + row))*HD + h*64 + part*8);
  }
  __syncthreads();
  ushort* o = VT + (size_t)bh*64*224;
  for (int idx = tid; idx < 64*224; idx += 256) {
    const int d = idx/224, s = idx - d*224;
    o[idx] = (s < SEQ) ? Vs[s*72 + d] : (ushort)0;
  }
}

// ---------- P.V ----------

__global__ __launch_bounds__(256) void attn_pv(const ushort* __restrict__ P,
    const ushort* __restrict__ VT, ushort* __restrict__ ctx) {
  __shared__ ushort Ps[112*232];
  const int bh = blockIdx.x, b = bh >> 3, h = bh & 7;
  const int tid = threadIdx.x, w = tid >> 6, lane = tid & 63, g = lane >> 4, c = lane & 15;
  bf16x8 bv[7];
  const ushort* vt = VT + (size_t)bh*64*224 + (size_t)(w*16 + c)*224;
#pragma unroll
  for (int ks = 0; ks < 7; ++ks) bv[ks] = *(const bf16x8*)(vt + ks*32 + g*8);
  const char* pg = (const char*)(P + (size_t)bh*(208*232));
#pragma unroll
  for (int half = 0; half < 2; ++half) {
    const int r0 = half ? 112 : 0;
    const int nbytes = half ? 96*464 : 112*464;
    __syncthreads();
    for (int byte = tid*16; byte < nbytes; byte += 4096)
      *(uint4*)((char*)Ps + byte) = *(const uint4*)(pg + r0*464 + byte);
    __syncthreads();
    const int rtlo = half ? 7 : 0, rthi = half ? 13 : 7;
    for (int rt = rtlo; rt < rthi; ++rt) {
      const int lrow = rt*16 - r0 + c;
      f32x4 acc = (f32x4)(0.0f);
#pragma unroll
      for (int ks = 0; ks < 7; ++ks) {
        const bf16x8 a = *(const bf16x8*)(&Ps[lrow*232 + ks*32 + g*8]);
        acc = mfma16(a, bv[ks], acc);
      }
#pragma unroll
      for (int q = 0; q < 4; ++q) {
        const int srow = rt*16 + g*4 + q;
        if (srow < SEQ)
          ctx[((size_t)(b*SEQ + srow))*HD + h*64 + w*16 + c] = f2bf(acc[q]);
      }
    }
  }
}

// ---------- LayerNorm + residual ----------

__global__ __launch_bounds__(256) void ln_kernel(const float* __restrict__ tmp,
    const float* __restrict__ xin, const float* __restrict__ g,
    const float* __restrict__ bta, float* __restrict__ out) {
  const int row = blockIdx.x*4 + (threadIdx.x >> 6);
  const int lane = threadIdx.x & 63;
  const float* t = tmp + (size_t)row*HD;
  const float* x = xin + (size_t)row*HD;
  float v[8]; float s = 0.f;
#pragma unroll
  for (int i = 0; i < 8; ++i) { const float val = t[i*64 + lane] + x[i*64 + lane]; v[i] = val; s += val; }
  s = waveSum(s);
  const float mu = s * (1.f/HD);
  float sq = 0.f;
#pragma unroll
  for (int i = 0; i < 8; ++i) { const float d = v[i] - mu; sq += d*d; }
  sq = waveSum(sq);
  const float istd = rsqrtf(sq*(1.f/HD) + 1e-5f);
#pragma unroll
  for (int i = 0; i < 8; ++i) {
    const int d = i*64 + lane;
    out[(size_t)row*HD + d] = (v[i] - mu)*istd*g[d] + bta[d];
  }
}

// ---------- prototypes / losses / per-row ----------

__global__ __launch_bounds__(256) void mw_kernel(const float* __restrict__ xout,
    const float* __restrict__ Wm, float* __restrict__ m) {
  const int row = blockIdx.x*4 + (threadIdx.x >> 6);
  const int lane = threadIdx.x & 63;
  const float* x = xout + (size_t)row*HD;
  float xv[8];
#pragma unroll
  for (int i = 0; i < 8; ++i) xv[i] = x[i*64 + lane];
#pragma unroll
  for (int p = 0; p < PP; ++p) {
    const float* wp = Wm + p*HD;
    float s = 0.f;
#pragma unroll
    for (int i = 0; i < 8; ++i) s = fmaf(xv[i], wp[i*64 + lane], s);
    s = waveSum(s);
    if (lane == 0) m[row*PP + p] = s;
  }
}

// stage 1: per-p softmax over 980 rows -> normalized weights
__global__ __launch_bounds__(256) void wsm_kernel(const float* __restrict__ m,
                                                  float* __restrict__ wsm) {
  __shared__ float red[256];
  const int p = blockIdx.x, tid = threadIdx.x;
  float lmax = -1e30f;
  for (int r = tid; r < 980; r += 256) lmax = fmaxf(lmax, m[r*PP + p]);
  red[tid] = lmax; __syncthreads();
  for (int s = 128; s; s >>= 1) { if (tid < s) red[tid] = fmaxf(red[tid], red[tid+s]); __syncthreads(); }
  const float bmax = red[0]; __syncthreads();
  float lsum = 0.f;
  for (int r = tid; r < 980; r += 256) {
    const float e = __expf(m[r*PP + p] - bmax);
    wsm[p*980 + r] = e; lsum += e;
  }
  red[tid] = lsum; __syncthreads();
  for (int s = 128; s; s >>= 1) { if (tid < s) red[tid] += red[tid+s]; __syncthreads(); }
  const float invZ = 1.f / red[0];
  for (int r = tid; r < 980; r += 256) wsm[p*980 + r] *= invZ;
}

// stage 2: split-K weighted pool
__global__ __launch_bounds__(256) void protos_part(const float* __restrict__ wsm,
    const float* __restrict__ xout, float* __restrict__ part) {
  const int p = blockIdx.y, chunk = blockIdx.x, tid = threadIdx.x;
  const int r0 = chunk*49;
  float a0 = 0.f, a1 = 0.f;
  for (int r = r0; r < r0 + 49; ++r) {
    const float w = wsm[p*980 + r];
    a0 = fmaf(w, xout[(size_t)r*HD + tid], a0);
    a1 = fmaf(w, xout[(size_t)r*HD + tid + 256], a1);
  }
  float* o = part + (((size_t)p*20 + chunk) << 9);
  o[tid] = a0;
  o[tid + 256] = a1;
}

// stage 3: reduce partials, l2-normalize
__global__ __launch_bounds__(256) void protos_fin(const float* __restrict__ part,
                                                  float* __restrict__ pn) {
  __shared__ float red[256];
  const int p = blockIdx.x, tid = threadIdx.x;
  float a0 = 0.f, a1 = 0.f;
  for (int cch = 0; cch < 20; ++cch) {
    const float* o = part + (((size_t)p*20 + cch) << 9);
    a0 += o[tid];
    a1 += o[tid + 256];
  }
  red[tid] = a0*a0 + a1*a1; __syncthreads();
  for (int s = 128; s; s >>= 1) { if (tid < s) red[tid] += red[tid+s]; __syncthreads(); }
  const float rn = 1.f / fmaxf(sqrtf(red[0]), 1e-12f);
  pn[p*HD + tid] = a0*rn;
  pn[p*HD + tid + 256] = a1*rn;
}

__global__ __launch_bounds__(256) void losses_kernel(const float* __restrict__ pn, float* __restrict__ out) {
  __shared__ float redc[256], redd[256];
  const int tid = threadIdx.x;
  float cpart = 0.f, dpart = 0.f;
  for (int d = tid; d < HD; d += 256) {
    float a[PP];
#pragma unroll
    for (int j = 0; j < PP; ++j) a[j] = pn[j*HD + d];
#pragma unroll
    for (int j = 0; j < PP; ++j) {
      if (d > j) {
#pragma unroll
        for (int i = 0; i < PP; ++i) {
          const float df = a[j] - a[i];
          const float t = 1.f - df*df;
          if (t > 0.f) dpart += t;
        }
      }
    }
#pragma unroll
    for (int j = 0; j < PP - 1; ++j) { const float df = a[j+1] - a[j]; cpart += df*df; }
  }
  redc[tid] = cpart; redd[tid] = dpart; __syncthreads();
  for (int s = 128; s; s >>= 1) {
    if (tid < s) { redc[tid] += redc[tid+s]; redd[tid] += redd[tid+s]; }
    __syncthreads();
  }
  if (tid == 0) {
    out[OUT_UPD + 1] = redc[0] / 9.f;
    out[OUT_UPD + 2] = redd[0] * (2.f / (90.f * 512.f));
  }
}

__global__ __launch_bounds__(256) void rowk(const float* __restrict__ xout, const float* __restrict__ pn,
    ushort* __restrict__ newq, float* __restrict__ feapart) {
  __shared__ float Ps[PP*HD];
  __shared__ float fred[4];
  const int tid = threadIdx.x;
  for (int idx = tid; idx < PP*HD; idx += 256) Ps[idx] = pn[idx];
  __syncthreads();
  const int row = blockIdx.x*4 + (tid >> 6);
  const int lane = tid & 63;
  const float* x = xout + (size_t)(WAYS*SEQ + row)*HD;
  float xv[8];
#pragma unroll
  for (int i = 0; i < 8; ++i) xv[i] = x[i*64 + lane];
  float sc[PP];
#pragma unroll
  for (int p = 0; p < PP; ++p) {
    float s = 0.f;
#pragma unroll
    for (int i = 0; i < 8; ++i) s = fmaf(xv[i], Ps[p*HD + i*64 + lane], s);
    sc[p] = waveSum(s);
  }
  float mx = sc[0]; int am = 0;
#pragma unroll
  for (int p = 1; p < PP; ++p) if (sc[p] > mx) { mx = sc[p]; am = p; }
  float Z = 0.f; float sp[PP];
#pragma unroll
  for (int p = 0; p < PP; ++p) { const float e = expf(sc[p] - mx); sp[p] = e; Z += e; }
  const float rz = 1.f / Z;
  float nv[8]; float ss = 0.f;
#pragma unroll
  for (int i = 0; i < 8; ++i) {
    float a = 0.f;
#pragma unroll
    for (int p = 0; p < PP; ++p) a = fmaf(sp[p], Ps[p*HD + i*64 + lane], a);
    a *= rz; nv[i] = a; ss += a*a;
  }
  ss = waveSum(ss);
  const float rn = 1.f / fmaxf(sqrtf(ss), 1e-12f);
#pragma unroll
  for (int i = 0; i < 8; ++i) newq[(size_t)row*HD + i*64 + lane] = f2bf(nv[i]*rn);
  float fp = 0.f;
#pragma unroll
  for (int i = 0; i < 8; ++i) { const float d = xv[i] - Ps[am*HD + i*64 + lane]; fp += d*d; }
  fp = waveSum(fp);
  if (lane == 0) fred[tid >> 6] = fp;
  __syncthreads();
  if (tid == 0) feapart[blockIdx.x] = fred[0] + fred[1] + fred[2] + fred[3];
}

__global__ __launch_bounds__(256) void fea_finalize(const float* __restrict__ feapart,
                                                    float* __restrict__ out) {
  __shared__ float red[256];
  float s = 0.f;
  for (int i = threadIdx.x; i < NBLK_ROWK; i += 256) s += feapart[i];
  red[threadIdx.x] = s; __syncthreads();
  for (int st = 128; st; st >>= 1) {
    if (threadIdx.x < st) red[threadIdx.x] += red[threadIdx.x + st];
    __syncthreads();
  }
  if (threadIdx.x == 0) out[OUT_UPD] = red[0] / (float)((size_t)NQB*SEQ*HD);
}

__global__ __launch_bounds__(256) void bn2_apply(const float* __restrict__ y2, const float* __restrict__ scale,
    const float* __restrict__ shift, const float* __restrict__ query, float* __restrict__ out) {
  __shared__ float tile[32][33];
  const int n = blockIdx.z, o0 = blockIdx.y*32, hw0 = blockIdx.x*32;
  const int tj = threadIdx.x & 31, ti = threadIdx.x >> 5;
#pragma unroll
  for (int it = 0; it < 4; ++it) {
    const int hw = hw0 + it*8 + ti;
    const int o = o0 + tj;
    float v = 0.f;
    if (hw < SEQ) v = fmaxf(fmaf(y2[((size_t)n*SEQ + hw)*FDIMC + o], scale[o], shift[o]), 0.f);
    tile[it*8 + ti][tj] = v;
  }
  __syncthreads();
#pragma unroll
  for (int it = 0; it < 4; ++it) {
    const int o = o0 + it*8 + ti;
    const int hw = hw0 + tj;
    if (hw < SEQ) {
      const size_t oi = ((size_t)n*FDIMC + o)*SEQ + hw;
      out[oi] = tile[tj][it*8 + ti] + query[oi];
    }
  }
}

extern "C" void kernel_launch(void* const* d_in, const int* in_sizes, int n_in,
                              void* d_out, int out_size, void* d_ws, size_t ws_size,
                              hipStream_t stream) {
  const float* key   = (const float*)d_in[0];
  const float* query = (const float*)d_in[1];
  const float* Wc    = (const float*)d_in[2];
  const float* bc    = (const float*)d_in[3];
  const float* g1    = (const float*)d_in[4];
  const float* b1    = (const float*)d_in[5];
  const float* Wq    = (const float*)d_in[6];
  const float* bq    = (const float*)d_in[7];
  const float* Wk    = (const float*)d_in[8];
  const float* bk    = (const float*)d_in[9];
  const float* Wv    = (const float*)d_in[10];
  const float* bv    = (const float*)d_in[11];
  const float* Wa    = (const float*)d_in[12];
  const float* ba    = (const float*)d_in[13];
  const float* ln_g  = (const float*)d_in[14];
  const float* ln_b  = (const float*)d_in[15];
  const float* Wm    = (const float*)d_in[16];
  const float* Wo    = (const float*)d_in[17];
  const float* bo    = (const float*)d_in[18];
  const float* g2    = (const float*)d_in[19];
  const float* b2    = (const float*)d_in[20];
  float* out = (float*)d_out;
  float* w = (float*)d_ws;

  float*  y1    = w + RB;
  ushort* P     = (ushort*)(w + RB);
  float*  y2    = w + RB;
  float*  xbuf  = w + RC;
  ushort* keyT  = (ushort*)(w + RD);
  ushort* qb    = (ushort*)(w + RD);
  float*  tmp   = w + RD;
  ushort* xbufh = (ushort*)(w + RE);
  ushort* VT    = (ushort*)(w + RE);
  float*  xout  = w + RE;
  float*  sraw  = w + RF;
  ushort* kb    = (ushort*)(w + RF);
  ushort* newq  = (ushort*)(w + RF);
  ushort* vb    = (ushort*)(w + RG);
  ushort* ctx   = (ushort*)(w + RG);
  ushort* wh    = (ushort*)(w + RH);
  float*  feapart = w + OFF_FEAP;
  float*  wsm   = w + OFF_WSM;
  float*  ppart = w + OFF_PPART;
  ushort* Wcb = wh;
  ushort* Wqb = wh + 327680;
  ushort* Wkb = wh + 589824;
  ushort* Wvb = wh + 851968;
  ushort* Wab = wh + 1114112;
  ushort* Wob = wh + 1376256;

  hipMemsetAsync(w, 0, ZERO_FLOATS*sizeof(float), stream);

  key_transpose<<<dim3(7, 20, NB), 256, 0, stream>>>(key, keyT);
  wconvert<<<6656, 256, 0, stream>>>(Wc, Wq, Wk, Wv, Wa, Wo, wh);

  // conv1 (bf16 MFMA, fused BN col-stats) + BN1 + relu
  gemm_bf<0,1><<<dim3(4, 154), 256, 0, stream>>>(keyT, Wcb, bc, y1, nullptr, M1, HD, FDIMC,
                                                 w + OFF_CS1S, w + OFF_CS1Q);
  bn_finalize<<<2, 256, 0, stream>>>(w + OFF_CS1S, w + OFF_CS1Q, g1, b1, HD, 1.f/M1,
                                     w + OFF_ST1SC, w + OFF_ST1SH);
  bn1_apply<<<M1*HD/4/256, 256, 0, stream>>>(y1, w + OFF_ST1SC, w + OFF_ST1SH, sraw, xbuf, xbufh);
  support_mean<<<WAYS*SEQ*HD/4/256, 256, 0, stream>>>(sraw, xbuf, xbufh);

  // MHA projections (bf16 out; q pre-scaled by 1/8)
  gemm_bf<2,0><<<dim3(4, 123), 256, 0, stream>>>(xbufh, Wqb, bq, nullptr, qb, MMHA, HD, HD, nullptr, nullptr);
  gemm_bf<1,0><<<dim3(4, 123), 256, 0, stream>>>(xbufh, Wkb, bk, nullptr, kb, MMHA, HD, HD, nullptr, nullptr);
  gemm_bf<1,0><<<dim3(4, 123), 256, 0, stream>>>(xbufh, Wvb, bv, nullptr, vb, MMHA, HD, HD, nullptr, nullptr);

  v_transpose<<<NMHA*8, 256, 0, stream>>>(vb, VT);
  attn_qk<<<NMHA*8, 256, 0, stream>>>(qb, kb, P);
  attn_pv<<<NMHA*8, 256, 0, stream>>>(P, VT, ctx);

  gemm_bf<0,0><<<dim3(4, 123), 256, 0, stream>>>(ctx, Wab, ba, tmp, nullptr, MMHA, HD, HD, nullptr, nullptr);
  ln_kernel<<<MMHA/4, 256, 0, stream>>>(tmp, xbuf, ln_g, ln_b, xout);

  // prototypes + losses (parallel 3-stage pooling)
  mw_kernel<<<245, 256, 0, stream>>>(xout, Wm, w + OFF_M);
  wsm_kernel<<<PP, 256, 0, stream>>>(w + OFF_M, wsm);
  protos_part<<<dim3(20, PP), 256, 0, stream>>>(wsm, xout, ppart);
  protos_fin<<<PP, 256, 0, stream>>>(ppart, w + OFF_PN);
  losses_kernel<<<1, 256, 0, stream>>>(w + OFF_PN, out);
  rowk<<<NBLK_ROWK, 256, 0, stream>>>(xout, w + OFF_PN, newq, feapart);

  // conv2 (bf16 MFMA, fused BN col-stats) + BN2 + relu + residual
  gemm_bf<0,1><<<dim3(5, 115), 256, 0, stream>>>(newq, Wob, bo, y2, nullptr, MQ, FDIMC, HD,
                                                 w + OFF_CS2S, w + OFF_CS2Q);
  bn_finalize<<<3, 256, 0, stream>>>(w + OFF_CS2S, w + OFF_CS2Q, g2, b2, FDIMC, 1.f/MQ,
                                     w + OFF_ST2SC, w + OFF_ST2SH);
  fea_finalize<<<1, 256, 0, stream>>>(feapart, out);
  bn2_apply<<<dim3(7, 20, NQB), 256, 0, stream>>>(y2, w + OFF_ST2SC, w + OFF_ST2SH, query, out);
}

// Round 7
// 381.004 us; speedup vs baseline: 4.5922x; 1.0316x over previous
//
#include <hip/hip_runtime.h>
#include <math.h>

// ---- problem constants ----
#define WAYS 5
#define SHOTS 5
#define PP 10
#define FDIMC 640
#define HD 512
#define SEQ 196
#define NB 100
#define NQB 75
#define NMHA 80
#define M1 (NB*SEQ)       // 19600
#define MMHA (NMHA*SEQ)   // 15680
#define MQ (NQB*SEQ)      // 14700
#define NBLK_ROWK (MQ/4)  // 3675
#define OUT_UPD (NQB*FDIMC*SEQ)  // 9,408,000

// ---- small stats block (float offsets) ----
#define OFF_CS1S 0
#define OFF_CS1Q 512
#define OFF_CS2S 1024
#define OFF_CS2Q 1664
#define ZERO_FLOATS 2306
#define OFF_ST1SC 2308
#define OFF_ST1SH 2820
#define OFF_ST2SC 3332
#define OFF_ST2SH 3972
#define OFF_M    4612
#define OFF_PN   14412

// ---- big regions (float offsets) ----
#define RB 20480                   /* y1h bf16 / P bf16 / y2 fp32 ; xouth at +10M */
#define RC (RB + 15439360)         /* VT bf16 */
#define RD (RC + 8028160)          /* keyT bf16 -> qb bf16 -> tmp fp32 */
#define RE (RD + 8028160)          /* xbufh bf16 */
#define RF (RE + 8028160)          /* srawh bf16 -> kb bf16 -> newq bf16 + feapart */
#define RG (RF + 4014080)          /* vb bf16 -> ctx bf16 -> wsm/ppart */
#define RH (RG + 4014080)          /* weights bf16 concat */
#define OFF_XOUT (RB + 10000000)   /* 4,014,080 floats (bf16 xout) */
#define OFF_FEAP (RF + 3763200)
#define OFF_WSM  RG
#define OFF_PPART (RG + 16384)

typedef __bf16 bf16x8 __attribute__((ext_vector_type(8)));
typedef float f32x4 __attribute__((ext_vector_type(4)));

__device__ __forceinline__ ushort f2bf(float f) {
  unsigned u = __float_as_uint(f);
  return (ushort)((u + 0x7fffu + ((u >> 16) & 1u)) >> 16);
}
__device__ __forceinline__ float bf2f(ushort u) {
  return __uint_as_float(((unsigned)u) << 16);
}

__device__ __forceinline__ f32x4 mfma16(bf16x8 a, bf16x8 b, f32x4 c) {
  return __builtin_amdgcn_mfma_f32_16x16x32_bf16(a, b, c, 0, 0, 0);
}

__device__ __forceinline__ float waveSum(float v) {
#pragma unroll
  for (int o = 32; o; o >>= 1) v += __shfl_xor(v, o, 64);
  return v;
}

// ---------- transposes / converts ----------

__global__ __launch_bounds__(256) void key_transpose(const float* __restrict__ key,
                                                     ushort* __restrict__ keyT) {
  __shared__ float T[32][33];
  const int n = blockIdx.z, c0 = blockIdx.y*32, s0 = blockIdx.x*32;
  const int tj = threadIdx.x & 31, ti = threadIdx.x >> 5;
#pragma unroll
  for (int it = 0; it < 4; ++it) {
    const int cl = it*8 + ti;
    const int s = s0 + tj;
    T[cl][tj] = (s < SEQ) ? key[((size_t)n*FDIMC + c0 + cl)*SEQ + s] : 0.f;
  }
  __syncthreads();
#pragma unroll
  for (int it = 0; it < 4; ++it) {
    const int sl = it*8 + ti;
    const int s = s0 + sl;
    if (s < SEQ) keyT[((size_t)(n*SEQ + s))*FDIMC + c0 + tj] = f2bf(T[tj][sl]);
  }
}

__global__ void wconvert(const float* __restrict__ Wc, const float* __restrict__ Wq,
                         const float* __restrict__ Wk, const float* __restrict__ Wv,
                         const float* __restrict__ Wa, const float* __restrict__ Wo,
                         ushort* __restrict__ wh) {
  const int i = blockIdx.x*256 + threadIdx.x;
  float v;
  if (i < 327680) v = Wc[i];
  else if (i < 589824) v = Wq[i - 327680];
  else if (i < 851968) v = Wk[i - 589824];
  else if (i < 1114112) v = Wv[i - 851968];
  else if (i < 1376256) v = Wa[i - 1114112];
  else v = Wo[i - 1376256];
  wh[i] = f2bf(v);
}

// ---------- bf16 MFMA GEMM: C = A(MxK) . W(NxK)^T + bias ----------
// OM: 0 -> fp32 out, 1 -> bf16 out, 2 -> bf16 out scaled by 0.125
// CS: 1 -> accumulate per-column sum/sumsq of fp32 output into gsum/gsq
template<int OM, int CS>
__global__ __launch_bounds__(256) void gemm_bf(const ushort* __restrict__ A,
    const ushort* __restrict__ W, const float* __restrict__ bias,
    float* __restrict__ Cf, ushort* __restrict__ Ch, int M, int N, int K,
    float* __restrict__ gsum, float* __restrict__ gsq) {
  __shared__ ushort As[128*32];
  __shared__ ushort Bs[128*32];
  __shared__ float csum[128], csq[128];
  const int tid = threadIdx.x;
  const int m0 = blockIdx.y*128, n0 = blockIdx.x*128;
  const int w = tid >> 6, lane = tid & 63;
  const int wr = w >> 1, wc = w & 1;
  const int g = lane >> 4, c = lane & 15;

  const int ch0 = tid, ch1 = 256 + tid;
  const int ar0 = ch0 >> 2, ar1 = ch1 >> 2;
  const int ak0 = (ch0 & 3) * 8, ak1 = (ch1 & 3) * 8;
  int gr0 = m0 + ar0; if (gr0 > M-1) gr0 = M-1;
  int gr1 = m0 + ar1; if (gr1 > M-1) gr1 = M-1;
  const ushort* Ap0 = A + (size_t)gr0*K + ak0;
  const ushort* Ap1 = A + (size_t)gr1*K + ak1;
  const ushort* Wp0 = W + (size_t)(n0 + ar0)*K + ak0;
  const ushort* Wp1 = W + (size_t)(n0 + ar1)*K + ak1;

  f32x4 acc[4][4];
#pragma unroll
  for (int i = 0; i < 4; ++i)
#pragma unroll
    for (int j = 0; j < 4; ++j) acc[i][j] = (f32x4)(0.0f);

  for (int k0 = 0; k0 < K; k0 += 32) {
    const uint4 a0 = *(const uint4*)(Ap0 + k0);
    const uint4 a1 = *(const uint4*)(Ap1 + k0);
    const uint4 b0 = *(const uint4*)(Wp0 + k0);
    const uint4 b1 = *(const uint4*)(Wp1 + k0);
    __syncthreads();
    *(uint4*)(&As[ch0*8]) = a0;
    *(uint4*)(&As[ch1*8]) = a1;
    *(uint4*)(&Bs[ch0*8]) = b0;
    *(uint4*)(&Bs[ch1*8]) = b1;
    __syncthreads();
    bf16x8 af[4], bfr[4];
#pragma unroll
    for (int mi = 0; mi < 4; ++mi)
      af[mi] = *(const bf16x8*)(&As[(wr*64 + mi*16 + c)*32 + g*8]);
#pragma unroll
    for (int ni = 0; ni < 4; ++ni)
      bfr[ni] = *(const bf16x8*)(&Bs[(wc*64 + ni*16 + c)*32 + g*8]);
#pragma unroll
    for (int mi = 0; mi < 4; ++mi)
#pragma unroll
      for (int ni = 0; ni < 4; ++ni)
        acc[mi][ni] = mfma16(af[mi], bfr[ni], acc[mi][ni]);
  }

  if (CS) {
    __syncthreads();
    if (tid < 128) { csum[tid] = 0.f; csq[tid] = 0.f; }
    __syncthreads();
  }

#pragma unroll
  for (int ni = 0; ni < 4; ++ni) {
    const int col = n0 + wc*64 + ni*16 + c;
    const float bb = bias[col];
    float ls = 0.f, lq = 0.f;
#pragma unroll
    for (int mi = 0; mi < 4; ++mi) {
#pragma unroll
      for (int q = 0; q < 4; ++q) {
        const int row = m0 + wr*64 + mi*16 + g*4 + q;
        if (row < M) {
          const float v = acc[mi][ni][q] + bb;
          if (OM == 0) Cf[(size_t)row*N + col] = v;
          else if (OM == 1) Ch[(size_t)row*N + col] = f2bf(v);
          else Ch[(size_t)row*N + col] = f2bf(v*0.125f);
          if (CS) { ls += v; lq += v*v; }
        }
      }
    }
    if (CS) {
      const int lcol = wc*64 + ni*16 + c;
      atomicAdd(&csum[lcol], ls);
      atomicAdd(&csq[lcol], lq);
    }
  }
  if (CS) {
    __syncthreads();
    if (tid < 128) {
      atomicAdd(&gsum[n0 + tid], csum[tid]);
      atomicAdd(&gsq[n0 + tid], csq[tid]);
    }
  }
}

// ---------- BN pieces ----------

__global__ void bn_finalize(const float* __restrict__ sums, const float* __restrict__ sumsq,
    const float* __restrict__ g, const float* __restrict__ b, int C, float invM,
    float* __restrict__ scale, float* __restrict__ shift) {
  const int c = blockIdx.x*256 + threadIdx.x;
  if (c >= C) return;
  const float mu = sums[c]*invM;
  const float var = sumsq[c]*invM - mu*mu;
  const float sc = rsqrtf(var + 1e-5f) * g[c];
  scale[c] = sc;
  shift[c] = b[c] - mu*sc;
}

// BN1 apply + relu on bf16; route first 25 batches -> srawh, rest -> xbufh[5..79]
__global__ __launch_bounds__(256) void bn1_apply(const ushort* __restrict__ y1,
    const float* __restrict__ scale, const float* __restrict__ shift,
    ushort* __restrict__ srawh, ushort* __restrict__ xbufh) {
  const int i8 = blockIdx.x*256 + threadIdx.x;
  if (i8 >= M1*HD/8) return;
  const int e = i8 << 3;
  const int col = e & (HD - 1);
  const uint4 raw = ((const uint4*)y1)[i8];
  unsigned rw[4] = {raw.x, raw.y, raw.z, raw.w};
  unsigned res[4];
#pragma unroll
  for (int j = 0; j < 4; ++j) {
    float v0 = bf2f((ushort)(rw[j] & 0xffffu));
    float v1 = bf2f((ushort)(rw[j] >> 16));
    v0 = fmaxf(fmaf(v0, scale[col + 2*j],     shift[col + 2*j]),     0.f);
    v1 = fmaxf(fmaf(v1, scale[col + 2*j + 1], shift[col + 2*j + 1]), 0.f);
    res[j] = (unsigned)f2bf(v0) | ((unsigned)f2bf(v1) << 16);
  }
  const uint4 o = make_uint4(res[0], res[1], res[2], res[3]);
  if (e < 25*SEQ*HD) ((uint4*)srawh)[i8] = o;
  else ((uint4*)xbufh)[i8 - (20*SEQ*HD/8)] = o;
}

__global__ void support_mean(const ushort* __restrict__ srawh, ushort* __restrict__ xbufh) {
  const int i8 = blockIdx.x*256 + threadIdx.x;
  if (i8 >= WAYS*SEQ*HD/8) return;
  const int e = i8 << 3;
  const int w = e / (SEQ*HD);
  const int rem = e - w*(SEQ*HD);
  float acc[8] = {};
#pragma unroll
  for (int s = 0; s < SHOTS; ++s) {
    const uint4 v = *(const uint4*)(srawh + (size_t)(s*WAYS + w)*(SEQ*HD) + rem);
    const unsigned rw[4] = {v.x, v.y, v.z, v.w};
#pragma unroll
    for (int j = 0; j < 4; ++j) {
      acc[2*j]   += bf2f((ushort)(rw[j] & 0xffffu));
      acc[2*j+1] += bf2f((ushort)(rw[j] >> 16));
    }
  }
  unsigned res[4];
#pragma unroll
  for (int j = 0; j < 4; ++j)
    res[j] = (unsigned)f2bf(acc[2*j]*0.2f) | ((unsigned)f2bf(acc[2*j+1]*0.2f) << 16);
  ((uint4*)xbufh)[i8] = make_uint4(res[0], res[1], res[2], res[3]);
}

// ---------- attention: QK^T + softmax -> P bf16 [bh][208][232] ----------

__global__ __launch_bounds__(256) void attn_qk(const ushort* __restrict__ qb,
    const ushort* __restrict__ kb, ushort* __restrict__ P) {
  __shared__ ushort Ks[208*72];
  const int bh = blockIdx.x, b = bh >> 3, h = bh & 7;
  const int tid = threadIdx.x;
  for (int idx = tid; idx < 208*8; idx += 256) {
    const int row = idx >> 3, part = idx & 7;
    uint4 v = make_uint4(0u,0u,0u,0u);
    if (row < SEQ) v = *(const uint4*)(kb + ((size_t)(b*SEQ + row))*HD + h*64 + part*8);
    *(uint4*)(&Ks[row*72 + part*8]) = v;
  }
  __syncthreads();
  const int w = tid >> 6, lane = tid & 63, g = lane >> 4, c = lane & 15;
  for (int rt = w; rt < 13; rt += 4) {
    int qrow = b*SEQ + rt*16 + c; if (qrow > MMHA-1) qrow = MMHA-1;
    const bf16x8 aq0 = *(const bf16x8*)(qb + (size_t)qrow*HD + h*64 + g*8);
    const bf16x8 aq1 = *(const bf16x8*)(qb + (size_t)qrow*HD + h*64 + 32 + g*8);
    f32x4 acc[13];
#pragma unroll
    for (int ct = 0; ct < 13; ++ct) acc[ct] = (f32x4)(0.0f);
#pragma unroll
    for (int ct = 0; ct < 13; ++ct) {
      const bf16x8 b0 = *(const bf16x8*)(&Ks[(ct*16 + c)*72 + g*8]);
      const bf16x8 b1 = *(const bf16x8*)(&Ks[(ct*16 + c)*72 + 32 + g*8]);
      acc[ct] = mfma16(aq0, b0, acc[ct]);
      acc[ct] = mfma16(aq1, b1, acc[ct]);
    }
    if (c >= 4) acc[12] = (f32x4)(-1e30f);
    float mrow[4], Z[4];
#pragma unroll
    for (int q = 0; q < 4; ++q) {
      float mx = acc[0][q];
#pragma unroll
      for (int ct = 1; ct < 13; ++ct) mx = fmaxf(mx, acc[ct][q]);
      mrow[q] = mx;
    }
#pragma unroll
    for (int q = 0; q < 4; ++q) {
#pragma unroll
      for (int msk = 1; msk < 16; msk <<= 1)
        mrow[q] = fmaxf(mrow[q], __shfl_xor(mrow[q], msk, 64));
    }
#pragma unroll
    for (int q = 0; q < 4; ++q) Z[q] = 0.f;
#pragma unroll
    for (int ct = 0; ct < 13; ++ct)
#pragma unroll
      for (int q = 0; q < 4; ++q) {
        const float e = __expf(acc[ct][q] - mrow[q]);
        acc[ct][q] = e; Z[q] += e;
      }
#pragma unroll
    for (int q = 0; q < 4; ++q) {
#pragma unroll
      for (int msk = 1; msk < 16; msk <<= 1) Z[q] += __shfl_xor(Z[q], msk, 64);
      Z[q] = 1.f / Z[q];
    }
    const size_t pb = (size_t)bh*(208*232);
#pragma unroll
    for (int q = 0; q < 4; ++q) {
      ushort* pr = P + pb + (size_t)(rt*16 + g*4 + q)*232;
#pragma unroll
      for (int ct = 0; ct < 13; ++ct) pr[ct*16 + c] = f2bf(acc[ct][q]*Z[q]);
      pr[208 + c] = 0;
      if (c < 8) pr[224 + c] = 0;
    }
  }
}

// ---------- V transpose ----------

__global__ __launch_bounds__(256) void v_transpose(const ushort* __restrict__ vb,
                                                   ushort* __restrict__ VT) {
  __shared__ ushort Vs[196*72];
  const int bh = blockIdx.x, b = bh >> 3, h = bh & 7;
  const int tid = threadIdx.x;
  for (int idx = tid; idx < 196*8; idx += 256) {
    const int row = idx >> 3, part = idx & 7;
    *(uint4*)(&Vs[row*72 + part*8]) =
        *(const uint4*)(vb + ((size_t)(b*SEQ + row))*HD + h*64 + part*8);
  }
  __syncthreads();
  ushort* o = VT + (size_t)bh*64*224;
  for (int idx = tid; idx < 64*224; idx += 256) {
    const int d = idx/224, s = idx - d*224;
    o[idx] = (s < SEQ) ? Vs[s*72 + d] : (ushort)0;
  }
}

// ---------- P.V ----------

__global__ __launch_bounds__(256) void attn_pv(const ushort* __restrict__ P,
    const ushort* __restrict__ VT, ushort* __restrict__ ctx) {
  __shared__ ushort Ps[112*232];
  const int bh = blockIdx.x, b = bh >> 3, h = bh & 7;
  const int tid = threadIdx.x, w = tid >> 6, lane = tid & 63, g = lane >> 4, c = lane & 15;
  bf16x8 bv[7];
  const ushort* vt = VT + (size_t)bh*64*224 + (size_t)(w*16 + c)*224;
#pragma unroll
  for (int ks = 0; ks < 7; ++ks) bv[ks] = *(const bf16x8*)(vt + ks*32 + g*8);
  const char* pg = (const char*)(P + (size_t)bh*(208*232));
#pragma unroll
  for (int half = 0; half < 2; ++half) {
    const int r0 = half ? 112 : 0;
    const int nbytes = half ? 96*464 : 112*464;
    __syncthreads();
    for (int byte = tid*16; byte < nbytes; byte += 4096)
      *(uint4*)((char*)Ps + byte) = *(const uint4*)(pg + r0*464 + byte);
    __syncthreads();
    const int rtlo = half ? 7 : 0, rthi = half ? 13 : 7;
    for (int rt = rtlo; rt < rthi; ++rt) {
      const int lrow = rt*16 - r0 + c;
      f32x4 acc = (f32x4)(0.0f);
#pragma unroll
      for (int ks = 0; ks < 7; ++ks) {
        const bf16x8 a = *(const bf16x8*)(&Ps[lrow*232 + ks*32 + g*8]);
        acc = mfma16(a, bv[ks], acc);
      }
#pragma unroll
      for (int q = 0; q < 4; ++q) {
        const int srow = rt*16 + g*4 + q;
        if (srow < SEQ)
          ctx[((size_t)(b*SEQ + srow))*HD + h*64 + w*16 + c] = f2bf(acc[q]);
      }
    }
  }
}

// ---------- LayerNorm + residual (tmp fp32 + xin bf16 -> bf16) ----------

__global__ __launch_bounds__(256) void ln_kernel(const float* __restrict__ tmp,
    const ushort* __restrict__ xin, const float* __restrict__ g,
    const float* __restrict__ bta, ushort* __restrict__ outh) {
  const int row = blockIdx.x*4 + (threadIdx.x >> 6);
  const int lane = threadIdx.x & 63;
  const float* t = tmp + (size_t)row*HD;
  const ushort* x = xin + (size_t)row*HD;
  float v[8]; float s = 0.f;
#pragma unroll
  for (int i = 0; i < 8; ++i) {
    const float val = t[i*64 + lane] + bf2f(x[i*64 + lane]);
    v[i] = val; s += val;
  }
  s = waveSum(s);
  const float mu = s * (1.f/HD);
  float sq = 0.f;
#pragma unroll
  for (int i = 0; i < 8; ++i) { const float d = v[i] - mu; sq += d*d; }
  sq = waveSum(sq);
  const float istd = rsqrtf(sq*(1.f/HD) + 1e-5f);
#pragma unroll
  for (int i = 0; i < 8; ++i) {
    const int d = i*64 + lane;
    outh[(size_t)row*HD + d] = f2bf((v[i] - mu)*istd*g[d] + bta[d]);
  }
}

// ---------- prototypes / losses / per-row ----------

__global__ __launch_bounds__(256) void mw_kernel(const ushort* __restrict__ xout,
    const float* __restrict__ Wm, float* __restrict__ m) {
  const int row = blockIdx.x*4 + (threadIdx.x >> 6);
  const int lane = threadIdx.x & 63;
  const ushort* x = xout + (size_t)row*HD;
  float xv[8];
#pragma unroll
  for (int i = 0; i < 8; ++i) xv[i] = bf2f(x[i*64 + lane]);
#pragma unroll
  for (int p = 0; p < PP; ++p) {
    const float* wp = Wm + p*HD;
    float s = 0.f;
#pragma unroll
    for (int i = 0; i < 8; ++i) s = fmaf(xv[i], wp[i*64 + lane], s);
    s = waveSum(s);
    if (lane == 0) m[row*PP + p] = s;
  }
}

__global__ __launch_bounds__(256) void wsm_kernel(const float* __restrict__ m,
                                                  float* __restrict__ wsm) {
  __shared__ float red[256];
  const int p = blockIdx.x, tid = threadIdx.x;
  float lmax = -1e30f;
  for (int r = tid; r < 980; r += 256) lmax = fmaxf(lmax, m[r*PP + p]);
  red[tid] = lmax; __syncthreads();
  for (int s = 128; s; s >>= 1) { if (tid < s) red[tid] = fmaxf(red[tid], red[tid+s]); __syncthreads(); }
  const float bmax = red[0]; __syncthreads();
  float lsum = 0.f;
  for (int r = tid; r < 980; r += 256) {
    const float e = __expf(m[r*PP + p] - bmax);
    wsm[p*980 + r] = e; lsum += e;
  }
  red[tid] = lsum; __syncthreads();
  for (int s = 128; s; s >>= 1) { if (tid < s) red[tid] += red[tid+s]; __syncthreads(); }
  const float invZ = 1.f / red[0];
  for (int r = tid; r < 980; r += 256) wsm[p*980 + r] *= invZ;
}

__global__ __launch_bounds__(256) void protos_part(const float* __restrict__ wsm,
    const ushort* __restrict__ xout, float* __restrict__ part) {
  const int p = blockIdx.y, chunk = blockIdx.x, tid = threadIdx.x;
  const int r0 = chunk*49;
  float a0 = 0.f, a1 = 0.f;
  for (int r = r0; r < r0 + 49; ++r) {
    const float w = wsm[p*980 + r];
    a0 = fmaf(w, bf2f(xout[(size_t)r*HD + tid]), a0);
    a1 = fmaf(w, bf2f(xout[(size_t)r*HD + tid + 256]), a1);
  }
  float* o = part + (((size_t)p*20 + chunk) << 9);
  o[tid] = a0;
  o[tid + 256] = a1;
}

__global__ __launch_bounds__(256) void protos_fin(const float* __restrict__ part,
                                                  float* __restrict__ pn) {
  __shared__ float red[256];
  const int p = blockIdx.x, tid = threadIdx.x;
  float a0 = 0.f, a1 = 0.f;
  for (int cch = 0; cch < 20; ++cch) {
    const float* o = part + (((size_t)p*20 + cch) << 9);
    a0 += o[tid];
    a1 += o[tid + 256];
  }
  red[tid] = a0*a0 + a1*a1; __syncthreads();
  for (int s = 128; s; s >>= 1) { if (tid < s) red[tid] += red[tid+s]; __syncthreads(); }
  const float rn = 1.f / fmaxf(sqrtf(red[0]), 1e-12f);
  pn[p*HD + tid] = a0*rn;
  pn[p*HD + tid + 256] = a1*rn;
}

__global__ __launch_bounds__(256) void losses_kernel(const float* __restrict__ pn, float* __restrict__ out) {
  __shared__ float redc[256], redd[256];
  const int tid = threadIdx.x;
  float cpart = 0.f, dpart = 0.f;
  for (int d = tid; d < HD; d += 256) {
    float a[PP];
#pragma unroll
    for (int j = 0; j < PP; ++j) a[j] = pn[j*HD + d];
#pragma unroll
    for (int j = 0; j < PP; ++j) {
      if (d > j) {
#pragma unroll
        for (int i = 0; i < PP; ++i) {
          const float df = a[j] - a[i];
          const float t = 1.f - df*df;
          if (t > 0.f) dpart += t;
        }
      }
    }
#pragma unroll
    for (int j = 0; j < PP - 1; ++j) { const float df = a[j+1] - a[j]; cpart += df*df; }
  }
  redc[tid] = cpart; redd[tid] = dpart; __syncthreads();
  for (int s = 128; s; s >>= 1) {
    if (tid < s) { redc[tid] += redc[tid+s]; redd[tid] += redd[tid+s]; }
    __syncthreads();
  }
  if (tid == 0) {
    out[OUT_UPD + 1] = redc[0] / 9.f;
    out[OUT_UPD + 2] = redd[0] * (2.f / (90.f * 512.f));
  }
}

__global__ __launch_bounds__(256) void rowk(const ushort* __restrict__ xout, const float* __restrict__ pn,
    ushort* __restrict__ newq, float* __restrict__ feapart) {
  __shared__ float Ps[PP*HD];
  __shared__ float fred[4];
  const int tid = threadIdx.x;
  for (int idx = tid; idx < PP*HD; idx += 256) Ps[idx] = pn[idx];
  __syncthreads();
  const int row = blockIdx.x*4 + (tid >> 6);
  const int lane = tid & 63;
  const ushort* x = xout + (size_t)(WAYS*SEQ + row)*HD;
  float xv[8];
#pragma unroll
  for (int i = 0; i < 8; ++i) xv[i] = bf2f(x[i*64 + lane]);
  float sc[PP];
#pragma unroll
  for (int p = 0; p < PP; ++p) {
    float s = 0.f;
#pragma unroll
    for (int i = 0; i < 8; ++i) s = fmaf(xv[i], Ps[p*HD + i*64 + lane], s);
    sc[p] = waveSum(s);
  }
  float mx = sc[0]; int am = 0;
#pragma unroll
  for (int p = 1; p < PP; ++p) if (sc[p] > mx) { mx = sc[p]; am = p; }
  float Z = 0.f; float sp[PP];
#pragma unroll
  for (int p = 0; p < PP; ++p) { const float e = expf(sc[p] - mx); sp[p] = e; Z += e; }
  const float rz = 1.f / Z;
  float nv[8]; float ss = 0.f;
#pragma unroll
  for (int i = 0; i < 8; ++i) {
    float a = 0.f;
#pragma unroll
    for (int p = 0; p < PP; ++p) a = fmaf(sp[p], Ps[p*HD + i*64 + lane], a);
    a *= rz; nv[i] = a; ss += a*a;
  }
  ss = waveSum(ss);
  const float rn = 1.f / fmaxf(sqrtf(ss), 1e-12f);
#pragma unroll
  for (int i = 0; i < 8; ++i) newq[(size_t)row*HD + i*64 + lane] = f2bf(nv[i]*rn);
  float fp = 0.f;
#pragma unroll
  for (int i = 0; i < 8; ++i) { const float d = xv[i] - Ps[am*HD + i*64 + lane]; fp += d*d; }
  fp = waveSum(fp);
  if (lane == 0) fred[tid >> 6] = fp;
  __syncthreads();
  if (tid == 0) feapart[blockIdx.x] = fred[0] + fred[1] + fred[2] + fred[3];
}

__global__ __launch_bounds__(256) void fea_finalize(const float* __restrict__ feapart,
                                                    float* __restrict__ out) {
  __shared__ float red[256];
  float s = 0.f;
  for (int i = threadIdx.x; i < NBLK_ROWK; i += 256) s += feapart[i];
  red[threadIdx.x] = s; __syncthreads();
  for (int st = 128; st; st >>= 1) {
    if (threadIdx.x < st) red[threadIdx.x] += red[threadIdx.x + st];
    __syncthreads();
  }
  if (threadIdx.x == 0) out[OUT_UPD] = red[0] / (float)((size_t)NQB*SEQ*HD);
}

__global__ __launch_bounds__(256) void bn2_apply(const float* __restrict__ y2, const float* __restrict__ scale,
    const float* __restrict__ shift, const float* __restrict__ query, float* __restrict__ out) {
  __shared__ float tile[32][33];
  const int n = blockIdx.z, o0 = blockIdx.y*32, hw0 = blockIdx.x*32;
  const int tj = threadIdx.x & 31, ti = threadIdx.x >> 5;
#pragma unroll
  for (int it = 0; it < 4; ++it) {
    const int hw = hw0 + it*8 + ti;
    const int o = o0 + tj;
    float v = 0.f;
    if (hw < SEQ) v = fmaxf(fmaf(y2[((size_t)n*SEQ + hw)*FDIMC + o], scale[o], shift[o]), 0.f);
    tile[it*8 + ti][tj] = v;
  }
  __syncthreads();
#pragma unroll
  for (int it = 0; it < 4; ++it) {
    const int o = o0 + it*8 + ti;
    const int hw = hw0 + tj;
    if (hw < SEQ) {
      const size_t oi = ((size_t)n*FDIMC + o)*SEQ + hw;
      out[oi] = tile[tj][it*8 + ti] + query[oi];
    }
  }
}

extern "C" void kernel_launch(void* const* d_in, const int* in_sizes, int n_in,
                              void* d_out, int out_size, void* d_ws, size_t ws_size,
                              hipStream_t stream) {
  const float* key   = (const float*)d_in[0];
  const float* query = (const float*)d_in[1];
  const float* Wc    = (const float*)d_in[2];
  const float* bc    = (const float*)d_in[3];
  const float* g1    = (const float*)d_in[4];
  const float* b1    = (const float*)d_in[5];
  const float* Wq    = (const float*)d_in[6];
  const float* bq    = (const float*)d_in[7];
  const float* Wk    = (const float*)d_in[8];
  const float* bk    = (const float*)d_in[9];
  const float* Wv    = (const float*)d_in[10];
  const float* bv    = (const float*)d_in[11];
  const float* Wa    = (const float*)d_in[12];
  const float* ba    = (const float*)d_in[13];
  const float* ln_g  = (const float*)d_in[14];
  const float* ln_b  = (const float*)d_in[15];
  const float* Wm    = (const float*)d_in[16];
  const float* Wo    = (const float*)d_in[17];
  const float* bo    = (const float*)d_in[18];
  const float* g2    = (const float*)d_in[19];
  const float* b2    = (const float*)d_in[20];
  float* out = (float*)d_out;
  float* w = (float*)d_ws;

  ushort* y1h   = (ushort*)(w + RB);
  ushort* P     = (ushort*)(w + RB);
  float*  y2f   = w + RB;
  ushort* xouth = (ushort*)(w + OFF_XOUT);
  ushort* VT    = (ushort*)(w + RC);
  ushort* keyT  = (ushort*)(w + RD);
  ushort* qb    = (ushort*)(w + RD);
  float*  tmpf  = w + RD;
  ushort* xbufh = (ushort*)(w + RE);
  ushort* srawh = (ushort*)(w + RF);
  ushort* kb    = (ushort*)(w + RF);
  ushort* newq  = (ushort*)(w + RF);
  ushort* vb    = (ushort*)(w + RG);
  ushort* ctx   = (ushort*)(w + RG);
  ushort* wh    = (ushort*)(w + RH);
  float*  feapart = w + OFF_FEAP;
  float*  wsm   = w + OFF_WSM;
  float*  ppart = w + OFF_PPART;
  ushort* Wcb = wh;
  ushort* Wqb = wh + 327680;
  ushort* Wkb = wh + 589824;
  ushort* Wvb = wh + 851968;
  ushort* Wab = wh + 1114112;
  ushort* Wob = wh + 1376256;

  hipMemsetAsync(w, 0, ZERO_FLOATS*sizeof(float), stream);

  key_transpose<<<dim3(7, 20, NB), 256, 0, stream>>>(key, keyT);
  wconvert<<<6656, 256, 0, stream>>>(Wc, Wq, Wk, Wv, Wa, Wo, wh);

  // conv1 (bf16 MFMA, fused BN col-stats from fp32 acc) -> y1h bf16
  gemm_bf<1,1><<<dim3(4, 154), 256, 0, stream>>>(keyT, Wcb, bc, nullptr, y1h, M1, HD, FDIMC,
                                                 w + OFF_CS1S, w + OFF_CS1Q);
  bn_finalize<<<2, 256, 0, stream>>>(w + OFF_CS1S, w + OFF_CS1Q, g1, b1, HD, 1.f/M1,
                                     w + OFF_ST1SC, w + OFF_ST1SH);
  bn1_apply<<<M1*HD/8/256, 256, 0, stream>>>(y1h, w + OFF_ST1SC, w + OFF_ST1SH, srawh, xbufh);
  support_mean<<<WAYS*SEQ*HD/8/256, 256, 0, stream>>>(srawh, xbufh);

  // MHA projections (bf16 out; q pre-scaled by 1/8)
  gemm_bf<2,0><<<dim3(4, 123), 256, 0, stream>>>(xbufh, Wqb, bq, nullptr, qb, MMHA, HD, HD, nullptr, nullptr);
  gemm_bf<1,0><<<dim3(4, 123), 256, 0, stream>>>(xbufh, Wkb, bk, nullptr, kb, MMHA, HD, HD, nullptr, nullptr);
  gemm_bf<1,0><<<dim3(4, 123), 256, 0, stream>>>(xbufh, Wvb, bv, nullptr, vb, MMHA, HD, HD, nullptr, nullptr);

  v_transpose<<<NMHA*8, 256, 0, stream>>>(vb, VT);
  attn_qk<<<NMHA*8, 256, 0, stream>>>(qb, kb, P);
  attn_pv<<<NMHA*8, 256, 0, stream>>>(P, VT, ctx);

  // out-proj -> tmp fp32 (precision-critical: pre-LN residual path)
  gemm_bf<0,0><<<dim3(4, 123), 256, 0, stream>>>(ctx, Wab, ba, tmpf, nullptr, MMHA, HD, HD, nullptr, nullptr);
  ln_kernel<<<MMHA/4, 256, 0, stream>>>(tmpf, xbufh, ln_g, ln_b, xouth);

  // prototypes + losses
  mw_kernel<<<245, 256, 0, stream>>>(xouth, Wm, w + OFF_M);
  wsm_kernel<<<PP, 256, 0, stream>>>(w + OFF_M, wsm);
  protos_part<<<dim3(20, PP), 256, 0, stream>>>(wsm, xouth, ppart);
  protos_fin<<<PP, 256, 0, stream>>>(ppart, w + OFF_PN);
  losses_kernel<<<1, 256, 0, stream>>>(w + OFF_PN, out);
  rowk<<<NBLK_ROWK, 256, 0, stream>>>(xouth, w + OFF_PN, newq, feapart);

  // conv2 -> y2 fp32 (precision-critical: pre-BN2 output path), fused BN col-stats
  gemm_bf<0,1><<<dim3(5, 115), 256, 0, stream>>>(newq, Wob, bo, y2f, nullptr, MQ, FDIMC, HD,
                                                 w + OFF_CS2S, w + OFF_CS2Q);
  bn_finalize<<<3, 256, 0, stream>>>(w + OFF_CS2S, w + OFF_CS2Q, g2, b2, FDIMC, 1.f/MQ,
                                     w + OFF_ST2SC, w + OFF_ST2SH);
  fea_finalize<<<1, 256, 0, stream>>>(feapart, out);
  bn2_apply<<<dim3(7, 20, NQB), 256, 0, stream>>>(y2f, w + OFF_ST2SC, w + OFF_ST2SH, query, out);
}

// Round 8
// 370.428 us; speedup vs baseline: 4.7233x; 1.0286x over previous
//
#include <hip/hip_runtime.h>
#include <math.h>

// ---- problem constants ----
#define WAYS 5
#define SHOTS 5
#define PP 10
#define FDIMC 640
#define HD 512
#define SEQ 196
#define NB 100
#define NQB 75
#define NMHA 80
#define M1 (NB*SEQ)       // 19600
#define MMHA (NMHA*SEQ)   // 15680
#define MQ (NQB*SEQ)      // 14700
#define NBLK_ROWK (MQ/4)  // 3675
#define OUT_UPD (NQB*FDIMC*SEQ)  // 9,408,000

// ---- small stats block (float offsets) ----
#define OFF_CS1S 0
#define OFF_CS1Q 512
#define OFF_CS2S 1024
#define OFF_CS2Q 1664
#define ZERO_FLOATS 2306
#define OFF_ST1SC 2308
#define OFF_ST1SH 2820
#define OFF_ST2SC 3332
#define OFF_ST2SH 3972
#define OFF_M    4612
#define OFF_PN   14412

// ---- big regions (float offsets) ----
#define RB 20480                   /* y1h bf16 / P bf16 / y2 fp32 ; xouth at +10M */
#define RC (RB + 15439360)         /* VT bf16 */
#define RD (RC + 8028160)          /* keyT bf16 -> qb bf16 -> tmp fp32 */
#define RE (RD + 8028160)          /* xbufh bf16 */
#define RF (RE + 8028160)          /* srawh bf16 -> kb bf16 -> newq bf16 + feapart */
#define RG (RF + 4014080)          /* vb bf16 -> ctx bf16 -> wsm/ppart */
#define RH (RG + 4014080)          /* weights bf16 concat */
#define OFF_XOUT (RB + 10000000)   /* bf16 xout */
#define OFF_FEAP (RF + 3763200)
#define OFF_WSM  RG
#define OFF_PPART (RG + 16384)

typedef __bf16 bf16x8 __attribute__((ext_vector_type(8)));
typedef float f32x4 __attribute__((ext_vector_type(4)));

__device__ __forceinline__ ushort f2bf(float f) {
  unsigned u = __float_as_uint(f);
  return (ushort)((u + 0x7fffu + ((u >> 16) & 1u)) >> 16);
}
__device__ __forceinline__ float bf2f(ushort u) {
  return __uint_as_float(((unsigned)u) << 16);
}

__device__ __forceinline__ f32x4 mfma16(bf16x8 a, bf16x8 b, f32x4 c) {
  return __builtin_amdgcn_mfma_f32_16x16x32_bf16(a, b, c, 0, 0, 0);
}

__device__ __forceinline__ float waveSum(float v) {
#pragma unroll
  for (int o = 32; o; o >>= 1) v += __shfl_xor(v, o, 64);
  return v;
}

// async global -> LDS, 16 B per lane (wave-uniform LDS base + lane*16)
__device__ __forceinline__ void gld16(const void* g, void* l) {
  __builtin_amdgcn_global_load_lds(
      (const __attribute__((address_space(1))) void*)g,
      (__attribute__((address_space(3))) void*)l,
      16, 0, 0);
}

// ---------- transposes / converts ----------

__global__ __launch_bounds__(256) void key_transpose(const float* __restrict__ key,
                                                     ushort* __restrict__ keyT) {
  __shared__ float T[32][33];
  const int n = blockIdx.z, c0 = blockIdx.y*32, s0 = blockIdx.x*32;
  const int tj = threadIdx.x & 31, ti = threadIdx.x >> 5;
#pragma unroll
  for (int it = 0; it < 4; ++it) {
    const int cl = it*8 + ti;
    const int s = s0 + tj;
    T[cl][tj] = (s < SEQ) ? key[((size_t)n*FDIMC + c0 + cl)*SEQ + s] : 0.f;
  }
  __syncthreads();
#pragma unroll
  for (int it = 0; it < 4; ++it) {
    const int sl = it*8 + ti;
    const int s = s0 + sl;
    if (s < SEQ) keyT[((size_t)(n*SEQ + s))*FDIMC + c0 + tj] = f2bf(T[tj][sl]);
  }
}

__global__ void wconvert(const float* __restrict__ Wc, const float* __restrict__ Wq,
                         const float* __restrict__ Wk, const float* __restrict__ Wv,
                         const float* __restrict__ Wa, const float* __restrict__ Wo,
                         ushort* __restrict__ wh) {
  const int i = blockIdx.x*256 + threadIdx.x;
  float v;
  if (i < 327680) v = Wc[i];
  else if (i < 589824) v = Wq[i - 327680];
  else if (i < 851968) v = Wk[i - 589824];
  else if (i < 1114112) v = Wv[i - 851968];
  else if (i < 1376256) v = Wa[i - 1114112];
  else v = Wo[i - 1376256];
  wh[i] = f2bf(v);
}

// ---------- bf16 MFMA GEMM: C = A(MxK) . W(NxK)^T + bias ----------
// OM: 0 -> fp32 out, 1 -> bf16 out, 2 -> bf16 out scaled by 0.125
// CS: 1 -> accumulate per-column sum/sumsq of fp32 output into gsum/gsq
// Staging: global_load_lds width-16 (4 per thread per K-step), 2-barrier loop.
// Block-id: bijective XCD-aware swizzle (A-panel L2 co-location).
template<int OM, int CS>
__global__ __launch_bounds__(256) void gemm_bf(const ushort* __restrict__ A,
    const ushort* __restrict__ W, const float* __restrict__ bias,
    float* __restrict__ Cf, ushort* __restrict__ Ch, int M, int N, int K,
    float* __restrict__ gsum, float* __restrict__ gsq) {
  __shared__ ushort As[128*32];
  __shared__ ushort Bs[128*32];
  __shared__ float csum[128], csq[128];
  const int tid = threadIdx.x;

  // XCD-aware bijective swizzle (m204): flat -> chunked per-XCD
  const int nwg = gridDim.x * gridDim.y;
  int flat = blockIdx.y * gridDim.x + blockIdx.x;
  {
    const int q = nwg >> 3, r = nwg & 7;
    const int j = flat & 7, t = flat >> 3;
    flat = (j < r ? j*(q+1) : r*(q+1) + (j-r)*q) + t;
  }
  const int m0 = (flat / gridDim.x) * 128;
  const int n0 = (flat % gridDim.x) * 128;

  const int w = tid >> 6, lane = tid & 63;
  const int wr = w >> 1, wc = w & 1;
  const int g = lane >> 4, c = lane & 15;

  // staging: wave w owns chunks {w, 4+w} of As and Bs (1024 B each)
  const int srow = w*16 + (lane >> 2);       // row within 0..63 half
  const int sk   = (lane & 3) * 8;           // k element offset
  int ar0 = m0 + srow;       if (ar0 > M-1) ar0 = M-1;
  int ar1 = m0 + 64 + srow;  if (ar1 > M-1) ar1 = M-1;
  const ushort* Ap0 = A + (size_t)ar0*K + sk;
  const ushort* Ap1 = A + (size_t)ar1*K + sk;
  const ushort* Bp0 = W + (size_t)(n0 + srow)*K + sk;
  const ushort* Bp1 = W + (size_t)(n0 + 64 + srow)*K + sk;
  ushort* lA0 = &As[w*512];
  ushort* lA1 = &As[(4+w)*512];
  ushort* lB0 = &Bs[w*512];
  ushort* lB1 = &Bs[(4+w)*512];

  f32x4 acc[4][4];
#pragma unroll
  for (int i = 0; i < 4; ++i)
#pragma unroll
    for (int j = 0; j < 4; ++j) acc[i][j] = (f32x4)(0.0f);

  for (int k0 = 0; k0 < K; k0 += 32) {
    __syncthreads();              // prev iter finished reading LDS
    gld16(Ap0 + k0, lA0);
    gld16(Ap1 + k0, lA1);
    gld16(Bp0 + k0, lB0);
    gld16(Bp1 + k0, lB1);
    __syncthreads();              // vmcnt(0) drain before barrier -> LDS ready
    bf16x8 af[4], bfr[4];
#pragma unroll
    for (int mi = 0; mi < 4; ++mi)
      af[mi] = *(const bf16x8*)(&As[(wr*64 + mi*16 + c)*32 + g*8]);
#pragma unroll
    for (int ni = 0; ni < 4; ++ni)
      bfr[ni] = *(const bf16x8*)(&Bs[(wc*64 + ni*16 + c)*32 + g*8]);
#pragma unroll
    for (int mi = 0; mi < 4; ++mi)
#pragma unroll
      for (int ni = 0; ni < 4; ++ni)
        acc[mi][ni] = mfma16(af[mi], bfr[ni], acc[mi][ni]);
  }

  if (CS) {
    __syncthreads();
    if (tid < 128) { csum[tid] = 0.f; csq[tid] = 0.f; }
    __syncthreads();
  }

#pragma unroll
  for (int ni = 0; ni < 4; ++ni) {
    const int col = n0 + wc*64 + ni*16 + c;
    const float bb = bias[col];
    float ls = 0.f, lq = 0.f;
#pragma unroll
    for (int mi = 0; mi < 4; ++mi) {
#pragma unroll
      for (int q = 0; q < 4; ++q) {
        const int row = m0 + wr*64 + mi*16 + g*4 + q;
        if (row < M) {
          const float v = acc[mi][ni][q] + bb;
          if (OM == 0) Cf[(size_t)row*N + col] = v;
          else if (OM == 1) Ch[(size_t)row*N + col] = f2bf(v);
          else Ch[(size_t)row*N + col] = f2bf(v*0.125f);
          if (CS) { ls += v; lq += v*v; }
        }
      }
    }
    if (CS) {
      const int lcol = wc*64 + ni*16 + c;
      atomicAdd(&csum[lcol], ls);
      atomicAdd(&csq[lcol], lq);
    }
  }
  if (CS) {
    __syncthreads();
    if (tid < 128) {
      atomicAdd(&gsum[n0 + tid], csum[tid]);
      atomicAdd(&gsq[n0 + tid], csq[tid]);
    }
  }
}

// ---------- BN pieces ----------

__global__ void bn_finalize(const float* __restrict__ sums, const float* __restrict__ sumsq,
    const float* __restrict__ g, const float* __restrict__ b, int C, float invM,
    float* __restrict__ scale, float* __restrict__ shift) {
  const int c = blockIdx.x*256 + threadIdx.x;
  if (c >= C) return;
  const float mu = sums[c]*invM;
  const float var = sumsq[c]*invM - mu*mu;
  const float sc = rsqrtf(var + 1e-5f) * g[c];
  scale[c] = sc;
  shift[c] = b[c] - mu*sc;
}

// BN1 apply + relu on bf16; route first 25 batches -> srawh, rest -> xbufh[5..79]
__global__ __launch_bounds__(256) void bn1_apply(const ushort* __restrict__ y1,
    const float* __restrict__ scale, const float* __restrict__ shift,
    ushort* __restrict__ srawh, ushort* __restrict__ xbufh) {
  const int i8 = blockIdx.x*256 + threadIdx.x;
  if (i8 >= M1*HD/8) return;
  const int e = i8 << 3;
  const int col = e & (HD - 1);
  const uint4 raw = ((const uint4*)y1)[i8];
  unsigned rw[4] = {raw.x, raw.y, raw.z, raw.w};
  unsigned res[4];
#pragma unroll
  for (int j = 0; j < 4; ++j) {
    float v0 = bf2f((ushort)(rw[j] & 0xffffu));
    float v1 = bf2f((ushort)(rw[j] >> 16));
    v0 = fmaxf(fmaf(v0, scale[col + 2*j],     shift[col + 2*j]),     0.f);
    v1 = fmaxf(fmaf(v1, scale[col + 2*j + 1], shift[col + 2*j + 1]), 0.f);
    res[j] = (unsigned)f2bf(v0) | ((unsigned)f2bf(v1) << 16);
  }
  const uint4 o = make_uint4(res[0], res[1], res[2], res[3]);
  if (e < 25*SEQ*HD) ((uint4*)srawh)[i8] = o;
  else ((uint4*)xbufh)[i8 - (20*SEQ*HD/8)] = o;
}

__global__ void support_mean(const ushort* __restrict__ srawh, ushort* __restrict__ xbufh) {
  const int i8 = blockIdx.x*256 + threadIdx.x;
  if (i8 >= WAYS*SEQ*HD/8) return;
  const int e = i8 << 3;
  const int w = e / (SEQ*HD);
  const int rem = e - w*(SEQ*HD);
  float acc[8] = {};
#pragma unroll
  for (int s = 0; s < SHOTS; ++s) {
    const uint4 v = *(const uint4*)(srawh + (size_t)(s*WAYS + w)*(SEQ*HD) + rem);
    const unsigned rw[4] = {v.x, v.y, v.z, v.w};
#pragma unroll
    for (int j = 0; j < 4; ++j) {
      acc[2*j]   += bf2f((ushort)(rw[j] & 0xffffu));
      acc[2*j+1] += bf2f((ushort)(rw[j] >> 16));
    }
  }
  unsigned res[4];
#pragma unroll
  for (int j = 0; j < 4; ++j)
    res[j] = (unsigned)f2bf(acc[2*j]*0.2f) | ((unsigned)f2bf(acc[2*j+1]*0.2f) << 16);
  ((uint4*)xbufh)[i8] = make_uint4(res[0], res[1], res[2], res[3]);
}

// ---------- attention: QK^T + softmax -> P bf16 [bh][208][232] ----------

__global__ __launch_bounds__(256) void attn_qk(const ushort* __restrict__ qb,
    const ushort* __restrict__ kb, ushort* __restrict__ P) {
  __shared__ ushort Ks[208*72];
  const int bh = blockIdx.x, b = bh >> 3, h = bh & 7;
  const int tid = threadIdx.x;
  for (int idx = tid; idx < 208*8; idx += 256) {
    const int row = idx >> 3, part = idx & 7;
    uint4 v = make_uint4(0u,0u,0u,0u);
    if (row < SEQ) v = *(const uint4*)(kb + ((size_t)(b*SEQ + row))*HD + h*64 + part*8);
    *(uint4*)(&Ks[row*72 + part*8]) = v;
  }
  __syncthreads();
  const int w = tid >> 6, lane = tid & 63, g = lane >> 4, c = lane & 15;
  for (int rt = w; rt < 13; rt += 4) {
    int qrow = b*SEQ + rt*16 + c; if (qrow > MMHA-1) qrow = MMHA-1;
    const bf16x8 aq0 = *(const bf16x8*)(qb + (size_t)qrow*HD + h*64 + g*8);
    const bf16x8 aq1 = *(const bf16x8*)(qb + (size_t)qrow*HD + h*64 + 32 + g*8);
    f32x4 acc[13];
#pragma unroll
    for (int ct = 0; ct < 13; ++ct) acc[ct] = (f32x4)(0.0f);
#pragma unroll
    for (int ct = 0; ct < 13; ++ct) {
      const bf16x8 b0 = *(const bf16x8*)(&Ks[(ct*16 + c)*72 + g*8]);
      const bf16x8 b1 = *(const bf16x8*)(&Ks[(ct*16 + c)*72 + 32 + g*8]);
      acc[ct] = mfma16(aq0, b0, acc[ct]);
      acc[ct] = mfma16(aq1, b1, acc[ct]);
    }
    if (c >= 4) acc[12] = (f32x4)(-1e30f);
    float mrow[4], Z[4];
#pragma unroll
    for (int q = 0; q < 4; ++q) {
      float mx = acc[0][q];
#pragma unroll
      for (int ct = 1; ct < 13; ++ct) mx = fmaxf(mx, acc[ct][q]);
      mrow[q] = mx;
    }
#pragma unroll
    for (int q = 0; q < 4; ++q) {
#pragma unroll
      for (int msk = 1; msk < 16; msk <<= 1)
        mrow[q] = fmaxf(mrow[q], __shfl_xor(mrow[q], msk, 64));
    }
#pragma unroll
    for (int q = 0; q < 4; ++q) Z[q] = 0.f;
#pragma unroll
    for (int ct = 0; ct < 13; ++ct)
#pragma unroll
      for (int q = 0; q < 4; ++q) {
        const float e = __expf(acc[ct][q] - mrow[q]);
        acc[ct][q] = e; Z[q] += e;
      }
#pragma unroll
    for (int q = 0; q < 4; ++q) {
#pragma unroll
      for (int msk = 1; msk < 16; msk <<= 1) Z[q] += __shfl_xor(Z[q], msk, 64);
      Z[q] = 1.f / Z[q];
    }
    const size_t pb = (size_t)bh*(208*232);
#pragma unroll
    for (int q = 0; q < 4; ++q) {
      ushort* pr = P + pb + (size_t)(rt*16 + g*4 + q)*232;
#pragma unroll
      for (int ct = 0; ct < 13; ++ct) pr[ct*16 + c] = f2bf(acc[ct][q]*Z[q]);
      pr[208 + c] = 0;
      if (c < 8) pr[224 + c] = 0;
    }
  }
}

// ---------- V transpose ----------

__global__ __launch_bounds__(256) void v_transpose(const ushort* __restrict__ vb,
                                                   ushort* __restrict__ VT) {
  __shared__ ushort Vs[196*72];
  const int bh = blockIdx.x, b = bh >> 3, h = bh & 7;
  const int tid = threadIdx.x;
  for (int idx = tid; idx < 196*8; idx += 256) {
    const int row = idx >> 3, part = idx & 7;
    *(uint4*)(&Vs[row*72 + part*8]) =
        *(const uint4*)(vb + ((size_t)(b*SEQ + row))*HD + h*64 + part*8);
  }
  __syncthreads();
  ushort* o = VT + (size_t)bh*64*224;
  for (int idx = tid; idx < 64*224; idx += 256) {
    const int d = idx/224, s = idx - d*224;
    o[idx] = (s < SEQ) ? Vs[s*72 + d] : (ushort)0;
  }
}

// ---------- P.V ----------

__global__ __launch_bounds__(256) void attn_pv(const ushort* __restrict__ P,
    const ushort* __restrict__ VT, ushort* __restrict__ ctx) {
  __shared__ ushort Ps[112*232];
  const int bh = blockIdx.x, b = bh >> 3, h = bh & 7;
  const int tid = threadIdx.x, w = tid >> 6, lane = tid & 63, g = lane >> 4, c = lane & 15;
  bf16x8 bv[7];
  const ushort* vt = VT + (size_t)bh*64*224 + (size_t)(w*16 + c)*224;
#pragma unroll
  for (int ks = 0; ks < 7; ++ks) bv[ks] = *(const bf16x8*)(vt + ks*32 + g*8);
  const char* pg = (const char*)(P + (size_t)bh*(208*232));
#pragma unroll
  for (int half = 0; half < 2; ++half) {
    const int r0 = half ? 112 : 0;
    const int nbytes = half ? 96*464 : 112*464;
    __syncthreads();
    for (int byte = tid*16; byte < nbytes; byte += 4096)
      *(uint4*)((char*)Ps + byte) = *(const uint4*)(pg + r0*464 + byte);
    __syncthreads();
    const int rtlo = half ? 7 : 0, rthi = half ? 13 : 7;
    for (int rt = rtlo; rt < rthi; ++rt) {
      const int lrow = rt*16 - r0 + c;
      f32x4 acc = (f32x4)(0.0f);
#pragma unroll
      for (int ks = 0; ks < 7; ++ks) {
        const bf16x8 a = *(const bf16x8*)(&Ps[lrow*232 + ks*32 + g*8]);
        acc = mfma16(a, bv[ks], acc);
      }
#pragma unroll
      for (int q = 0; q < 4; ++q) {
        const int srow = rt*16 + g*4 + q;
        if (srow < SEQ)
          ctx[((size_t)(b*SEQ + srow))*HD + h*64 + w*16 + c] = f2bf(acc[q]);
      }
    }
  }
}

// ---------- LayerNorm + residual (tmp fp32 + xin bf16 -> bf16) ----------

__global__ __launch_bounds__(256) void ln_kernel(const float* __restrict__ tmp,
    const ushort* __restrict__ xin, const float* __restrict__ g,
    const float* __restrict__ bta, ushort* __restrict__ outh) {
  const int row = blockIdx.x*4 + (threadIdx.x >> 6);
  const int lane = threadIdx.x & 63;
  const float* t = tmp + (size_t)row*HD;
  const ushort* x = xin + (size_t)row*HD;
  float v[8]; float s = 0.f;
#pragma unroll
  for (int i = 0; i < 8; ++i) {
    const float val = t[i*64 + lane] + bf2f(x[i*64 + lane]);
    v[i] = val; s += val;
  }
  s = waveSum(s);
  const float mu = s * (1.f/HD);
  float sq = 0.f;
#pragma unroll
  for (int i = 0; i < 8; ++i) { const float d = v[i] - mu; sq += d*d; }
  sq = waveSum(sq);
  const float istd = rsqrtf(sq*(1.f/HD) + 1e-5f);
#pragma unroll
  for (int i = 0; i < 8; ++i) {
    const int d = i*64 + lane;
    outh[(size_t)row*HD + d] = f2bf((v[i] - mu)*istd*g[d] + bta[d]);
  }
}

// ---------- prototypes / losses / per-row ----------

__global__ __launch_bounds__(256) void mw_kernel(const ushort* __restrict__ xout,
    const float* __restrict__ Wm, float* __restrict__ m) {
  const int row = blockIdx.x*4 + (threadIdx.x >> 6);
  const int lane = threadIdx.x & 63;
  const ushort* x = xout + (size_t)row*HD;
  float xv[8];
#pragma unroll
  for (int i = 0; i < 8; ++i) xv[i] = bf2f(x[i*64 + lane]);
#pragma unroll
  for (int p = 0; p < PP; ++p) {
    const float* wp = Wm + p*HD;
    float s = 0.f;
#pragma unroll
    for (int i = 0; i < 8; ++i) s = fmaf(xv[i], wp[i*64 + lane], s);
    s = waveSum(s);
    if (lane == 0) m[row*PP + p] = s;
  }
}

__global__ __launch_bounds__(256) void wsm_kernel(const float* __restrict__ m,
                                                  float* __restrict__ wsm) {
  __shared__ float red[256];
  const int p = blockIdx.x, tid = threadIdx.x;
  float lmax = -1e30f;
  for (int r = tid; r < 980; r += 256) lmax = fmaxf(lmax, m[r*PP + p]);
  red[tid] = lmax; __syncthreads();
  for (int s = 128; s; s >>= 1) { if (tid < s) red[tid] = fmaxf(red[tid], red[tid+s]); __syncthreads(); }
  const float bmax = red[0]; __syncthreads();
  float lsum = 0.f;
  for (int r = tid; r < 980; r += 256) {
    const float e = __expf(m[r*PP + p] - bmax);
    wsm[p*980 + r] = e; lsum += e;
  }
  red[tid] = lsum; __syncthreads();
  for (int s = 128; s; s >>= 1) { if (tid < s) red[tid] += red[tid+s]; __syncthreads(); }
  const float invZ = 1.f / red[0];
  for (int r = tid; r < 980; r += 256) wsm[p*980 + r] *= invZ;
}

__global__ __launch_bounds__(256) void protos_part(const float* __restrict__ wsm,
    const ushort* __restrict__ xout, float* __restrict__ part) {
  const int p = blockIdx.y, chunk = blockIdx.x, tid = threadIdx.x;
  const int r0 = chunk*49;
  float a0 = 0.f, a1 = 0.f;
  for (int r = r0; r < r0 + 49; ++r) {
    const float w = wsm[p*980 + r];
    a0 = fmaf(w, bf2f(xout[(size_t)r*HD + tid]), a0);
    a1 = fmaf(w, bf2f(xout[(size_t)r*HD + tid + 256]), a1);
  }
  float* o = part + (((size_t)p*20 + chunk) << 9);
  o[tid] = a0;
  o[tid + 256] = a1;
}

__global__ __launch_bounds__(256) void protos_fin(const float* __restrict__ part,
                                                  float* __restrict__ pn) {
  __shared__ float red[256];
  const int p = blockIdx.x, tid = threadIdx.x;
  float a0 = 0.f, a1 = 0.f;
  for (int cch = 0; cch < 20; ++cch) {
    const float* o = part + (((size_t)p*20 + cch) << 9);
    a0 += o[tid];
    a1 += o[tid + 256];
  }
  red[tid] = a0*a0 + a1*a1; __syncthreads();
  for (int s = 128; s; s >>= 1) { if (tid < s) red[tid] += red[tid+s]; __syncthreads(); }
  const float rn = 1.f / fmaxf(sqrtf(red[0]), 1e-12f);
  pn[p*HD + tid] = a0*rn;
  pn[p*HD + tid + 256] = a1*rn;
}

__global__ __launch_bounds__(256) void losses_kernel(const float* __restrict__ pn, float* __restrict__ out) {
  __shared__ float redc[256], redd[256];
  const int tid = threadIdx.x;
  float cpart = 0.f, dpart = 0.f;
  for (int d = tid; d < HD; d += 256) {
    float a[PP];
#pragma unroll
    for (int j = 0; j < PP; ++j) a[j] = pn[j*HD + d];
#pragma unroll
    for (int j = 0; j < PP; ++j) {
      if (d > j) {
#pragma unroll
        for (int i = 0; i < PP; ++i) {
          const float df = a[j] - a[i];
          const float t = 1.f - df*df;
          if (t > 0.f) dpart += t;
        }
      }
    }
#pragma unroll
    for (int j = 0; j < PP - 1; ++j) { const float df = a[j+1] - a[j]; cpart += df*df; }
  }
  redc[tid] = cpart; redd[tid] = dpart; __syncthreads();
  for (int s = 128; s; s >>= 1) {
    if (tid < s) { redc[tid] += redc[tid+s]; redd[tid] += redd[tid+s]; }
    __syncthreads();
  }
  if (tid == 0) {
    out[OUT_UPD + 1] = redc[0] / 9.f;
    out[OUT_UPD + 2] = redd[0] * (2.f / (90.f * 512.f));
  }
}

__global__ __launch_bounds__(256) void rowk(const ushort* __restrict__ xout, const float* __restrict__ pn,
    ushort* __restrict__ newq, float* __restrict__ feapart) {
  __shared__ float Ps[PP*HD];
  __shared__ float fred[4];
  const int tid = threadIdx.x;
  for (int idx = tid; idx < PP*HD; idx += 256) Ps[idx] = pn[idx];
  __syncthreads();
  const int row = blockIdx.x*4 + (tid >> 6);
  const int lane = tid & 63;
  const ushort* x = xout + (size_t)(WAYS*SEQ + row)*HD;
  float xv[8];
#pragma unroll
  for (int i = 0; i < 8; ++i) xv[i] = bf2f(x[i*64 + lane]);
  float sc[PP];
#pragma unroll
  for (int p = 0; p < PP; ++p) {
    float s = 0.f;
#pragma unroll
    for (int i = 0; i < 8; ++i) s = fmaf(xv[i], Ps[p*HD + i*64 + lane], s);
    sc[p] = waveSum(s);
  }
  float mx = sc[0]; int am = 0;
#pragma unroll
  for (int p = 1; p < PP; ++p) if (sc[p] > mx) { mx = sc[p]; am = p; }
  float Z = 0.f; float sp[PP];
#pragma unroll
  for (int p = 0; p < PP; ++p) { const float e = expf(sc[p] - mx); sp[p] = e; Z += e; }
  const float rz = 1.f / Z;
  float nv[8]; float ss = 0.f;
#pragma unroll
  for (int i = 0; i < 8; ++i) {
    float a = 0.f;
#pragma unroll
    for (int p = 0; p < PP; ++p) a = fmaf(sp[p], Ps[p*HD + i*64 + lane], a);
    a *= rz; nv[i] = a; ss += a*a;
  }
  ss = waveSum(ss);
  const float rn = 1.f / fmaxf(sqrtf(ss), 1e-12f);
#pragma unroll
  for (int i = 0; i < 8; ++i) newq[(size_t)row*HD + i*64 + lane] = f2bf(nv[i]*rn);
  float fp = 0.f;
#pragma unroll
  for (int i = 0; i < 8; ++i) { const float d = xv[i] - Ps[am*HD + i*64 + lane]; fp += d*d; }
  fp = waveSum(fp);
  if (lane == 0) fred[tid >> 6] = fp;
  __syncthreads();
  if (tid == 0) feapart[blockIdx.x] = fred[0] + fred[1] + fred[2] + fred[3];
}

__global__ __launch_bounds__(256) void fea_finalize(const float* __restrict__ feapart,
                                                    float* __restrict__ out) {
  __shared__ float red[256];
  float s = 0.f;
  for (int i = threadIdx.x; i < NBLK_ROWK; i += 256) s += feapart[i];
  red[threadIdx.x] = s; __syncthreads();
  for (int st = 128; st; st >>= 1) {
    if (threadIdx.x < st) red[threadIdx.x] += red[threadIdx.x + st];
    __syncthreads();
  }
  if (threadIdx.x == 0) out[OUT_UPD] = red[0] / (float)((size_t)NQB*SEQ*HD);
}

__global__ __launch_bounds__(256) void bn2_apply(const float* __restrict__ y2, const float* __restrict__ scale,
    const float* __restrict__ shift, const float* __restrict__ query, float* __restrict__ out) {
  __shared__ float tile[32][33];
  const int n = blockIdx.z, o0 = blockIdx.y*32, hw0 = blockIdx.x*32;
  const int tj = threadIdx.x & 31, ti = threadIdx.x >> 5;
#pragma unroll
  for (int it = 0; it < 4; ++it) {
    const int hw = hw0 + it*8 + ti;
    const int o = o0 + tj;
    float v = 0.f;
    if (hw < SEQ) v = fmaxf(fmaf(y2[((size_t)n*SEQ + hw)*FDIMC + o], scale[o], shift[o]), 0.f);
    tile[it*8 + ti][tj] = v;
  }
  __syncthreads();
#pragma unroll
  for (int it = 0; it < 4; ++it) {
    const int o = o0 + it*8 + ti;
    const int hw = hw0 + tj;
    if (hw < SEQ) {
      const size_t oi = ((size_t)n*FDIMC + o)*SEQ + hw;
      out[oi] = tile[tj][it*8 + ti] + query[oi];
    }
  }
}

extern "C" void kernel_launch(void* const* d_in, const int* in_sizes, int n_in,
                              void* d_out, int out_size, void* d_ws, size_t ws_size,
                              hipStream_t stream) {
  const float* key   = (const float*)d_in[0];
  const float* query = (const float*)d_in[1];
  const float* Wc    = (const float*)d_in[2];
  const float* bc    = (const float*)d_in[3];
  const float* g1    = (const float*)d_in[4];
  const float* b1    = (const float*)d_in[5];
  const float* Wq    = (const float*)d_in[6];
  const float* bq    = (const float*)d_in[7];
  const float* Wk    = (const float*)d_in[8];
  const float* bk    = (const float*)d_in[9];
  const float* Wv    = (const float*)d_in[10];
  const float* bv    = (const float*)d_in[11];
  const float* Wa    = (const float*)d_in[12];
  const float* ba    = (const float*)d_in[13];
  const float* ln_g  = (const float*)d_in[14];
  const float* ln_b  = (const float*)d_in[15];
  const float* Wm    = (const float*)d_in[16];
  const float* Wo    = (const float*)d_in[17];
  const float* bo    = (const float*)d_in[18];
  const float* g2    = (const float*)d_in[19];
  const float* b2    = (const float*)d_in[20];
  float* out = (float*)d_out;
  float* w = (float*)d_ws;

  ushort* y1h   = (ushort*)(w + RB);
  ushort* P     = (ushort*)(w + RB);
  float*  y2f   = w + RB;
  ushort* xouth = (ushort*)(w + OFF_XOUT);
  ushort* VT    = (ushort*)(w + RC);
  ushort* keyT  = (ushort*)(w + RD);
  ushort* qb    = (ushort*)(w + RD);
  float*  tmpf  = w + RD;
  ushort* xbufh = (ushort*)(w + RE);
  ushort* srawh = (ushort*)(w + RF);
  ushort* kb    = (ushort*)(w + RF);
  ushort* newq  = (ushort*)(w + RF);
  ushort* vb    = (ushort*)(w + RG);
  ushort* ctx   = (ushort*)(w + RG);
  ushort* wh    = (ushort*)(w + RH);
  float*  feapart = w + OFF_FEAP;
  float*  wsm   = w + OFF_WSM;
  float*  ppart = w + OFF_PPART;
  ushort* Wcb = wh;
  ushort* Wqb = wh + 327680;
  ushort* Wkb = wh + 589824;
  ushort* Wvb = wh + 851968;
  ushort* Wab = wh + 1114112;
  ushort* Wob = wh + 1376256;

  hipMemsetAsync(w, 0, ZERO_FLOATS*sizeof(float), stream);

  key_transpose<<<dim3(7, 20, NB), 256, 0, stream>>>(key, keyT);
  wconvert<<<6656, 256, 0, stream>>>(Wc, Wq, Wk, Wv, Wa, Wo, wh);

  // conv1 (bf16 MFMA, gload_lds staging, fused BN col-stats) -> y1h bf16
  gemm_bf<1,1><<<dim3(4, 154), 256, 0, stream>>>(keyT, Wcb, bc, nullptr, y1h, M1, HD, FDIMC,
                                                 w + OFF_CS1S, w + OFF_CS1Q);
  bn_finalize<<<2, 256, 0, stream>>>(w + OFF_CS1S, w + OFF_CS1Q, g1, b1, HD, 1.f/M1,
                                     w + OFF_ST1SC, w + OFF_ST1SH);
  bn1_apply<<<M1*HD/8/256, 256, 0, stream>>>(y1h, w + OFF_ST1SC, w + OFF_ST1SH, srawh, xbufh);
  support_mean<<<WAYS*SEQ*HD/8/256, 256, 0, stream>>>(srawh, xbufh);

  // MHA projections (bf16 out; q pre-scaled by 1/8)
  gemm_bf<2,0><<<dim3(4, 123), 256, 0, stream>>>(xbufh, Wqb, bq, nullptr, qb, MMHA, HD, HD, nullptr, nullptr);
  gemm_bf<1,0><<<dim3(4, 123), 256, 0, stream>>>(xbufh, Wkb, bk, nullptr, kb, MMHA, HD, HD, nullptr, nullptr);
  gemm_bf<1,0><<<dim3(4, 123), 256, 0, stream>>>(xbufh, Wvb, bv, nullptr, vb, MMHA, HD, HD, nullptr, nullptr);

  v_transpose<<<NMHA*8, 256, 0, stream>>>(vb, VT);
  attn_qk<<<NMHA*8, 256, 0, stream>>>(qb, kb, P);
  attn_pv<<<NMHA*8, 256, 0, stream>>>(P, VT, ctx);

  // out-proj -> tmp fp32 (precision-critical: pre-LN residual path)
  gemm_bf<0,0><<<dim3(4, 123), 256, 0, stream>>>(ctx, Wab, ba, tmpf, nullptr, MMHA, HD, HD, nullptr, nullptr);
  ln_kernel<<<MMHA/4, 256, 0, stream>>>(tmpf, xbufh, ln_g, ln_b, xouth);

  // prototypes + losses
  mw_kernel<<<245, 256, 0, stream>>>(xouth, Wm, w + OFF_M);
  wsm_kernel<<<PP, 256, 0, stream>>>(w + OFF_M, wsm);
  protos_part<<<dim3(20, PP), 256, 0, stream>>>(wsm, xouth, ppart);
  protos_fin<<<PP, 256, 0, stream>>>(ppart, w + OFF_PN);
  losses_kernel<<<1, 256, 0, stream>>>(w + OFF_PN, out);
  rowk<<<NBLK_ROWK, 256, 0, stream>>>(xouth, w + OFF_PN, newq, feapart);

  // conv2 -> y2 fp32 (precision-critical), fused BN col-stats
  gemm_bf<0,1><<<dim3(5, 115), 256, 0, stream>>>(newq, Wob, bo, y2f, nullptr, MQ, FDIMC, HD,
                                                 w + OFF_CS2S, w + OFF_CS2Q);
  bn_finalize<<<3, 256, 0, stream>>>(w + OFF_CS2S, w + OFF_CS2Q, g2, b2, FDIMC, 1.f/MQ,
                                     w + OFF_ST2SC, w + OFF_ST2SH);
  fea_finalize<<<1, 256, 0, stream>>>(feapart, out);
  bn2_apply<<<dim3(7, 20, NQB), 256, 0, stream>>>(y2f, w + OFF_ST2SC, w + OFF_ST2SH, query, out);
}

// Round 9
// 343.666 us; speedup vs baseline: 5.0911x; 1.0779x over previous
//
#include <hip/hip_runtime.h>
#include <math.h>

// ---- problem constants ----
#define WAYS 5
#define SHOTS 5
#define PP 10
#define FDIMC 640
#define HD 512
#define QKVS 1536
#define SEQ 196
#define NB 100
#define NQB 75
#define NMHA 80
#define M1 (NB*SEQ)       // 19600
#define MMHA (NMHA*SEQ)   // 15680
#define MQ (NQB*SEQ)      // 14700
#define NBLK_ROWK (MQ/4)  // 3675
#define OUT_UPD (NQB*FDIMC*SEQ)  // 9,408,000

// ---- small stats block (float offsets) ----
#define OFF_CS1S 0
#define OFF_CS1Q 512
#define OFF_CS2S 1024
#define OFF_CS2Q 1664
#define ZERO_FLOATS 2306
#define OFF_ST1SC 2308
#define OFF_ST1SH 2820
#define OFF_ST2SC 3332
#define OFF_ST2SH 3972
#define OFF_M    4612
#define OFF_PN   14412

// ---- big regions (float offsets) ----
#define RB 20480                   /* y1h bf16 / P bf16 / y2 fp32 ; xouth at +10M */
#define RC (RB + 15439360)         /* VT bf16 */
#define RD (RC + 8028160)          /* keyT bf16 -> tmp fp32 */
#define RE (RD + 8028160)          /* xbufh bf16 */
#define RF (RE + 8028160)          /* srawh bf16 -> newq bf16 + feapart + bqkv */
#define RG (RF + 4014080)          /* ctx bf16 -> wsm/ppart */
#define RH (RG + 4014080)          /* weights bf16 concat */
#define RQ 48424960                /* qkv bf16 [MMHA][1536] = 12,042,240 fl */
#define OFF_XOUT (RB + 10000000)
#define OFF_FEAP (RF + 3763200)
#define OFF_BQKV (RF + 3767296)
#define OFF_WSM  RG
#define OFF_PPART (RG + 16384)

typedef __bf16 bf16x8 __attribute__((ext_vector_type(8)));
typedef float f32x4 __attribute__((ext_vector_type(4)));

__device__ __forceinline__ ushort f2bf(float f) {
  unsigned u = __float_as_uint(f);
  return (ushort)((u + 0x7fffu + ((u >> 16) & 1u)) >> 16);
}
__device__ __forceinline__ float bf2f(ushort u) {
  return __uint_as_float(((unsigned)u) << 16);
}

__device__ __forceinline__ f32x4 mfma16(bf16x8 a, bf16x8 b, f32x4 c) {
  return __builtin_amdgcn_mfma_f32_16x16x32_bf16(a, b, c, 0, 0, 0);
}

__device__ __forceinline__ float waveSum(float v) {
#pragma unroll
  for (int o = 32; o; o >>= 1) v += __shfl_xor(v, o, 64);
  return v;
}

// async global -> LDS, 16 B per lane (wave-uniform LDS base + lane*16)
__device__ __forceinline__ void gld16(const void* g, void* l) {
  __builtin_amdgcn_global_load_lds(
      (const __attribute__((address_space(1))) void*)g,
      (__attribute__((address_space(3))) void*)l,
      16, 0, 0);
}

// ---------- transposes / converts ----------

__global__ __launch_bounds__(256) void key_transpose(const float* __restrict__ key,
                                                     ushort* __restrict__ keyT) {
  __shared__ float T[32][33];
  const int n = blockIdx.z, c0 = blockIdx.y*32, s0 = blockIdx.x*32;
  const int tj = threadIdx.x & 31, ti = threadIdx.x >> 5;
#pragma unroll
  for (int it = 0; it < 4; ++it) {
    const int cl = it*8 + ti;
    const int s = s0 + tj;
    T[cl][tj] = (s < SEQ) ? key[((size_t)n*FDIMC + c0 + cl)*SEQ + s] : 0.f;
  }
  __syncthreads();
#pragma unroll
  for (int it = 0; it < 4; ++it) {
    const int sl = it*8 + ti;
    const int s = s0 + sl;
    if (s < SEQ) keyT[((size_t)(n*SEQ + s))*FDIMC + c0 + tj] = f2bf(T[tj][sl]);
  }
}

__global__ void wconvert(const float* __restrict__ Wc, const float* __restrict__ Wq,
                         const float* __restrict__ Wk, const float* __restrict__ Wv,
                         const float* __restrict__ Wa, const float* __restrict__ Wo,
                         ushort* __restrict__ wh) {
  const int i = blockIdx.x*256 + threadIdx.x;
  float v;
  if (i < 327680) v = Wc[i];
  else if (i < 589824) v = Wq[i - 327680];
  else if (i < 851968) v = Wk[i - 589824];
  else if (i < 1114112) v = Wv[i - 851968];
  else if (i < 1376256) v = Wa[i - 1114112];
  else v = Wo[i - 1376256];
  wh[i] = f2bf(v);
}

__global__ void qkv_bias(const float* __restrict__ bq, const float* __restrict__ bk,
                         const float* __restrict__ bv, float* __restrict__ o) {
  const int i = blockIdx.x*256 + threadIdx.x;
  if (i >= QKVS) return;
  o[i] = (i < 512) ? bq[i] : (i < 1024 ? bk[i-512] : bv[i-1024]);
}

// ---------- bf16 MFMA GEMM: C = A(MxK) . W(NxK)^T + bias ----------
// OM: 0 -> fp32 out, 1 -> bf16 out, 3 -> bf16 out, cols<HD scaled by 0.125 (QKV fused)
// CS: 1 -> accumulate per-column sum/sumsq of fp32 output into gsum/gsq
// 2-phase double-buffered LDS, global_load_lds staging with XOR k-slot swizzle,
// bijective XCD-aware block swizzle.
template<int OM, int CS>
__global__ __launch_bounds__(256) void gemm_bf(const ushort* __restrict__ A,
    const ushort* __restrict__ W, const float* __restrict__ bias,
    float* __restrict__ Cf, ushort* __restrict__ Ch, int M, int N, int K,
    float* __restrict__ gsum, float* __restrict__ gsq) {
  __shared__ ushort As[2][128*32];
  __shared__ ushort Bs[2][128*32];
  __shared__ float csum[128], csq[128];
  const int tid = threadIdx.x;

  // XCD-aware bijective swizzle (m204)
  const int nwg = gridDim.x * gridDim.y;
  int flat = blockIdx.y * gridDim.x + blockIdx.x;
  {
    const int q = nwg >> 3, r = nwg & 7;
    const int j = flat & 7, tt = flat >> 3;
    flat = (j < r ? j*(q+1) : r*(q+1) + (j-r)*q) + tt;
  }
  const int m0 = (flat / gridDim.x) * 128;
  const int n0 = (flat % gridDim.x) * 128;

  const int w = tid >> 6, lane = tid & 63;
  const int wr = w >> 1, wc = w & 1;
  const int g = lane >> 4, c = lane & 15;

  // staging: wave w owns chunks {w, 4+w}; XOR-swizzled source k-slot so that
  // linear LDS write + swizzled read = bank-spread layout (rule #21)
  const int srow = w*16 + (lane >> 2);
  const int sk = ((lane & 3) ^ ((lane >> 2) & 3)) * 8;
  int ar0 = m0 + srow;       if (ar0 > M-1) ar0 = M-1;
  int ar1 = m0 + 64 + srow;  if (ar1 > M-1) ar1 = M-1;
  const ushort* Ap0 = A + (size_t)ar0*K + sk;
  const ushort* Ap1 = A + (size_t)ar1*K + sk;
  const ushort* Bp0 = W + (size_t)(n0 + srow)*K + sk;
  const ushort* Bp1 = W + (size_t)(n0 + 64 + srow)*K + sk;

  f32x4 acc[4][4];
#pragma unroll
  for (int i = 0; i < 4; ++i)
#pragma unroll
    for (int j = 0; j < 4; ++j) acc[i][j] = (f32x4)(0.0f);

  const int nt = K >> 5;
  // prologue: stage tile 0 -> buf 0
  gld16(Ap0, &As[0][w*512]);
  gld16(Ap1, &As[0][(4+w)*512]);
  gld16(Bp0, &Bs[0][w*512]);
  gld16(Bp1, &Bs[0][(4+w)*512]);
  asm volatile("s_waitcnt vmcnt(0)" ::: "memory");
  __builtin_amdgcn_s_barrier();

  int cur = 0;
  for (int t = 0; t < nt; ++t) {
    const int nxt = cur ^ 1;
    if (t + 1 < nt) {                      // issue next tile while computing
      const int k0 = (t + 1) << 5;
      gld16(Ap0 + k0, &As[nxt][w*512]);
      gld16(Ap1 + k0, &As[nxt][(4+w)*512]);
      gld16(Bp0 + k0, &Bs[nxt][w*512]);
      gld16(Bp1 + k0, &Bs[nxt][(4+w)*512]);
    }
    bf16x8 af[4], bfr[4];
#pragma unroll
    for (int mi = 0; mi < 4; ++mi) {
      const int row = wr*64 + mi*16 + c;
      af[mi] = *(const bf16x8*)(&As[cur][row*32 + (g ^ (c & 3))*8]);
    }
#pragma unroll
    for (int ni = 0; ni < 4; ++ni) {
      const int row = wc*64 + ni*16 + c;
      bfr[ni] = *(const bf16x8*)(&Bs[cur][row*32 + (g ^ (c & 3))*8]);
    }
#pragma unroll
    for (int mi = 0; mi < 4; ++mi)
#pragma unroll
      for (int ni = 0; ni < 4; ++ni)
        acc[mi][ni] = mfma16(af[mi], bfr[ni], acc[mi][ni]);
    asm volatile("s_waitcnt vmcnt(0)" ::: "memory");  // own 4 next-tile loads landed
    __builtin_amdgcn_s_barrier();                     // all waves done reading buf[cur]
    cur = nxt;
  }

  if (CS) {
    __syncthreads();
    if (tid < 128) { csum[tid] = 0.f; csq[tid] = 0.f; }
    __syncthreads();
  }

#pragma unroll
  for (int ni = 0; ni < 4; ++ni) {
    const int col = n0 + wc*64 + ni*16 + c;
    const float bb = bias[col];
    float ls = 0.f, lq = 0.f;
#pragma unroll
    for (int mi = 0; mi < 4; ++mi) {
#pragma unroll
      for (int q = 0; q < 4; ++q) {
        const int row = m0 + wr*64 + mi*16 + g*4 + q;
        if (row < M) {
          const float v = acc[mi][ni][q] + bb;
          if (OM == 0) Cf[(size_t)row*N + col] = v;
          else if (OM == 1) Ch[(size_t)row*N + col] = f2bf(v);
          else Ch[(size_t)row*N + col] = f2bf(col < HD ? v*0.125f : v);
          if (CS) { ls += v; lq += v*v; }
        }
      }
    }
    if (CS) {
      const int lcol = wc*64 + ni*16 + c;
      atomicAdd(&csum[lcol], ls);
      atomicAdd(&csq[lcol], lq);
    }
  }
  if (CS) {
    __syncthreads();
    if (tid < 128) {
      atomicAdd(&gsum[n0 + tid], csum[tid]);
      atomicAdd(&gsq[n0 + tid], csq[tid]);
    }
  }
}

// ---------- BN pieces ----------

__global__ void bn_finalize(const float* __restrict__ sums, const float* __restrict__ sumsq,
    const float* __restrict__ g, const float* __restrict__ b, int C, float invM,
    float* __restrict__ scale, float* __restrict__ shift) {
  const int c = blockIdx.x*256 + threadIdx.x;
  if (c >= C) return;
  const float mu = sums[c]*invM;
  const float var = sumsq[c]*invM - mu*mu;
  const float sc = rsqrtf(var + 1e-5f) * g[c];
  scale[c] = sc;
  shift[c] = b[c] - mu*sc;
}

__global__ __launch_bounds__(256) void bn1_apply(const ushort* __restrict__ y1,
    const float* __restrict__ scale, const float* __restrict__ shift,
    ushort* __restrict__ srawh, ushort* __restrict__ xbufh) {
  const int i8 = blockIdx.x*256 + threadIdx.x;
  if (i8 >= M1*HD/8) return;
  const int e = i8 << 3;
  const int col = e & (HD - 1);
  const uint4 raw = ((const uint4*)y1)[i8];
  unsigned rw[4] = {raw.x, raw.y, raw.z, raw.w};
  unsigned res[4];
#pragma unroll
  for (int j = 0; j < 4; ++j) {
    float v0 = bf2f((ushort)(rw[j] & 0xffffu));
    float v1 = bf2f((ushort)(rw[j] >> 16));
    v0 = fmaxf(fmaf(v0, scale[col + 2*j],     shift[col + 2*j]),     0.f);
    v1 = fmaxf(fmaf(v1, scale[col + 2*j + 1], shift[col + 2*j + 1]), 0.f);
    res[j] = (unsigned)f2bf(v0) | ((unsigned)f2bf(v1) << 16);
  }
  const uint4 o = make_uint4(res[0], res[1], res[2], res[3]);
  if (e < 25*SEQ*HD) ((uint4*)srawh)[i8] = o;
  else ((uint4*)xbufh)[i8 - (20*SEQ*HD/8)] = o;
}

__global__ void support_mean(const ushort* __restrict__ srawh, ushort* __restrict__ xbufh) {
  const int i8 = blockIdx.x*256 + threadIdx.x;
  if (i8 >= WAYS*SEQ*HD/8) return;
  const int e = i8 << 3;
  const int w = e / (SEQ*HD);
  const int rem = e - w*(SEQ*HD);
  float acc[8] = {};
#pragma unroll
  for (int s = 0; s < SHOTS; ++s) {
    const uint4 v = *(const uint4*)(srawh + (size_t)(s*WAYS + w)*(SEQ*HD) + rem);
    const unsigned rw[4] = {v.x, v.y, v.z, v.w};
#pragma unroll
    for (int j = 0; j < 4; ++j) {
      acc[2*j]   += bf2f((ushort)(rw[j] & 0xffffu));
      acc[2*j+1] += bf2f((ushort)(rw[j] >> 16));
    }
  }
  unsigned res[4];
#pragma unroll
  for (int j = 0; j < 4; ++j)
    res[j] = (unsigned)f2bf(acc[2*j]*0.2f) | ((unsigned)f2bf(acc[2*j+1]*0.2f) << 16);
  ((uint4*)xbufh)[i8] = make_uint4(res[0], res[1], res[2], res[3]);
}

// ---------- attention: QK^T + softmax -> P bf16 [bh][208][232] ----------
// q/k live in fused qkv [MMHA][1536]: q at +0 (pre-scaled 1/8), k at +512.

__global__ __launch_bounds__(256) void attn_qk(const ushort* __restrict__ qkv,
                                               ushort* __restrict__ P) {
  __shared__ ushort Ks[208*72];
  const int bh = blockIdx.x, b = bh >> 3, h = bh & 7;
  const int tid = threadIdx.x;
  for (int idx = tid; idx < 208*8; idx += 256) {
    const int row = idx >> 3, part = idx & 7;
    uint4 v = make_uint4(0u,0u,0u,0u);
    if (row < SEQ)
      v = *(const uint4*)(qkv + (size_t)(b*SEQ + row)*QKVS + 512 + h*64 + part*8);
    *(uint4*)(&Ks[row*72 + part*8]) = v;
  }
  __syncthreads();
  const int w = tid >> 6, lane = tid & 63, g = lane >> 4, c = lane & 15;
  for (int rt = w; rt < 13; rt += 4) {
    int qrow = b*SEQ + rt*16 + c; if (qrow > MMHA-1) qrow = MMHA-1;
    const bf16x8 aq0 = *(const bf16x8*)(qkv + (size_t)qrow*QKVS + h*64 + g*8);
    const bf16x8 aq1 = *(const bf16x8*)(qkv + (size_t)qrow*QKVS + h*64 + 32 + g*8);
    f32x4 acc[13];
#pragma unroll
    for (int ct = 0; ct < 13; ++ct) acc[ct] = (f32x4)(0.0f);
#pragma unroll
    for (int ct = 0; ct < 13; ++ct) {
      const bf16x8 b0 = *(const bf16x8*)(&Ks[(ct*16 + c)*72 + g*8]);
      const bf16x8 b1 = *(const bf16x8*)(&Ks[(ct*16 + c)*72 + 32 + g*8]);
      acc[ct] = mfma16(aq0, b0, acc[ct]);
      acc[ct] = mfma16(aq1, b1, acc[ct]);
    }
    if (c >= 4) acc[12] = (f32x4)(-1e30f);
    float mrow[4], Z[4];
#pragma unroll
    for (int q = 0; q < 4; ++q) {
      float mx = acc[0][q];
#pragma unroll
      for (int ct = 1; ct < 13; ++ct) mx = fmaxf(mx, acc[ct][q]);
      mrow[q] = mx;
    }
#pragma unroll
    for (int q = 0; q < 4; ++q) {
#pragma unroll
      for (int msk = 1; msk < 16; msk <<= 1)
        mrow[q] = fmaxf(mrow[q], __shfl_xor(mrow[q], msk, 64));
    }
#pragma unroll
    for (int q = 0; q < 4; ++q) Z[q] = 0.f;
#pragma unroll
    for (int ct = 0; ct < 13; ++ct)
#pragma unroll
      for (int q = 0; q < 4; ++q) {
        const float e = __expf(acc[ct][q] - mrow[q]);
        acc[ct][q] = e; Z[q] += e;
      }
#pragma unroll
    for (int q = 0; q < 4; ++q) {
#pragma unroll
      for (int msk = 1; msk < 16; msk <<= 1) Z[q] += __shfl_xor(Z[q], msk, 64);
      Z[q] = 1.f / Z[q];
    }
    const size_t pb = (size_t)bh*(208*232);
#pragma unroll
    for (int q = 0; q < 4; ++q) {
      ushort* pr = P + pb + (size_t)(rt*16 + g*4 + q)*232;
#pragma unroll
      for (int ct = 0; ct < 13; ++ct) pr[ct*16 + c] = f2bf(acc[ct][q]*Z[q]);
      pr[208 + c] = 0;
      if (c < 8) pr[224 + c] = 0;
    }
  }
}

// ---------- V transpose (v at qkv+1024) ----------

__global__ __launch_bounds__(256) void v_transpose(const ushort* __restrict__ qkv,
                                                   ushort* __restrict__ VT) {
  __shared__ ushort Vs[196*72];
  const int bh = blockIdx.x, b = bh >> 3, h = bh & 7;
  const int tid = threadIdx.x;
  for (int idx = tid; idx < 196*8; idx += 256) {
    const int row = idx >> 3, part = idx & 7;
    *(uint4*)(&Vs[row*72 + part*8]) =
        *(const uint4*)(qkv + (size_t)(b*SEQ + row)*QKVS + 1024 + h*64 + part*8);
  }
  __syncthreads();
  ushort* o = VT + (size_t)bh*64*224;
  for (int idx = tid; idx < 64*224; idx += 256) {
    const int d = idx/224, s = idx - d*224;
    o[idx] = (s < SEQ) ? Vs[s*72 + d] : (ushort)0;
  }
}

// ---------- P.V ----------

__global__ __launch_bounds__(256) void attn_pv(const ushort* __restrict__ P,
    const ushort* __restrict__ VT, ushort* __restrict__ ctx) {
  __shared__ ushort Ps[112*232];
  const int bh = blockIdx.x, b = bh >> 3, h = bh & 7;
  const int tid = threadIdx.x, w = tid >> 6, lane = tid & 63, g = lane >> 4, c = lane & 15;
  bf16x8 bv[7];
  const ushort* vt = VT + (size_t)bh*64*224 + (size_t)(w*16 + c)*224;
#pragma unroll
  for (int ks = 0; ks < 7; ++ks) bv[ks] = *(const bf16x8*)(vt + ks*32 + g*8);
  const char* pg = (const char*)(P + (size_t)bh*(208*232));
#pragma unroll
  for (int half = 0; half < 2; ++half) {
    const int r0 = half ? 112 : 0;
    const int nbytes = half ? 96*464 : 112*464;
    __syncthreads();
    for (int byte = tid*16; byte < nbytes; byte += 4096)
      *(uint4*)((char*)Ps + byte) = *(const uint4*)(pg + r0*464 + byte);
    __syncthreads();
    const int rtlo = half ? 7 : 0, rthi = half ? 13 : 7;
    for (int rt = rtlo; rt < rthi; ++rt) {
      const int lrow = rt*16 - r0 + c;
      f32x4 acc = (f32x4)(0.0f);
#pragma unroll
      for (int ks = 0; ks < 7; ++ks) {
        const bf16x8 a = *(const bf16x8*)(&Ps[lrow*232 + ks*32 + g*8]);
        acc = mfma16(a, bv[ks], acc);
      }
#pragma unroll
      for (int q = 0; q < 4; ++q) {
        const int srow = rt*16 + g*4 + q;
        if (srow < SEQ)
          ctx[((size_t)(b*SEQ + srow))*HD + h*64 + w*16 + c] = f2bf(acc[q]);
      }
    }
  }
}

// ---------- LayerNorm + residual (tmp fp32 + xin bf16 -> bf16) ----------

__global__ __launch_bounds__(256) void ln_kernel(const float* __restrict__ tmp,
    const ushort* __restrict__ xin, const float* __restrict__ g,
    const float* __restrict__ bta, ushort* __restrict__ outh) {
  const int row = blockIdx.x*4 + (threadIdx.x >> 6);
  const int lane = threadIdx.x & 63;
  const float* t = tmp + (size_t)row*HD;
  const ushort* x = xin + (size_t)row*HD;
  float v[8]; float s = 0.f;
#pragma unroll
  for (int i = 0; i < 8; ++i) {
    const float val = t[i*64 + lane] + bf2f(x[i*64 + lane]);
    v[i] = val; s += val;
  }
  s = waveSum(s);
  const float mu = s * (1.f/HD);
  float sq = 0.f;
#pragma unroll
  for (int i = 0; i < 8; ++i) { const float d = v[i] - mu; sq += d*d; }
  sq = waveSum(sq);
  const float istd = rsqrtf(sq*(1.f/HD) + 1e-5f);
#pragma unroll
  for (int i = 0; i < 8; ++i) {
    const int d = i*64 + lane;
    outh[(size_t)row*HD + d] = f2bf((v[i] - mu)*istd*g[d] + bta[d]);
  }
}

// ---------- prototypes / losses / per-row ----------

__global__ __launch_bounds__(256) void mw_kernel(const ushort* __restrict__ xout,
    const float* __restrict__ Wm, float* __restrict__ m) {
  const int row = blockIdx.x*4 + (threadIdx.x >> 6);
  const int lane = threadIdx.x & 63;
  const ushort* x = xout + (size_t)row*HD;
  float xv[8];
#pragma unroll
  for (int i = 0; i < 8; ++i) xv[i] = bf2f(x[i*64 + lane]);
#pragma unroll
  for (int p = 0; p < PP; ++p) {
    const float* wp = Wm + p*HD;
    float s = 0.f;
#pragma unroll
    for (int i = 0; i < 8; ++i) s = fmaf(xv[i], wp[i*64 + lane], s);
    s = waveSum(s);
    if (lane == 0) m[row*PP + p] = s;
  }
}

__global__ __launch_bounds__(256) void wsm_kernel(const float* __restrict__ m,
                                                  float* __restrict__ wsm) {
  __shared__ float red[256];
  const int p = blockIdx.x, tid = threadIdx.x;
  float lmax = -1e30f;
  for (int r = tid; r < 980; r += 256) lmax = fmaxf(lmax, m[r*PP + p]);
  red[tid] = lmax; __syncthreads();
  for (int s = 128; s; s >>= 1) { if (tid < s) red[tid] = fmaxf(red[tid], red[tid+s]); __syncthreads(); }
  const float bmax = red[0]; __syncthreads();
  float lsum = 0.f;
  for (int r = tid; r < 980; r += 256) {
    const float e = __expf(m[r*PP + p] - bmax);
    wsm[p*980 + r] = e; lsum += e;
  }
  red[tid] = lsum; __syncthreads();
  for (int s = 128; s; s >>= 1) { if (tid < s) red[tid] += red[tid+s]; __syncthreads(); }
  const float invZ = 1.f / red[0];
  for (int r = tid; r < 980; r += 256) wsm[p*980 + r] *= invZ;
}

__global__ __launch_bounds__(256) void protos_part(const float* __restrict__ wsm,
    const ushort* __restrict__ xout, float* __restrict__ part) {
  const int p = blockIdx.y, chunk = blockIdx.x, tid = threadIdx.x;
  const int r0 = chunk*49;
  float a0 = 0.f, a1 = 0.f;
  for (int r = r0; r < r0 + 49; ++r) {
    const float w = wsm[p*980 + r];
    a0 = fmaf(w, bf2f(xout[(size_t)r*HD + tid]), a0);
    a1 = fmaf(w, bf2f(xout[(size_t)r*HD + tid + 256]), a1);
  }
  float* o = part + (((size_t)p*20 + chunk) << 9);
  o[tid] = a0;
  o[tid + 256] = a1;
}

__global__ __launch_bounds__(256) void protos_fin(const float* __restrict__ part,
                                                  float* __restrict__ pn) {
  __shared__ float red[256];
  const int p = blockIdx.x, tid = threadIdx.x;
  float a0 = 0.f, a1 = 0.f;
  for (int cch = 0; cch < 20; ++cch) {
    const float* o = part + (((size_t)p*20 + cch) << 9);
    a0 += o[tid];
    a1 += o[tid + 256];
  }
  red[tid] = a0*a0 + a1*a1; __syncthreads();
  for (int s = 128; s; s >>= 1) { if (tid < s) red[tid] += red[tid+s]; __syncthreads(); }
  const float rn = 1.f / fmaxf(sqrtf(red[0]), 1e-12f);
  pn[p*HD + tid] = a0*rn;
  pn[p*HD + tid + 256] = a1*rn;
}

__global__ __launch_bounds__(256) void losses_kernel(const float* __restrict__ pn, float* __restrict__ out) {
  __shared__ float redc[256], redd[256];
  const int tid = threadIdx.x;
  float cpart = 0.f, dpart = 0.f;
  for (int d = tid; d < HD; d += 256) {
    float a[PP];
#pragma unroll
    for (int j = 0; j < PP; ++j) a[j] = pn[j*HD + d];
#pragma unroll
    for (int j = 0; j < PP; ++j) {
      if (d > j) {
#pragma unroll
        for (int i = 0; i < PP; ++i) {
          const float df = a[j] - a[i];
          const float t = 1.f - df*df;
          if (t > 0.f) dpart += t;
        }
      }
    }
#pragma unroll
    for (int j = 0; j < PP - 1; ++j) { const float df = a[j+1] - a[j]; cpart += df*df; }
  }
  redc[tid] = cpart; redd[tid] = dpart; __syncthreads();
  for (int s = 128; s; s >>= 1) {
    if (tid < s) { redc[tid] += redc[tid+s]; redd[tid] += redd[tid+s]; }
    __syncthreads();
  }
  if (tid == 0) {
    out[OUT_UPD + 1] = redc[0] / 9.f;
    out[OUT_UPD + 2] = redd[0] * (2.f / (90.f * 512.f));
  }
}

__global__ __launch_bounds__(256) void rowk(const ushort* __restrict__ xout, const float* __restrict__ pn,
    ushort* __restrict__ newq, float* __restrict__ feapart) {
  __shared__ float Ps[PP*HD];
  __shared__ float fred[4];
  const int tid = threadIdx.x;
  for (int idx = tid; idx < PP*HD; idx += 256) Ps[idx] = pn[idx];
  __syncthreads();
  const int row = blockIdx.x*4 + (tid >> 6);
  const int lane = tid & 63;
  const ushort* x = xout + (size_t)(WAYS*SEQ + row)*HD;
  float xv[8];
#pragma unroll
  for (int i = 0; i < 8; ++i) xv[i] = bf2f(x[i*64 + lane]);
  float sc[PP];
#pragma unroll
  for (int p = 0; p < PP; ++p) {
    float s = 0.f;
#pragma unroll
    for (int i = 0; i < 8; ++i) s = fmaf(xv[i], Ps[p*HD + i*64 + lane], s);
    sc[p] = waveSum(s);
  }
  float mx = sc[0]; int am = 0;
#pragma unroll
  for (int p = 1; p < PP; ++p) if (sc[p] > mx) { mx = sc[p]; am = p; }
  float Z = 0.f; float sp[PP];
#pragma unroll
  for (int p = 0; p < PP; ++p) { const float e = expf(sc[p] - mx); sp[p] = e; Z += e; }
  const float rz = 1.f / Z;
  float nv[8]; float ss = 0.f;
#pragma unroll
  for (int i = 0; i < 8; ++i) {
    float a = 0.f;
#pragma unroll
    for (int p = 0; p < PP; ++p) a = fmaf(sp[p], Ps[p*HD + i*64 + lane], a);
    a *= rz; nv[i] = a; ss += a*a;
  }
  ss = waveSum(ss);
  const float rn = 1.f / fmaxf(sqrtf(ss), 1e-12f);
#pragma unroll
  for (int i = 0; i < 8; ++i) newq[(size_t)row*HD + i*64 + lane] = f2bf(nv[i]*rn);
  float fp = 0.f;
#pragma unroll
  for (int i = 0; i < 8; ++i) { const float d = xv[i] - Ps[am*HD + i*64 + lane]; fp += d*d; }
  fp = waveSum(fp);
  if (lane == 0) fred[tid >> 6] = fp;
  __syncthreads();
  if (tid == 0) feapart[blockIdx.x] = fred[0] + fred[1] + fred[2] + fred[3];
}

__global__ __launch_bounds__(256) void fea_finalize(const float* __restrict__ feapart,
                                                    float* __restrict__ out) {
  __shared__ float red[256];
  float s = 0.f;
  for (int i = threadIdx.x; i < NBLK_ROWK; i += 256) s += feapart[i];
  red[threadIdx.x] = s; __syncthreads();
  for (int st = 128; st; st >>= 1) {
    if (threadIdx.x < st) red[threadIdx.x] += red[threadIdx.x + st];
    __syncthreads();
  }
  if (threadIdx.x == 0) out[OUT_UPD] = red[0] / (float)((size_t)NQB*SEQ*HD);
}

__global__ __launch_bounds__(256) void bn2_apply(const float* __restrict__ y2, const float* __restrict__ scale,
    const float* __restrict__ shift, const float* __restrict__ query, float* __restrict__ out) {
  __shared__ float tile[32][33];
  const int n = blockIdx.z, o0 = blockIdx.y*32, hw0 = blockIdx.x*32;
  const int tj = threadIdx.x & 31, ti = threadIdx.x >> 5;
#pragma unroll
  for (int it = 0; it < 4; ++it) {
    const int hw = hw0 + it*8 + ti;
    const int o = o0 + tj;
    float v = 0.f;
    if (hw < SEQ) v = fmaxf(fmaf(y2[((size_t)n*SEQ + hw)*FDIMC + o], scale[o], shift[o]), 0.f);
    tile[it*8 + ti][tj] = v;
  }
  __syncthreads();
#pragma unroll
  for (int it = 0; it < 4; ++it) {
    const int o = o0 + it*8 + ti;
    const int hw = hw0 + tj;
    if (hw < SEQ) {
      const size_t oi = ((size_t)n*FDIMC + o)*SEQ + hw;
      out[oi] = tile[tj][it*8 + ti] + query[oi];
    }
  }
}

extern "C" void kernel_launch(void* const* d_in, const int* in_sizes, int n_in,
                              void* d_out, int out_size, void* d_ws, size_t ws_size,
                              hipStream_t stream) {
  const float* key   = (const float*)d_in[0];
  const float* query = (const float*)d_in[1];
  const float* Wc    = (const float*)d_in[2];
  const float* bc    = (const float*)d_in[3];
  const float* g1    = (const float*)d_in[4];
  const float* b1    = (const float*)d_in[5];
  const float* Wq    = (const float*)d_in[6];
  const float* bq    = (const float*)d_in[7];
  const float* Wk    = (const float*)d_in[8];
  const float* bk    = (const float*)d_in[9];
  const float* Wv    = (const float*)d_in[10];
  const float* bv    = (const float*)d_in[11];
  const float* Wa    = (const float*)d_in[12];
  const float* ba    = (const float*)d_in[13];
  const float* ln_g  = (const float*)d_in[14];
  const float* ln_b  = (const float*)d_in[15];
  const float* Wm    = (const float*)d_in[16];
  const float* Wo    = (const float*)d_in[17];
  const float* bo    = (const float*)d_in[18];
  const float* g2    = (const float*)d_in[19];
  const float* b2    = (const float*)d_in[20];
  float* out = (float*)d_out;
  float* w = (float*)d_ws;

  ushort* y1h   = (ushort*)(w + RB);
  ushort* P     = (ushort*)(w + RB);
  float*  y2f   = w + RB;
  ushort* xouth = (ushort*)(w + OFF_XOUT);
  ushort* VT    = (ushort*)(w + RC);
  ushort* keyT  = (ushort*)(w + RD);
  float*  tmpf  = w + RD;
  ushort* xbufh = (ushort*)(w + RE);
  ushort* srawh = (ushort*)(w + RF);
  ushort* newq  = (ushort*)(w + RF);
  ushort* ctx   = (ushort*)(w + RG);
  ushort* wh    = (ushort*)(w + RH);
  ushort* qkv   = (ushort*)(w + RQ);
  float*  feapart = w + OFF_FEAP;
  float*  bqkv  = w + OFF_BQKV;
  float*  wsm   = w + OFF_WSM;
  float*  ppart = w + OFF_PPART;
  ushort* Wcb = wh;
  ushort* Wqb = wh + 327680;     // [Wq;Wk;Wv] contiguous = fused [1536,512]
  ushort* Wab = wh + 1114112;
  ushort* Wob = wh + 1376256;

  hipMemsetAsync(w, 0, ZERO_FLOATS*sizeof(float), stream);

  key_transpose<<<dim3(7, 20, NB), 256, 0, stream>>>(key, keyT);
  wconvert<<<6656, 256, 0, stream>>>(Wc, Wq, Wk, Wv, Wa, Wo, wh);
  qkv_bias<<<6, 256, 0, stream>>>(bq, bk, bv, bqkv);

  // conv1 (bf16 MFMA, 2-phase pipeline, fused BN col-stats) -> y1h bf16
  gemm_bf<1,1><<<dim3(4, 154), 256, 0, stream>>>(keyT, Wcb, bc, nullptr, y1h, M1, HD, FDIMC,
                                                 w + OFF_CS1S, w + OFF_CS1Q);
  bn_finalize<<<2, 256, 0, stream>>>(w + OFF_CS1S, w + OFF_CS1Q, g1, b1, HD, 1.f/M1,
                                     w + OFF_ST1SC, w + OFF_ST1SH);
  bn1_apply<<<M1*HD/8/256, 256, 0, stream>>>(y1h, w + OFF_ST1SC, w + OFF_ST1SH, srawh, xbufh);
  support_mean<<<WAYS*SEQ*HD/8/256, 256, 0, stream>>>(srawh, xbufh);

  // fused QKV projection: N=1536, q-range scaled by 1/8 in epilogue
  gemm_bf<3,0><<<dim3(12, 123), 256, 0, stream>>>(xbufh, Wqb, bqkv, nullptr, qkv,
                                                  MMHA, QKVS, HD, nullptr, nullptr);

  v_transpose<<<NMHA*8, 256, 0, stream>>>(qkv, VT);
  attn_qk<<<NMHA*8, 256, 0, stream>>>(qkv, P);
  attn_pv<<<NMHA*8, 256, 0, stream>>>(P, VT, ctx);

  // out-proj -> tmp fp32 (precision-critical: pre-LN residual path)
  gemm_bf<0,0><<<dim3(4, 123), 256, 0, stream>>>(ctx, Wab, ba, tmpf, nullptr, MMHA, HD, HD, nullptr, nullptr);
  ln_kernel<<<MMHA/4, 256, 0, stream>>>(tmpf, xbufh, ln_g, ln_b, xouth);

  // prototypes + losses
  mw_kernel<<<245, 256, 0, stream>>>(xouth, Wm, w + OFF_M);
  wsm_kernel<<<PP, 256, 0, stream>>>(w + OFF_M, wsm);
  protos_part<<<dim3(20, PP), 256, 0, stream>>>(wsm, xouth, ppart);
  protos_fin<<<PP, 256, 0, stream>>>(ppart, w + OFF_PN);
  losses_kernel<<<1, 256, 0, stream>>>(w + OFF_PN, out);
  rowk<<<NBLK_ROWK, 256, 0, stream>>>(xouth, w + OFF_PN, newq, feapart);

  // conv2 -> y2 fp32 (precision-critical), fused BN col-stats
  gemm_bf<0,1><<<dim3(5, 115), 256, 0, stream>>>(newq, Wob, bo, y2f, nullptr, MQ, FDIMC, HD,
                                                 w + OFF_CS2S, w + OFF_CS2Q);
  bn_finalize<<<3, 256, 0, stream>>>(w + OFF_CS2S, w + OFF_CS2Q, g2, b2, FDIMC, 1.f/MQ,
                                     w + OFF_ST2SC, w + OFF_ST2SH);
  fea_finalize<<<1, 256, 0, stream>>>(feapart, out);
  bn2_apply<<<dim3(7, 20, NQB), 256, 0, stream>>>(y2f, w + OFF_ST2SC, w + OFF_ST2SH, query, out);
}

// Round 12
// 342.879 us; speedup vs baseline: 5.1028x; 1.0023x over previous
//
#include <hip/hip_runtime.h>
#include <math.h>

// ---- problem constants ----
#define WAYS 5
#define SHOTS 5
#define PP 10
#define FDIMC 640
#define HD 512
#define QKVS 1536
#define SEQ 196
#define NB 100
#define NQB 75
#define NMHA 80
#define M1 (NB*SEQ)       // 19600
#define MMHA (NMHA*SEQ)   // 15680
#define MQ (NQB*SEQ)      // 14700
#define NBLK_ROWK (MQ/4)  // 3675
#define OUT_UPD (NQB*FDIMC*SEQ)  // 9,408,000

// ---- small stats block (float offsets) ----
#define OFF_CS1S 0
#define OFF_CS1Q 512
#define OFF_CS2S 1024
#define OFF_CS2Q 1664
#define ZERO_FLOATS 2306
#define OFF_ST1SC 2308
#define OFF_ST1SH 2820
#define OFF_ST2SC 3332
#define OFF_ST2SH 3972
#define OFF_M    4612
#define OFF_PN   14412

// ---- big regions (float offsets) ----
#define RB 20480                   /* y1h bf16 / P bf16 / y2 fp32 ; xouth at +10M */
#define RC (RB + 15439360)         /* VT bf16 */
#define RD (RC + 8028160)          /* keyT bf16 -> tmp fp32 */
#define RE (RD + 8028160)          /* xbufh bf16 */
#define RF (RE + 8028160)          /* srawh bf16 -> newq bf16 + feapart + bqkv */
#define RG (RF + 4014080)          /* ctx bf16 -> wsm/ppart */
#define RH (RG + 4014080)          /* weights bf16 concat */
#define RQ 48424960                /* qkv bf16 [MMHA][1536] */
#define OFF_XOUT (RB + 10000000)
#define OFF_FEAP (RF + 3763200)
#define OFF_BQKV (RF + 3767296)
#define OFF_WSM  RG
#define OFF_PPART (RG + 16384)

typedef __bf16 bf16x8 __attribute__((ext_vector_type(8)));
typedef float f32x4 __attribute__((ext_vector_type(4)));

__device__ __forceinline__ ushort f2bf(float f) {
  unsigned u = __float_as_uint(f);
  return (ushort)((u + 0x7fffu + ((u >> 16) & 1u)) >> 16);
}
__device__ __forceinline__ float bf2f(ushort u) {
  return __uint_as_float(((unsigned)u) << 16);
}

__device__ __forceinline__ f32x4 mfma16(bf16x8 a, bf16x8 b, f32x4 c) {
  return __builtin_amdgcn_mfma_f32_16x16x32_bf16(a, b, c, 0, 0, 0);
}

__device__ __forceinline__ float waveSum(float v) {
#pragma unroll
  for (int o = 32; o; o >>= 1) v += __shfl_xor(v, o, 64);
  return v;
}

// async global -> LDS, 16 B per lane (wave-uniform LDS base + lane*16)
__device__ __forceinline__ void gld16(const void* g, void* l) {
  __builtin_amdgcn_global_load_lds(
      (const __attribute__((address_space(1))) void*)g,
      (__attribute__((address_space(3))) void*)l,
      16, 0, 0);
}

// ---------- transposes / converts ----------

__global__ __launch_bounds__(256) void key_transpose(const float* __restrict__ key,
                                                     ushort* __restrict__ keyT) {
  __shared__ float T[32][33];
  const int n = blockIdx.z, c0 = blockIdx.y*32, s0 = blockIdx.x*32;
  const int tj = threadIdx.x & 31, ti = threadIdx.x >> 5;
#pragma unroll
  for (int it = 0; it < 4; ++it) {
    const int cl = it*8 + ti;
    const int s = s0 + tj;
    T[cl][tj] = (s < SEQ) ? key[((size_t)n*FDIMC + c0 + cl)*SEQ + s] : 0.f;
  }
  __syncthreads();
#pragma unroll
  for (int it = 0; it < 4; ++it) {
    const int sl = it*8 + ti;
    const int s = s0 + sl;
    if (s < SEQ) keyT[((size_t)(n*SEQ + s))*FDIMC + c0 + tj] = f2bf(T[tj][sl]);
  }
}

__global__ void wconvert(const float* __restrict__ Wc, const float* __restrict__ Wq,
                         const float* __restrict__ Wk, const float* __restrict__ Wv,
                         const float* __restrict__ Wa, const float* __restrict__ Wo,
                         ushort* __restrict__ wh) {
  const int i = blockIdx.x*256 + threadIdx.x;
  float v;
  if (i < 327680) v = Wc[i];
  else if (i < 589824) v = Wq[i - 327680];
  else if (i < 851968) v = Wk[i - 589824];
  else if (i < 1114112) v = Wv[i - 851968];
  else if (i < 1376256) v = Wa[i - 1114112];
  else v = Wo[i - 1376256];
  wh[i] = f2bf(v);
}

__global__ void qkv_bias(const float* __restrict__ bq, const float* __restrict__ bk,
                         const float* __restrict__ bv, float* __restrict__ o) {
  const int i = blockIdx.x*256 + threadIdx.x;
  if (i >= QKVS) return;
  o[i] = (i < 512) ? bq[i] : (i < 1024 ? bk[i-512] : bv[i-1024]);
}

// ---------- bf16 MFMA GEMM: C = A(MxK) . W(NxK)^T + bias ----------
// OM: 0 -> fp32 out, 1 -> bf16 out, 3 -> bf16 out, cols<HD scaled by 0.125 (QKV)
// CS: 1 -> accumulate per-column sum/sumsq of fp32 output into gsum/gsq
// 2-phase double-buffered LDS, gload_lds staging with 2-way-free slot swizzle:
//   LDS slot s of row r holds k-slot s ^ ((r&15)>>1 & 3)  (source pre-swizzle),
//   fragment read at slot g ^ ((c>>1)&3) recovers k-slot g (both-sides, rule #21).
// Bijective XCD-aware block swizzle. Direct scatter stores (round-8 epilogue).
template<int OM, int CS>
__global__ __launch_bounds__(256) void gemm_bf(const ushort* __restrict__ A,
    const ushort* __restrict__ W, const float* __restrict__ bias,
    float* __restrict__ Cf, ushort* __restrict__ Ch, int M, int N, int K,
    float* __restrict__ gsum, float* __restrict__ gsq) {
  __shared__ ushort As[2][128*32];
  __shared__ ushort Bs[2][128*32];
  __shared__ float csum[128], csq[128];
  const int tid = threadIdx.x;

  // XCD-aware bijective swizzle (m204)
  const int nwg = gridDim.x * gridDim.y;
  int flat = blockIdx.y * gridDim.x + blockIdx.x;
  {
    const int q = nwg >> 3, r = nwg & 7;
    const int j = flat & 7, tt = flat >> 3;
    flat = (j < r ? j*(q+1) : r*(q+1) + (j-r)*q) + tt;
  }
  const int m0 = (flat / gridDim.x) * 128;
  const int n0 = (flat % gridDim.x) * 128;

  const int w = tid >> 6, lane = tid & 63;
  const int wr = w >> 1, wc = w & 1;
  const int g = lane >> 4, c = lane & 15;

  // staging: wave w owns chunks {w, 4+w}; source k-slot swizzled (2-way-free)
  const int srow = w*16 + (lane >> 2);
  const int sk = ((lane & 3) ^ ((lane >> 3) & 3)) * 8;
  int ar0 = m0 + srow;       if (ar0 > M-1) ar0 = M-1;
  int ar1 = m0 + 64 + srow;  if (ar1 > M-1) ar1 = M-1;
  const ushort* Ap0 = A + (size_t)ar0*K + sk;
  const ushort* Ap1 = A + (size_t)ar1*K + sk;
  const ushort* Bp0 = W + (size_t)(n0 + srow)*K + sk;
  const ushort* Bp1 = W + (size_t)(n0 + 64 + srow)*K + sk;

  f32x4 acc[4][4];
#pragma unroll
  for (int i = 0; i < 4; ++i)
#pragma unroll
    for (int j = 0; j < 4; ++j) acc[i][j] = (f32x4)(0.0f);

  const int nt = K >> 5;
  // prologue: stage tile 0 -> buf 0
  gld16(Ap0, &As[0][w*512]);
  gld16(Ap1, &As[0][(4+w)*512]);
  gld16(Bp0, &Bs[0][w*512]);
  gld16(Bp1, &Bs[0][(4+w)*512]);
  asm volatile("s_waitcnt vmcnt(0)" ::: "memory");
  __builtin_amdgcn_s_barrier();

  int cur = 0;
  for (int t = 0; t < nt; ++t) {
    const int nxt = cur ^ 1;
    if (t + 1 < nt) {                      // issue next tile while computing
      const int k0 = (t + 1) << 5;
      gld16(Ap0 + k0, &As[nxt][w*512]);
      gld16(Ap1 + k0, &As[nxt][(4+w)*512]);
      gld16(Bp0 + k0, &Bs[nxt][w*512]);
      gld16(Bp1 + k0, &Bs[nxt][(4+w)*512]);
    }
    bf16x8 af[4], bfr[4];
    const int rslot = (g ^ ((c >> 1) & 3)) * 8;
#pragma unroll
    for (int mi = 0; mi < 4; ++mi) {
      const int row = wr*64 + mi*16 + c;
      af[mi] = *(const bf16x8*)(&As[cur][row*32 + rslot]);
    }
#pragma unroll
    for (int ni = 0; ni < 4; ++ni) {
      const int row = wc*64 + ni*16 + c;
      bfr[ni] = *(const bf16x8*)(&Bs[cur][row*32 + rslot]);
    }
#pragma unroll
    for (int mi = 0; mi < 4; ++mi)
#pragma unroll
      for (int ni = 0; ni < 4; ++ni)
        acc[mi][ni] = mfma16(af[mi], bfr[ni], acc[mi][ni]);
    asm volatile("s_waitcnt vmcnt(0)" ::: "memory");  // own next-tile loads landed
    __builtin_amdgcn_s_barrier();                     // all waves done reading buf[cur]
    cur = nxt;
  }

  if (CS) {
    __syncthreads();
    if (tid < 128) { csum[tid] = 0.f; csq[tid] = 0.f; }
    __syncthreads();
  }

#pragma unroll
  for (int ni = 0; ni < 4; ++ni) {
    const int col = n0 + wc*64 + ni*16 + c;
    const float bb = bias[col];
    float ls = 0.f, lq = 0.f;
#pragma unroll
    for (int mi = 0; mi < 4; ++mi) {
#pragma unroll
      for (int q = 0; q < 4; ++q) {
        const int row = m0 + wr*64 + mi*16 + g*4 + q;
        if (row < M) {
          const float v = acc[mi][ni][q] + bb;
          if (OM == 0) Cf[(size_t)row*N + col] = v;
          else if (OM == 1) Ch[(size_t)row*N + col] = f2bf(v);
          else Ch[(size_t)row*N + col] = f2bf(col < HD ? v*0.125f : v);
          if (CS) { ls += v; lq += v*v; }
        }
      }
    }
    if (CS) {
      const int lcol = wc*64 + ni*16 + c;
      atomicAdd(&csum[lcol], ls);
      atomicAdd(&csq[lcol], lq);
    }
  }
  if (CS) {
    __syncthreads();
    if (tid < 128) {
      atomicAdd(&gsum[n0 + tid], csum[tid]);
      atomicAdd(&gsq[n0 + tid], csq[tid]);
    }
  }
}

// ---------- BN pieces ----------

__global__ void bn_finalize(const float* __restrict__ sums, const float* __restrict__ sumsq,
    const float* __restrict__ g, const float* __restrict__ b, int C, float invM,
    float* __restrict__ scale, float* __restrict__ shift) {
  const int c = blockIdx.x*256 + threadIdx.x;
  if (c >= C) return;
  const float mu = sums[c]*invM;
  const float var = sumsq[c]*invM - mu*mu;
  const float sc = rsqrtf(var + 1e-5f) * g[c];
  scale[c] = sc;
  shift[c] = b[c] - mu*sc;
}

__global__ __launch_bounds__(256) void bn1_apply(const ushort* __restrict__ y1,
    const float* __restrict__ scale, const float* __restrict__ shift,
    ushort* __restrict__ srawh, ushort* __restrict__ xbufh) {
  const int i8 = blockIdx.x*256 + threadIdx.x;
  if (i8 >= M1*HD/8) return;
  const int e = i8 << 3;
  const int col = e & (HD - 1);
  const uint4 raw = ((const uint4*)y1)[i8];
  unsigned rw[4] = {raw.x, raw.y, raw.z, raw.w};
  unsigned res[4];
#pragma unroll
  for (int j = 0; j < 4; ++j) {
    float v0 = bf2f((ushort)(rw[j] & 0xffffu));
    float v1 = bf2f((ushort)(rw[j] >> 16));
    v0 = fmaxf(fmaf(v0, scale[col + 2*j],     shift[col + 2*j]),     0.f);
    v1 = fmaxf(fmaf(v1, scale[col + 2*j + 1], shift[col + 2*j + 1]), 0.f);
    res[j] = (unsigned)f2bf(v0) | ((unsigned)f2bf(v1) << 16);
  }
  const uint4 o = make_uint4(res[0], res[1], res[2], res[3]);
  if (e < 25*SEQ*HD) ((uint4*)srawh)[i8] = o;
  else ((uint4*)xbufh)[i8 - (20*SEQ*HD/8)] = o;
}

__global__ void support_mean(const ushort* __restrict__ srawh, ushort* __restrict__ xbufh) {
  const int i8 = blockIdx.x*256 + threadIdx.x;
  if (i8 >= WAYS*SEQ*HD/8) return;
  const int e = i8 << 3;
  const int w = e / (SEQ*HD);
  const int rem = e - w*(SEQ*HD);
  float acc[8] = {};
#pragma unroll
  for (int s = 0; s < SHOTS; ++s) {
    const uint4 v = *(const uint4*)(srawh + (size_t)(s*WAYS + w)*(SEQ*HD) + rem);
    const unsigned rw[4] = {v.x, v.y, v.z, v.w};
#pragma unroll
    for (int j = 0; j < 4; ++j) {
      acc[2*j]   += bf2f((ushort)(rw[j] & 0xffffu));
      acc[2*j+1] += bf2f((ushort)(rw[j] >> 16));
    }
  }
  unsigned res[4];
#pragma unroll
  for (int j = 0; j < 4; ++j)
    res[j] = (unsigned)f2bf(acc[2*j]*0.2f) | ((unsigned)f2bf(acc[2*j+1]*0.2f) << 16);
  ((uint4*)xbufh)[i8] = make_uint4(res[0], res[1], res[2], res[3]);
}

// ---------- attention: QK^T + softmax -> P bf16 [bh][208][232] ----------
// q/k live in fused qkv [MMHA][1536]: q at +0 (pre-scaled 1/8), k at +512.

__global__ __launch_bounds__(256) void attn_qk(const ushort* __restrict__ qkv,
                                               ushort* __restrict__ P) {
  __shared__ ushort Ks[208*72];
  const int bh = blockIdx.x, b = bh >> 3, h = bh & 7;
  const int tid = threadIdx.x;
  for (int idx = tid; idx < 208*8; idx += 256) {
    const int row = idx >> 3, part = idx & 7;
    uint4 v = make_uint4(0u,0u,0u,0u);
    if (row < SEQ)
      v = *(const uint4*)(qkv + (size_t)(b*SEQ + row)*QKVS + 512 + h*64 + part*8);
    *(uint4*)(&Ks[row*72 + part*8]) = v;
  }
  __syncthreads();
  const int w = tid >> 6, lane = tid & 63, g = lane >> 4, c = lane & 15;
  for (int rt = w; rt < 13; rt += 4) {
    int qrow = b*SEQ + rt*16 + c; if (qrow > MMHA-1) qrow = MMHA-1;
    const bf16x8 aq0 = *(const bf16x8*)(qkv + (size_t)qrow*QKVS + h*64 + g*8);
    const bf16x8 aq1 = *(const bf16x8*)(qkv + (size_t)qrow*QKVS + h*64 + 32 + g*8);
    f32x4 acc[13];
#pragma unroll
    for (int ct = 0; ct < 13; ++ct) acc[ct] = (f32x4)(0.0f);
#pragma unroll
    for (int ct = 0; ct < 13; ++ct) {
      const bf16x8 b0 = *(const bf16x8*)(&Ks[(ct*16 + c)*72 + g*8]);
      const bf16x8 b1 = *(const bf16x8*)(&Ks[(ct*16 + c)*72 + 32 + g*8]);
      acc[ct] = mfma16(aq0, b0, acc[ct]);
      acc[ct] = mfma16(aq1, b1, acc[ct]);
    }
    if (c >= 4) acc[12] = (f32x4)(-1e30f);
    float mrow[4], Z[4];
#pragma unroll
    for (int q = 0; q < 4; ++q) {
      float mx = acc[0][q];
#pragma unroll
      for (int ct = 1; ct < 13; ++ct) mx = fmaxf(mx, acc[ct][q]);
      mrow[q] = mx;
    }
#pragma unroll
    for (int q = 0; q < 4; ++q) {
#pragma unroll
      for (int msk = 1; msk < 16; msk <<= 1)
        mrow[q] = fmaxf(mrow[q], __shfl_xor(mrow[q], msk, 64));
    }
#pragma unroll
    for (int q = 0; q < 4; ++q) Z[q] = 0.f;
#pragma unroll
    for (int ct = 0; ct < 13; ++ct)
#pragma unroll
      for (int q = 0; q < 4; ++q) {
        const float e = __expf(acc[ct][q] - mrow[q]);
        acc[ct][q] = e; Z[q] += e;
      }
#pragma unroll
    for (int q = 0; q < 4; ++q) {
#pragma unroll
      for (int msk = 1; msk < 16; msk <<= 1) Z[q] += __shfl_xor(Z[q], msk, 64);
      Z[q] = 1.f / Z[q];
    }
    const size_t pb = (size_t)bh*(208*232);
#pragma unroll
    for (int q = 0; q < 4; ++q) {
      ushort* pr = P + pb + (size_t)(rt*16 + g*4 + q)*232;
#pragma unroll
      for (int ct = 0; ct < 13; ++ct) pr[ct*16 + c] = f2bf(acc[ct][q]*Z[q]);
      pr[208 + c] = 0;
      if (c < 8) pr[224 + c] = 0;
    }
  }
}

// ---------- V transpose (v at qkv+1024) ----------

__global__ __launch_bounds__(256) void v_transpose(const ushort* __restrict__ qkv,
                                                   ushort* __restrict__ VT) {
  __shared__ ushort Vs[196*72];
  const int bh = blockIdx.x, b = bh >> 3, h = bh & 7;
  const int tid = threadIdx.x;
  for (int idx = tid; idx < 196*8; idx += 256) {
    const int row = idx >> 3, part = idx & 7;
    *(uint4*)(&Vs[row*72 + part*8]) =
        *(const uint4*)(qkv + (size_t)(b*SEQ + row)*QKVS + 1024 + h*64 + part*8);
  }
  __syncthreads();
  ushort* o = VT + (size_t)bh*64*224;
  for (int idx = tid; idx < 64*224; idx += 256) {
    const int d = idx/224, s = idx - d*224;
    o[idx] = (s < SEQ) ? Vs[s*72 + d] : (ushort)0;
  }
}

// ---------- P.V ----------

__global__ __launch_bounds__(256) void attn_pv(const ushort* __restrict__ P,
    const ushort* __restrict__ VT, ushort* __restrict__ ctx) {
  __shared__ ushort Ps[112*232];
  const int bh = blockIdx.x, b = bh >> 3, h = bh & 7;
  const int tid = threadIdx.x, w = tid >> 6, lane = tid & 63, g = lane >> 4, c = lane & 15;
  bf16x8 bv[7];
  const ushort* vt = VT + (size_t)bh*64*224 + (size_t)(w*16 + c)*224;
#pragma unroll
  for (int ks = 0; ks < 7; ++ks) bv[ks] = *(const bf16x8*)(vt + ks*32 + g*8);
  const char* pg = (const char*)(P + (size_t)bh*(208*232));
#pragma unroll
  for (int half = 0; half < 2; ++half) {
    const int r0 = half ? 112 : 0;
    const int nbytes = half ? 96*464 : 112*464;
    __syncthreads();
    for (int byte = tid*16; byte < nbytes; byte += 4096)
      *(uint4*)((char*)Ps + byte) = *(const uint4*)(pg + r0*464 + byte);
    __syncthreads();
    const int rtlo = half ? 7 : 0, rthi = half ? 13 : 7;
    for (int rt = rtlo; rt < rthi; ++rt) {
      const int lrow = rt*16 - r0 + c;
      f32x4 acc = (f32x4)(0.0f);
#pragma unroll
      for (int ks = 0; ks < 7; ++ks) {
        const bf16x8 a = *(const bf16x8*)(&Ps[lrow*232 + ks*32 + g*8]);
        acc = mfma16(a, bv[ks], acc);
      }
#pragma unroll
      for (int q = 0; q < 4; ++q) {
        const int srow = rt*16 + g*4 + q;
        if (srow < SEQ)
          ctx[((size_t)(b*SEQ + srow))*HD + h*64 + w*16 + c] = f2bf(acc[q]);
      }
    }
  }
}

// ---------- LayerNorm + residual (tmp fp32 + xin bf16 -> bf16) ----------

__global__ __launch_bounds__(256) void ln_kernel(const float* __restrict__ tmp,
    const ushort* __restrict__ xin, const float* __restrict__ g,
    const float* __restrict__ bta, ushort* __restrict__ outh) {
  const int row = blockIdx.x*4 + (threadIdx.x >> 6);
  const int lane = threadIdx.x & 63;
  const float* t = tmp + (size_t)row*HD;
  const ushort* x = xin + (size_t)row*HD;
  float v[8]; float s = 0.f;
#pragma unroll
  for (int i = 0; i < 8; ++i) {
    const float val = t[i*64 + lane] + bf2f(x[i*64 + lane]);
    v[i] = val; s += val;
  }
  s = waveSum(s);
  const float mu = s * (1.f/HD);
  float sq = 0.f;
#pragma unroll
  for (int i = 0; i < 8; ++i) { const float d = v[i] - mu; sq += d*d; }
  sq = waveSum(sq);
  const float istd = rsqrtf(sq*(1.f/HD) + 1e-5f);
#pragma unroll
  for (int i = 0; i < 8; ++i) {
    const int d = i*64 + lane;
    outh[(size_t)row*HD + d] = f2bf((v[i] - mu)*istd*g[d] + bta[d]);
  }
}

// ---------- prototypes / losses / per-row ----------

__global__ __launch_bounds__(256) void mw_kernel(const ushort* __restrict__ xout,
    const float* __restrict__ Wm, float* __restrict__ m) {
  const int row = blockIdx.x*4 + (threadIdx.x >> 6);
  const int lane = threadIdx.x & 63;
  const ushort* x = xout + (size_t)row*HD;
  float xv[8];
#pragma unroll
  for (int i = 0; i < 8; ++i) xv[i] = bf2f(x[i*64 + lane]);
#pragma unroll
  for (int p = 0; p < PP; ++p) {
    const float* wp = Wm + p*HD;
    float s = 0.f;
#pragma unroll
    for (int i = 0; i < 8; ++i) s = fmaf(xv[i], wp[i*64 + lane], s);
    s = waveSum(s);
    if (lane == 0) m[row*PP + p] = s;
  }
}

__global__ __launch_bounds__(256) void wsm_kernel(const float* __restrict__ m,
                                                  float* __restrict__ wsm) {
  __shared__ float red[256];
  const int p = blockIdx.x, tid = threadIdx.x;
  float lmax = -1e30f;
  for (int r = tid; r < 980; r += 256) lmax = fmaxf(lmax, m[r*PP + p]);
  red[tid] = lmax; __syncthreads();
  for (int s = 128; s; s >>= 1) { if (tid < s) red[tid] = fmaxf(red[tid], red[tid+s]); __syncthreads(); }
  const float bmax = red[0]; __syncthreads();
  float lsum = 0.f;
  for (int r = tid; r < 980; r += 256) {
    const float e = __expf(m[r*PP + p] - bmax);
    wsm[p*980 + r] = e; lsum += e;
  }
  red[tid] = lsum; __syncthreads();
  for (int s = 128; s; s >>= 1) { if (tid < s) red[tid] += red[tid+s]; __syncthreads(); }
  const float invZ = 1.f / red[0];
  for (int r = tid; r < 980; r += 256) wsm[p*980 + r] *= invZ;
}

__global__ __launch_bounds__(256) void protos_part(const float* __restrict__ wsm,
    const ushort* __restrict__ xout, float* __restrict__ part) {
  const int p = blockIdx.y, chunk = blockIdx.x, tid = threadIdx.x;
  const int r0 = chunk*49;
  float a0 = 0.f, a1 = 0.f;
  for (int r = r0; r < r0 + 49; ++r) {
    const float w = wsm[p*980 + r];
    a0 = fmaf(w, bf2f(xout[(size_t)r*HD + tid]), a0);
    a1 = fmaf(w, bf2f(xout[(size_t)r*HD + tid + 256]), a1);
  }
  float* o = part + (((size_t)p*20 + chunk) << 9);
  o[tid] = a0;
  o[tid + 256] = a1;
}

__global__ __launch_bounds__(256) void protos_fin(const float* __restrict__ part,
                                                  float* __restrict__ pn) {
  __shared__ float red[256];
  const int p = blockIdx.x, tid = threadIdx.x;
  float a0 = 0.f, a1 = 0.f;
  for (int cch = 0; cch < 20; ++cch) {
    const float* o = part + (((size_t)p*20 + cch) << 9);
    a0 += o[tid];
    a1 += o[tid + 256];
  }
  red[tid] = a0*a0 + a1*a1; __syncthreads();
  for (int s = 128; s; s >>= 1) { if (tid < s) red[tid] += red[tid+s]; __syncthreads(); }
  const float rn = 1.f / fmaxf(sqrtf(red[0]), 1e-12f);
  pn[p*HD + tid] = a0*rn;
  pn[p*HD + tid + 256] = a1*rn;
}

__global__ __launch_bounds__(256) void losses_kernel(const float* __restrict__ pn, float* __restrict__ out) {
  __shared__ float redc[256], redd[256];
  const int tid = threadIdx.x;
  float cpart = 0.f, dpart = 0.f;
  for (int d = tid; d < HD; d += 256) {
    float a[PP];
#pragma unroll
    for (int j = 0; j < PP; ++j) a[j] = pn[j*HD + d];
#pragma unroll
    for (int j = 0; j < PP; ++j) {
      if (d > j) {
#pragma unroll
        for (int i = 0; i < PP; ++i) {
          const float df = a[j] - a[i];
          const float t = 1.f - df*df;
          if (t > 0.f) dpart += t;
        }
      }
    }
#pragma unroll
    for (int j = 0; j < PP - 1; ++j) { const float df = a[j+1] - a[j]; cpart += df*df; }
  }
  redc[tid] = cpart; redd[tid] = dpart; __syncthreads();
  for (int s = 128; s; s >>= 1) {
    if (tid < s) { redc[tid] += redc[tid+s]; redd[tid] += redd[tid+s]; }
    __syncthreads();
  }
  if (tid == 0) {
    out[OUT_UPD + 1] = redc[0] / 9.f;
    out[OUT_UPD + 2] = redd[0] * (2.f / (90.f * 512.f));
  }
}

__global__ __launch_bounds__(256) void rowk(const ushort* __restrict__ xout, const float* __restrict__ pn,
    ushort* __restrict__ newq, float* __restrict__ feapart) {
  __shared__ float Ps[PP*HD];
  __shared__ float fred[4];
  const int tid = threadIdx.x;
  for (int idx = tid; idx < PP*HD; idx += 256) Ps[idx] = pn[idx];
  __syncthreads();
  const int row = blockIdx.x*4 + (tid >> 6);
  const int lane = tid & 63;
  const ushort* x = xout + (size_t)(WAYS*SEQ + row)*HD;
  float xv[8];
#pragma unroll
  for (int i = 0; i < 8; ++i) xv[i] = bf2f(x[i*64 + lane]);
  float sc[PP];
#pragma unroll
  for (int p = 0; p < PP; ++p) {
    float s = 0.f;
#pragma unroll
    for (int i = 0; i < 8; ++i) s = fmaf(xv[i], Ps[p*HD + i*64 + lane], s);
    sc[p] = waveSum(s);
  }
  float mx = sc[0]; int am = 0;
#pragma unroll
  for (int p = 1; p < PP; ++p) if (sc[p] > mx) { mx = sc[p]; am = p; }
  float Z = 0.f; float sp[PP];
#pragma unroll
  for (int p = 0; p < PP; ++p) { const float e = expf(sc[p] - mx); sp[p] = e; Z += e; }
  const float rz = 1.f / Z;
  float nv[8]; float ss = 0.f;
#pragma unroll
  for (int i = 0; i < 8; ++i) {
    float a = 0.f;
#pragma unroll
    for (int p = 0; p < PP; ++p) a = fmaf(sp[p], Ps[p*HD + i*64 + lane], a);
    a *= rz; nv[i] = a; ss += a*a;
  }
  ss = waveSum(ss);
  const float rn = 1.f / fmaxf(sqrtf(ss), 1e-12f);
#pragma unroll
  for (int i = 0; i < 8; ++i) newq[(size_t)row*HD + i*64 + lane] = f2bf(nv[i]*rn);
  float fp = 0.f;
#pragma unroll
  for (int i = 0; i < 8; ++i) { const float d = xv[i] - Ps[am*HD + i*64 + lane]; fp += d*d; }
  fp = waveSum(fp);
  if (lane == 0) fred[tid >> 6] = fp;
  __syncthreads();
  if (tid == 0) feapart[blockIdx.x] = fred[0] + fred[1] + fred[2] + fred[3];
}

__global__ __launch_bounds__(256) void fea_finalize(const float* __restrict__ feapart,
                                                    float* __restrict__ out) {
  __shared__ float red[256];
  float s = 0.f;
  for (int i = threadIdx.x; i < NBLK_ROWK; i += 256) s += feapart[i];
  red[threadIdx.x] = s; __syncthreads();
  for (int st = 128; st; st >>= 1) {
    if (threadIdx.x < st) red[threadIdx.x] += red[threadIdx.x + st];
    __syncthreads();
  }
  if (threadIdx.x == 0) out[OUT_UPD] = red[0] / (float)((size_t)NQB*SEQ*HD);
}

__global__ __launch_bounds__(256) void bn2_apply(const float* __restrict__ y2, const float* __restrict__ scale,
    const float* __restrict__ shift, const float* __restrict__ query, float* __restrict__ out) {
  __shared__ float tile[32][33];
  const int n = blockIdx.z, o0 = blockIdx.y*32, hw0 = blockIdx.x*32;
  const int tj = threadIdx.x & 31, ti = threadIdx.x >> 5;
#pragma unroll
  for (int it = 0; it < 4; ++it) {
    const int hw = hw0 + it*8 + ti;
    const int o = o0 + tj;
    float v = 0.f;
    if (hw < SEQ) v = fmaxf(fmaf(y2[((size_t)n*SEQ + hw)*FDIMC + o], scale[o], shift[o]), 0.f);
    tile[it*8 + ti][tj] = v;
  }
  __syncthreads();
#pragma unroll
  for (int it = 0; it < 4; ++it) {
    const int o = o0 + it*8 + ti;
    const int hw = hw0 + tj;
    if (hw < SEQ) {
      const size_t oi = ((size_t)n*FDIMC + o)*SEQ + hw;
      out[oi] = tile[tj][it*8 + ti] + query[oi];
    }
  }
}

extern "C" void kernel_launch(void* const* d_in, const int* in_sizes, int n_in,
                              void* d_out, int out_size, void* d_ws, size_t ws_size,
                              hipStream_t stream) {
  const float* key   = (const float*)d_in[0];
  const float* query = (const float*)d_in[1];
  const float* Wc    = (const float*)d_in[2];
  const float* bc    = (const float*)d_in[3];
  const float* g1    = (const float*)d_in[4];
  const float* b1    = (const float*)d_in[5];
  const float* Wq    = (const float*)d_in[6];
  const float* bq    = (const float*)d_in[7];
  const float* Wk    = (const float*)d_in[8];
  const float* bk    = (const float*)d_in[9];
  const float* Wv    = (const float*)d_in[10];
  const float* bv    = (const float*)d_in[11];
  const float* Wa    = (const float*)d_in[12];
  const float* ba    = (const float*)d_in[13];
  const float* ln_g  = (const float*)d_in[14];
  const float* ln_b  = (const float*)d_in[15];
  const float* Wm    = (const float*)d_in[16];
  const float* Wo    = (const float*)d_in[17];
  const float* bo    = (const float*)d_in[18];
  const float* g2    = (const float*)d_in[19];
  const float* b2    = (const float*)d_in[20];
  float* out = (float*)d_out;
  float* w = (float*)d_ws;

  ushort* y1h   = (ushort*)(w + RB);
  ushort* P     = (ushort*)(w + RB);
  float*  y2f   = w + RB;
  ushort* xouth = (ushort*)(w + OFF_XOUT);
  ushort* VT    = (ushort*)(w + RC);
  ushort* keyT  = (ushort*)(w + RD);
  float*  tmpf  = w + RD;
  ushort* xbufh = (ushort*)(w + RE);
  ushort* srawh = (ushort*)(w + RF);
  ushort* newq  = (ushort*)(w + RF);
  ushort* ctx   = (ushort*)(w + RG);
  ushort* wh    = (ushort*)(w + RH);
  ushort* qkv   = (ushort*)(w + RQ);
  float*  feapart = w + OFF_FEAP;
  float*  bqkv  = w + OFF_BQKV;
  float*  wsm   = w + OFF_WSM;
  float*  ppart = w + OFF_PPART;
  ushort* Wcb = wh;
  ushort* Wqb = wh + 327680;     // [Wq;Wk;Wv] contiguous = fused [1536,512]
  ushort* Wab = wh + 1114112;
  ushort* Wob = wh + 1376256;

  hipMemsetAsync(w, 0, ZERO_FLOATS*sizeof(float), stream);

  key_transpose<<<dim3(7, 20, NB), 256, 0, stream>>>(key, keyT);
  wconvert<<<6656, 256, 0, stream>>>(Wc, Wq, Wk, Wv, Wa, Wo, wh);
  qkv_bias<<<6, 256, 0, stream>>>(bq, bk, bv, bqkv);

  // conv1 (bf16 MFMA, 2-phase pipeline, fused BN col-stats) -> y1h bf16
  gemm_bf<1,1><<<dim3(4, 154), 256, 0, stream>>>(keyT, Wcb, bc, nullptr, y1h, M1, HD, FDIMC,
                                                 w + OFF_CS1S, w + OFF_CS1Q);
  bn_finalize<<<2, 256, 0, stream>>>(w + OFF_CS1S, w + OFF_CS1Q, g1, b1, HD, 1.f/M1,
                                     w + OFF_ST1SC, w + OFF_ST1SH);
  bn1_apply<<<M1*HD/8/256, 256, 0, stream>>>(y1h, w + OFF_ST1SC, w + OFF_ST1SH, srawh, xbufh);
  support_mean<<<WAYS*SEQ*HD/8/256, 256, 0, stream>>>(srawh, xbufh);

  // fused QKV projection: N=1536, q-range scaled by 1/8 in epilogue
  gemm_bf<3,0><<<dim3(12, 123), 256, 0, stream>>>(xbufh, Wqb, bqkv, nullptr, qkv,
                                                  MMHA, QKVS, HD, nullptr, nullptr);

  v_transpose<<<NMHA*8, 256, 0, stream>>>(qkv, VT);
  attn_qk<<<NMHA*8, 256, 0, stream>>>(qkv, P);
  attn_pv<<<NMHA*8, 256, 0, stream>>>(P, VT, ctx);

  // out-proj -> tmp fp32 (precision-critical: pre-LN residual path)
  gemm_bf<0,0><<<dim3(4, 123), 256, 0, stream>>>(ctx, Wab, ba, tmpf, nullptr, MMHA, HD, HD, nullptr, nullptr);
  ln_kernel<<<MMHA/4, 256, 0, stream>>>(tmpf, xbufh, ln_g, ln_b, xouth);

  // prototypes + losses
  mw_kernel<<<245, 256, 0, stream>>>(xouth, Wm, w + OFF_M);
  wsm_kernel<<<PP, 256, 0, stream>>>(w + OFF_M, wsm);
  protos_part<<<dim3(20, PP), 256, 0, stream>>>(wsm, xouth, ppart);
  protos_fin<<<PP, 256, 0, stream>>>(ppart, w + OFF_PN);
  losses_kernel<<<1, 256, 0, stream>>>(w + OFF_PN, out);
  rowk<<<NBLK_ROWK, 256, 0, stream>>>(xouth, w + OFF_PN, newq, feapart);

  // conv2 -> y2 fp32 (precision-critical), fused BN col-stats
  gemm_bf<0,1><<<dim3(5, 115), 256, 0, stream>>>(newq, Wob, bo, y2f, nullptr, MQ, FDIMC, HD,
                                                 w + OFF_CS2S, w + OFF_CS2Q);
  bn_finalize<<<3, 256, 0, stream>>>(w + OFF_CS2S, w + OFF_CS2Q, g2, b2, FDIMC, 1.f/MQ,
                                     w + OFF_ST2SC, w + OFF_ST2SH);
  fea_finalize<<<1, 256, 0, stream>>>(feapart, out);
  bn2_apply<<<dim3(7, 20, NQB), 256, 0, stream>>>(y2f, w + OFF_ST2SC, w + OFF_ST2SH, query, out);
}

// Round 13
// 342.712 us; speedup vs baseline: 5.1053x; 1.0005x over previous
//
#include <hip/hip_runtime.h>
#include <math.h>

// ---- problem constants ----
#define WAYS 5
#define SHOTS 5
#define PP 10
#define FDIMC 640
#define HD 512
#define QKVS 1536
#define SEQ 196
#define NB 100
#define NQB 75
#define NMHA 80
#define M1 (NB*SEQ)       // 19600
#define MMHA (NMHA*SEQ)   // 15680
#define MQ (NQB*SEQ)      // 14700
#define NBLK_ROWK (MQ/4)  // 3675
#define OUT_UPD (NQB*FDIMC*SEQ)  // 9,408,000

// ---- small stats block (float offsets) ----
#define OFF_CS1S 0
#define OFF_CS1Q 512
#define OFF_CS2S 1024
#define OFF_CS2Q 1664
#define ZERO_FLOATS 2306
#define OFF_ST1SC 2308
#define OFF_ST1SH 2820
#define OFF_ST2SC 3332
#define OFF_ST2SH 3972
#define OFF_M    4612
#define OFF_PN   14412

// ---- big regions (float offsets) ----
#define RB 20480                   /* y1h bf16 / P bf16 / y2 fp32 ; xouth at +10M */
#define RC (RB + 15439360)         /* VT bf16 */
#define RD (RC + 8028160)          /* keyT bf16 -> tmp fp32 */
#define RE (RD + 8028160)          /* xbufh bf16 */
#define RF (RE + 8028160)          /* srawh bf16 -> newq bf16 + feapart + bqkv */
#define RG (RF + 4014080)          /* ctx bf16 -> wsm/ppart */
#define RH (RG + 4014080)          /* weights bf16 concat */
#define RQ 48424960                /* qkv bf16 [MMHA][1536] */
#define OFF_XOUT (RB + 10000000)
#define OFF_FEAP (RF + 3763200)
#define OFF_BQKV (RF + 3767296)
#define OFF_WSM  RG
#define OFF_PPART (RG + 16384)

typedef __bf16 bf16x8 __attribute__((ext_vector_type(8)));
typedef float f32x4 __attribute__((ext_vector_type(4)));

__device__ __forceinline__ ushort f2bf(float f) {
  unsigned u = __float_as_uint(f);
  return (ushort)((u + 0x7fffu + ((u >> 16) & 1u)) >> 16);
}
__device__ __forceinline__ float bf2f(ushort u) {
  return __uint_as_float(((unsigned)u) << 16);
}

__device__ __forceinline__ f32x4 mfma16(bf16x8 a, bf16x8 b, f32x4 c) {
  return __builtin_amdgcn_mfma_f32_16x16x32_bf16(a, b, c, 0, 0, 0);
}

__device__ __forceinline__ float waveSum(float v) {
#pragma unroll
  for (int o = 32; o; o >>= 1) v += __shfl_xor(v, o, 64);
  return v;
}

// async global -> LDS, 16 B per lane (wave-uniform LDS base + lane*16)
__device__ __forceinline__ void gld16(const void* g, void* l) {
  __builtin_amdgcn_global_load_lds(
      (const __attribute__((address_space(1))) void*)g,
      (__attribute__((address_space(3))) void*)l,
      16, 0, 0);
}

// ---------- transposes / converts ----------

__global__ __launch_bounds__(256) void key_transpose(const float* __restrict__ key,
                                                     ushort* __restrict__ keyT) {
  __shared__ float T[32][33];
  const int n = blockIdx.z, c0 = blockIdx.y*32, s0 = blockIdx.x*32;
  const int tj = threadIdx.x & 31, ti = threadIdx.x >> 5;
#pragma unroll
  for (int it = 0; it < 4; ++it) {
    const int cl = it*8 + ti;
    const int s = s0 + tj;
    T[cl][tj] = (s < SEQ) ? key[((size_t)n*FDIMC + c0 + cl)*SEQ + s] : 0.f;
  }
  __syncthreads();
#pragma unroll
  for (int it = 0; it < 4; ++it) {
    const int sl = it*8 + ti;
    const int s = s0 + sl;
    if (s < SEQ) keyT[((size_t)(n*SEQ + s))*FDIMC + c0 + tj] = f2bf(T[tj][sl]);
  }
}

__global__ void wconvert(const float* __restrict__ Wc, const float* __restrict__ Wq,
                         const float* __restrict__ Wk, const float* __restrict__ Wv,
                         const float* __restrict__ Wa, const float* __restrict__ Wo,
                         ushort* __restrict__ wh) {
  const int i = blockIdx.x*256 + threadIdx.x;
  float v;
  if (i < 327680) v = Wc[i];
  else if (i < 589824) v = Wq[i - 327680];
  else if (i < 851968) v = Wk[i - 589824];
  else if (i < 1114112) v = Wv[i - 851968];
  else if (i < 1376256) v = Wa[i - 1114112];
  else v = Wo[i - 1376256];
  wh[i] = f2bf(v);
}

__global__ void qkv_bias(const float* __restrict__ bq, const float* __restrict__ bk,
                         const float* __restrict__ bv, float* __restrict__ o) {
  const int i = blockIdx.x*256 + threadIdx.x;
  if (i >= QKVS) return;
  o[i] = (i < 512) ? bq[i] : (i < 1024 ? bk[i-512] : bv[i-1024]);
}

// ---------- bf16 MFMA GEMM: C = A(MxK) . W(NxK)^T + bias ----------
// OM: 0 -> fp32 out, 1 -> bf16 out, 3 -> bf16 out, cols<HD scaled by 0.125 (QKV)
// CS: 1 -> accumulate per-column sum/sumsq of fp32 output into gsum/gsq
// 2-deep counted-vmcnt pipeline (T4): at iter t, tile t+1's 4 loads are issued
// then we wait vmcnt(4) -> only tile t's loads (issued one iteration earlier)
// must land; t+1's stay in flight across compute + both barriers.
// 2-way-free slot swizzle (source pre-swizzle + matching fragment-read slot),
// bijective XCD block swizzle, direct scatter stores.
template<int OM, int CS>
__global__ __launch_bounds__(256) void gemm_bf(const ushort* __restrict__ A,
    const ushort* __restrict__ W, const float* __restrict__ bias,
    float* __restrict__ Cf, ushort* __restrict__ Ch, int M, int N, int K,
    float* __restrict__ gsum, float* __restrict__ gsq) {
  __shared__ ushort As[2][128*32];
  __shared__ ushort Bs[2][128*32];
  __shared__ float csum[128], csq[128];
  const int tid = threadIdx.x;

  // XCD-aware bijective swizzle (m204)
  const int nwg = gridDim.x * gridDim.y;
  int flat = blockIdx.y * gridDim.x + blockIdx.x;
  {
    const int q = nwg >> 3, r = nwg & 7;
    const int j = flat & 7, tt = flat >> 3;
    flat = (j < r ? j*(q+1) : r*(q+1) + (j-r)*q) + tt;
  }
  const int m0 = (flat / gridDim.x) * 128;
  const int n0 = (flat % gridDim.x) * 128;

  const int w = tid >> 6, lane = tid & 63;
  const int wr = w >> 1, wc = w & 1;
  const int g = lane >> 4, c = lane & 15;

  // staging: wave w owns chunks {w, 4+w}; source k-slot swizzled (2-way-free)
  const int srow = w*16 + (lane >> 2);
  const int sk = ((lane & 3) ^ ((lane >> 3) & 3)) * 8;
  int ar0 = m0 + srow;       if (ar0 > M-1) ar0 = M-1;
  int ar1 = m0 + 64 + srow;  if (ar1 > M-1) ar1 = M-1;
  const ushort* Ap0 = A + (size_t)ar0*K + sk;
  const ushort* Ap1 = A + (size_t)ar1*K + sk;
  const ushort* Bp0 = W + (size_t)(n0 + srow)*K + sk;
  const ushort* Bp1 = W + (size_t)(n0 + 64 + srow)*K + sk;

  f32x4 acc[4][4];
#pragma unroll
  for (int i = 0; i < 4; ++i)
#pragma unroll
    for (int j = 0; j < 4; ++j) acc[i][j] = (f32x4)(0.0f);

  const int nt = K >> 5;
  // prologue: stage tile 0 -> buf 0 (no wait; first iteration waits vmcnt(4))
  gld16(Ap0, &As[0][w*512]);
  gld16(Ap1, &As[0][(4+w)*512]);
  gld16(Bp0, &Bs[0][w*512]);
  gld16(Bp1, &Bs[0][(4+w)*512]);

  int cur = 0;
  for (int t = 0; t < nt; ++t) {
    const int nxt = cur ^ 1;
    if (t + 1 < nt) {
      // issue tile t+1 into buf[nxt] (its previous contents, tile t-1, were
      // fully consumed before the end-barrier of iteration t-1)
      const int k0 = (t + 1) << 5;
      gld16(Ap0 + k0, &As[nxt][w*512]);
      gld16(Ap1 + k0, &As[nxt][(4+w)*512]);
      gld16(Bp0 + k0, &Bs[nxt][w*512]);
      gld16(Bp1 + k0, &Bs[nxt][(4+w)*512]);
      asm volatile("s_waitcnt vmcnt(4)" ::: "memory"); // own tile-t loads landed
    } else {
      asm volatile("s_waitcnt vmcnt(0)" ::: "memory"); // drain last tile
    }
    __builtin_amdgcn_s_barrier();                      // all waves' tile-t data in LDS
    bf16x8 af[4], bfr[4];
    const int rslot = (g ^ ((c >> 1) & 3)) * 8;
#pragma unroll
    for (int mi = 0; mi < 4; ++mi) {
      const int row = wr*64 + mi*16 + c;
      af[mi] = *(const bf16x8*)(&As[cur][row*32 + rslot]);
    }
#pragma unroll
    for (int ni = 0; ni < 4; ++ni) {
      const int row = wc*64 + ni*16 + c;
      bfr[ni] = *(const bf16x8*)(&Bs[cur][row*32 + rslot]);
    }
#pragma unroll
    for (int mi = 0; mi < 4; ++mi)
#pragma unroll
      for (int ni = 0; ni < 4; ++ni)
        acc[mi][ni] = mfma16(af[mi], bfr[ni], acc[mi][ni]);
    __builtin_amdgcn_s_barrier();  // all waves done reading buf[cur]
    cur = nxt;
  }

  if (CS) {
    __syncthreads();
    if (tid < 128) { csum[tid] = 0.f; csq[tid] = 0.f; }
    __syncthreads();
  }

#pragma unroll
  for (int ni = 0; ni < 4; ++ni) {
    const int col = n0 + wc*64 + ni*16 + c;
    const float bb = bias[col];
    float ls = 0.f, lq = 0.f;
#pragma unroll
    for (int mi = 0; mi < 4; ++mi) {
#pragma unroll
      for (int q = 0; q < 4; ++q) {
        const int row = m0 + wr*64 + mi*16 + g*4 + q;
        if (row < M) {
          const float v = acc[mi][ni][q] + bb;
          if (OM == 0) Cf[(size_t)row*N + col] = v;
          else if (OM == 1) Ch[(size_t)row*N + col] = f2bf(v);
          else Ch[(size_t)row*N + col] = f2bf(col < HD ? v*0.125f : v);
          if (CS) { ls += v; lq += v*v; }
        }
      }
    }
    if (CS) {
      const int lcol = wc*64 + ni*16 + c;
      atomicAdd(&csum[lcol], ls);
      atomicAdd(&csq[lcol], lq);
    }
  }
  if (CS) {
    __syncthreads();
    if (tid < 128) {
      atomicAdd(&gsum[n0 + tid], csum[tid]);
      atomicAdd(&gsq[n0 + tid], csq[tid]);
    }
  }
}

// ---------- BN pieces ----------

__global__ void bn_finalize(const float* __restrict__ sums, const float* __restrict__ sumsq,
    const float* __restrict__ g, const float* __restrict__ b, int C, float invM,
    float* __restrict__ scale, float* __restrict__ shift) {
  const int c = blockIdx.x*256 + threadIdx.x;
  if (c >= C) return;
  const float mu = sums[c]*invM;
  const float var = sumsq[c]*invM - mu*mu;
  const float sc = rsqrtf(var + 1e-5f) * g[c];
  scale[c] = sc;
  shift[c] = b[c] - mu*sc;
}

__global__ __launch_bounds__(256) void bn1_apply(const ushort* __restrict__ y1,
    const float* __restrict__ scale, const float* __restrict__ shift,
    ushort* __restrict__ srawh, ushort* __restrict__ xbufh) {
  const int i8 = blockIdx.x*256 + threadIdx.x;
  if (i8 >= M1*HD/8) return;
  const int e = i8 << 3;
  const int col = e & (HD - 1);
  const uint4 raw = ((const uint4*)y1)[i8];
  unsigned rw[4] = {raw.x, raw.y, raw.z, raw.w};
  unsigned res[4];
#pragma unroll
  for (int j = 0; j < 4; ++j) {
    float v0 = bf2f((ushort)(rw[j] & 0xffffu));
    float v1 = bf2f((ushort)(rw[j] >> 16));
    v0 = fmaxf(fmaf(v0, scale[col + 2*j],     shift[col + 2*j]),     0.f);
    v1 = fmaxf(fmaf(v1, scale[col + 2*j + 1], shift[col + 2*j + 1]), 0.f);
    res[j] = (unsigned)f2bf(v0) | ((unsigned)f2bf(v1) << 16);
  }
  const uint4 o = make_uint4(res[0], res[1], res[2], res[3]);
  if (e < 25*SEQ*HD) ((uint4*)srawh)[i8] = o;
  else ((uint4*)xbufh)[i8 - (20*SEQ*HD/8)] = o;
}

__global__ void support_mean(const ushort* __restrict__ srawh, ushort* __restrict__ xbufh) {
  const int i8 = blockIdx.x*256 + threadIdx.x;
  if (i8 >= WAYS*SEQ*HD/8) return;
  const int e = i8 << 3;
  const int w = e / (SEQ*HD);
  const int rem = e - w*(SEQ*HD);
  float acc[8] = {};
#pragma unroll
  for (int s = 0; s < SHOTS; ++s) {
    const uint4 v = *(const uint4*)(srawh + (size_t)(s*WAYS + w)*(SEQ*HD) + rem);
    const unsigned rw[4] = {v.x, v.y, v.z, v.w};
#pragma unroll
    for (int j = 0; j < 4; ++j) {
      acc[2*j]   += bf2f((ushort)(rw[j] & 0xffffu));
      acc[2*j+1] += bf2f((ushort)(rw[j] >> 16));
    }
  }
  unsigned res[4];
#pragma unroll
  for (int j = 0; j < 4; ++j)
    res[j] = (unsigned)f2bf(acc[2*j]*0.2f) | ((unsigned)f2bf(acc[2*j+1]*0.2f) << 16);
  ((uint4*)xbufh)[i8] = make_uint4(res[0], res[1], res[2], res[3]);
}

// ---------- attention: QK^T + softmax -> P bf16 [bh][208][232] ----------
// q/k live in fused qkv [MMHA][1536]: q at +0 (pre-scaled 1/8), k at +512.

__global__ __launch_bounds__(256) void attn_qk(const ushort* __restrict__ qkv,
                                               ushort* __restrict__ P) {
  __shared__ ushort Ks[208*72];
  const int bh = blockIdx.x, b = bh >> 3, h = bh & 7;
  const int tid = threadIdx.x;
  for (int idx = tid; idx < 208*8; idx += 256) {
    const int row = idx >> 3, part = idx & 7;
    uint4 v = make_uint4(0u,0u,0u,0u);
    if (row < SEQ)
      v = *(const uint4*)(qkv + (size_t)(b*SEQ + row)*QKVS + 512 + h*64 + part*8);
    *(uint4*)(&Ks[row*72 + part*8]) = v;
  }
  __syncthreads();
  const int w = tid >> 6, lane = tid & 63, g = lane >> 4, c = lane & 15;
  for (int rt = w; rt < 13; rt += 4) {
    int qrow = b*SEQ + rt*16 + c; if (qrow > MMHA-1) qrow = MMHA-1;
    const bf16x8 aq0 = *(const bf16x8*)(qkv + (size_t)qrow*QKVS + h*64 + g*8);
    const bf16x8 aq1 = *(const bf16x8*)(qkv + (size_t)qrow*QKVS + h*64 + 32 + g*8);
    f32x4 acc[13];
#pragma unroll
    for (int ct = 0; ct < 13; ++ct) acc[ct] = (f32x4)(0.0f);
#pragma unroll
    for (int ct = 0; ct < 13; ++ct) {
      const bf16x8 b0 = *(const bf16x8*)(&Ks[(ct*16 + c)*72 + g*8]);
      const bf16x8 b1 = *(const bf16x8*)(&Ks[(ct*16 + c)*72 + 32 + g*8]);
      acc[ct] = mfma16(aq0, b0, acc[ct]);
      acc[ct] = mfma16(aq1, b1, acc[ct]);
    }
    if (c >= 4) acc[12] = (f32x4)(-1e30f);
    float mrow[4], Z[4];
#pragma unroll
    for (int q = 0; q < 4; ++q) {
      float mx = acc[0][q];
#pragma unroll
      for (int ct = 1; ct < 13; ++ct) mx = fmaxf(mx, acc[ct][q]);
      mrow[q] = mx;
    }
#pragma unroll
    for (int q = 0; q < 4; ++q) {
#pragma unroll
      for (int msk = 1; msk < 16; msk <<= 1)
        mrow[q] = fmaxf(mrow[q], __shfl_xor(mrow[q], msk, 64));
    }
#pragma unroll
    for (int q = 0; q < 4; ++q) Z[q] = 0.f;
#pragma unroll
    for (int ct = 0; ct < 13; ++ct)
#pragma unroll
      for (int q = 0; q < 4; ++q) {
        const float e = __expf(acc[ct][q] - mrow[q]);
        acc[ct][q] = e; Z[q] += e;
      }
#pragma unroll
    for (int q = 0; q < 4; ++q) {
#pragma unroll
      for (int msk = 1; msk < 16; msk <<= 1) Z[q] += __shfl_xor(Z[q], msk, 64);
      Z[q] = 1.f / Z[q];
    }
    const size_t pb = (size_t)bh*(208*232);
#pragma unroll
    for (int q = 0; q < 4; ++q) {
      ushort* pr = P + pb + (size_t)(rt*16 + g*4 + q)*232;
#pragma unroll
      for (int ct = 0; ct < 13; ++ct) pr[ct*16 + c] = f2bf(acc[ct][q]*Z[q]);
      pr[208 + c] = 0;
      if (c < 8) pr[224 + c] = 0;
    }
  }
}

// ---------- V transpose (v at qkv+1024) ----------

__global__ __launch_bounds__(256) void v_transpose(const ushort* __restrict__ qkv,
                                                   ushort* __restrict__ VT) {
  __shared__ ushort Vs[196*72];
  const int bh = blockIdx.x, b = bh >> 3, h = bh & 7;
  const int tid = threadIdx.x;
  for (int idx = tid; idx < 196*8; idx += 256) {
    const int row = idx >> 3, part = idx & 7;
    *(uint4*)(&Vs[row*72 + part*8]) =
        *(const uint4*)(qkv + (size_t)(b*SEQ + row)*QKVS + 1024 + h*64 + part*8);
  }
  __syncthreads();
  ushort* o = VT + (size_t)bh*64*224;
  for (int idx = tid; idx < 64*224; idx += 256) {
    const int d = idx/224, s = idx - d*224;
    o[idx] = (s < SEQ) ? Vs[s*72 + d] : (ushort)0;
  }
}

// ---------- P.V ----------

__global__ __launch_bounds__(256) void attn_pv(const ushort* __restrict__ P,
    const ushort* __restrict__ VT, ushort* __restrict__ ctx) {
  __shared__ ushort Ps[112*232];
  const int bh = blockIdx.x, b = bh >> 3, h = bh & 7;
  const int tid = threadIdx.x, w = tid >> 6, lane = tid & 63, g = lane >> 4, c = lane & 15;
  bf16x8 bv[7];
  const ushort* vt = VT + (size_t)bh*64*224 + (size_t)(w*16 + c)*224;
#pragma unroll
  for (int ks = 0; ks < 7; ++ks) bv[ks] = *(const bf16x8*)(vt + ks*32 + g*8);
  const char* pg = (const char*)(P + (size_t)bh*(208*232));
#pragma unroll
  for (int half = 0; half < 2; ++half) {
    const int r0 = half ? 112 : 0;
    const int nbytes = half ? 96*464 : 112*464;
    __syncthreads();
    for (int byte = tid*16; byte < nbytes; byte += 4096)
      *(uint4*)((char*)Ps + byte) = *(const uint4*)(pg + r0*464 + byte);
    __syncthreads();
    const int rtlo = half ? 7 : 0, rthi = half ? 13 : 7;
    for (int rt = rtlo; rt < rthi; ++rt) {
      const int lrow = rt*16 - r0 + c;
      f32x4 acc = (f32x4)(0.0f);
#pragma unroll
      for (int ks = 0; ks < 7; ++ks) {
        const bf16x8 a = *(const bf16x8*)(&Ps[lrow*232 + ks*32 + g*8]);
        acc = mfma16(a, bv[ks], acc);
      }
#pragma unroll
      for (int q = 0; q < 4; ++q) {
        const int srow = rt*16 + g*4 + q;
        if (srow < SEQ)
          ctx[((size_t)(b*SEQ + srow))*HD + h*64 + w*16 + c] = f2bf(acc[q]);
      }
    }
  }
}

// ---------- LayerNorm + residual (tmp fp32 + xin bf16 -> bf16) ----------

__global__ __launch_bounds__(256) void ln_kernel(const float* __restrict__ tmp,
    const ushort* __restrict__ xin, const float* __restrict__ g,
    const float* __restrict__ bta, ushort* __restrict__ outh) {
  const int row = blockIdx.x*4 + (threadIdx.x >> 6);
  const int lane = threadIdx.x & 63;
  const float* t = tmp + (size_t)row*HD;
  const ushort* x = xin + (size_t)row*HD;
  float v[8]; float s = 0.f;
#pragma unroll
  for (int i = 0; i < 8; ++i) {
    const float val = t[i*64 + lane] + bf2f(x[i*64 + lane]);
    v[i] = val; s += val;
  }
  s = waveSum(s);
  const float mu = s * (1.f/HD);
  float sq = 0.f;
#pragma unroll
  for (int i = 0; i < 8; ++i) { const float d = v[i] - mu; sq += d*d; }
  sq = waveSum(sq);
  const float istd = rsqrtf(sq*(1.f/HD) + 1e-5f);
#pragma unroll
  for (int i = 0; i < 8; ++i) {
    const int d = i*64 + lane;
    outh[(size_t)row*HD + d] = f2bf((v[i] - mu)*istd*g[d] + bta[d]);
  }
}

// ---------- prototypes / losses / per-row ----------

__global__ __launch_bounds__(256) void mw_kernel(const ushort* __restrict__ xout,
    const float* __restrict__ Wm, float* __restrict__ m) {
  const int row = blockIdx.x*4 + (threadIdx.x >> 6);
  const int lane = threadIdx.x & 63;
  const ushort* x = xout + (size_t)row*HD;
  float xv[8];
#pragma unroll
  for (int i = 0; i < 8; ++i) xv[i] = bf2f(x[i*64 + lane]);
#pragma unroll
  for (int p = 0; p < PP; ++p) {
    const float* wp = Wm + p*HD;
    float s = 0.f;
#pragma unroll
    for (int i = 0; i < 8; ++i) s = fmaf(xv[i], wp[i*64 + lane], s);
    s = waveSum(s);
    if (lane == 0) m[row*PP + p] = s;
  }
}

__global__ __launch_bounds__(256) void wsm_kernel(const float* __restrict__ m,
                                                  float* __restrict__ wsm) {
  __shared__ float red[256];
  const int p = blockIdx.x, tid = threadIdx.x;
  float lmax = -1e30f;
  for (int r = tid; r < 980; r += 256) lmax = fmaxf(lmax, m[r*PP + p]);
  red[tid] = lmax; __syncthreads();
  for (int s = 128; s; s >>= 1) { if (tid < s) red[tid] = fmaxf(red[tid], red[tid+s]); __syncthreads(); }
  const float bmax = red[0]; __syncthreads();
  float lsum = 0.f;
  for (int r = tid; r < 980; r += 256) {
    const float e = __expf(m[r*PP + p] - bmax);
    wsm[p*980 + r] = e; lsum += e;
  }
  red[tid] = lsum; __syncthreads();
  for (int s = 128; s; s >>= 1) { if (tid < s) red[tid] += red[tid+s]; __syncthreads(); }
  const float invZ = 1.f / red[0];
  for (int r = tid; r < 980; r += 256) wsm[p*980 + r] *= invZ;
}

__global__ __launch_bounds__(256) void protos_part(const float* __restrict__ wsm,
    const ushort* __restrict__ xout, float* __restrict__ part) {
  const int p = blockIdx.y, chunk = blockIdx.x, tid = threadIdx.x;
  const int r0 = chunk*49;
  float a0 = 0.f, a1 = 0.f;
  for (int r = r0; r < r0 + 49; ++r) {
    const float w = wsm[p*980 + r];
    a0 = fmaf(w, bf2f(xout[(size_t)r*HD + tid]), a0);
    a1 = fmaf(w, bf2f(xout[(size_t)r*HD + tid + 256]), a1);
  }
  float* o = part + (((size_t)p*20 + chunk) << 9);
  o[tid] = a0;
  o[tid + 256] = a1;
}

__global__ __launch_bounds__(256) void protos_fin(const float* __restrict__ part,
                                                  float* __restrict__ pn) {
  __shared__ float red[256];
  const int p = blockIdx.x, tid = threadIdx.x;
  float a0 = 0.f, a1 = 0.f;
  for (int cch = 0; cch < 20; ++cch) {
    const float* o = part + (((size_t)p*20 + cch) << 9);
    a0 += o[tid];
    a1 += o[tid + 256];
  }
  red[tid] = a0*a0 + a1*a1; __syncthreads();
  for (int s = 128; s; s >>= 1) { if (tid < s) red[tid] += red[tid+s]; __syncthreads(); }
  const float rn = 1.f / fmaxf(sqrtf(red[0]), 1e-12f);
  pn[p*HD + tid] = a0*rn;
  pn[p*HD + tid + 256] = a1*rn;
}

__global__ __launch_bounds__(256) void losses_kernel(const float* __restrict__ pn, float* __restrict__ out) {
  __shared__ float redc[256], redd[256];
  const int tid = threadIdx.x;
  float cpart = 0.f, dpart = 0.f;
  for (int d = tid; d < HD; d += 256) {
    float a[PP];
#pragma unroll
    for (int j = 0; j < PP; ++j) a[j] = pn[j*HD + d];
#pragma unroll
    for (int j = 0; j < PP; ++j) {
      if (d > j) {
#pragma unroll
        for (int i = 0; i < PP; ++i) {
          const float df = a[j] - a[i];
          const float t = 1.f - df*df;
          if (t > 0.f) dpart += t;
        }
      }
    }
#pragma unroll
    for (int j = 0; j < PP - 1; ++j) { const float df = a[j+1] - a[j]; cpart += df*df; }
  }
  redc[tid] = cpart; redd[tid] = dpart; __syncthreads();
  for (int s = 128; s; s >>= 1) {
    if (tid < s) { redc[tid] += redc[tid+s]; redd[tid] += redd[tid+s]; }
    __syncthreads();
  }
  if (tid == 0) {
    out[OUT_UPD + 1] = redc[0] / 9.f;
    out[OUT_UPD + 2] = redd[0] * (2.f / (90.f * 512.f));
  }
}

__global__ __launch_bounds__(256) void rowk(const ushort* __restrict__ xout, const float* __restrict__ pn,
    ushort* __restrict__ newq, float* __restrict__ feapart) {
  __shared__ float Ps[PP*HD];
  __shared__ float fred[4];
  const int tid = threadIdx.x;
  for (int idx = tid; idx < PP*HD; idx += 256) Ps[idx] = pn[idx];
  __syncthreads();
  const int row = blockIdx.x*4 + (tid >> 6);
  const int lane = tid & 63;
  const ushort* x = xout + (size_t)(WAYS*SEQ + row)*HD;
  float xv[8];
#pragma unroll
  for (int i = 0; i < 8; ++i) xv[i] = bf2f(x[i*64 + lane]);
  float sc[PP];
#pragma unroll
  for (int p = 0; p < PP; ++p) {
    float s = 0.f;
#pragma unroll
    for (int i = 0; i < 8; ++i) s = fmaf(xv[i], Ps[p*HD + i*64 + lane], s);
    sc[p] = waveSum(s);
  }
  float mx = sc[0]; int am = 0;
#pragma unroll
  for (int p = 1; p < PP; ++p) if (sc[p] > mx) { mx = sc[p]; am = p; }
  float Z = 0.f; float sp[PP];
#pragma unroll
  for (int p = 0; p < PP; ++p) { const float e = expf(sc[p] - mx); sp[p] = e; Z += e; }
  const float rz = 1.f / Z;
  float nv[8]; float ss = 0.f;
#pragma unroll
  for (int i = 0; i < 8; ++i) {
    float a = 0.f;
#pragma unroll
    for (int p = 0; p < PP; ++p) a = fmaf(sp[p], Ps[p*HD + i*64 + lane], a);
    a *= rz; nv[i] = a; ss += a*a;
  }
  ss = waveSum(ss);
  const float rn = 1.f / fmaxf(sqrtf(ss), 1e-12f);
#pragma unroll
  for (int i = 0; i < 8; ++i) newq[(size_t)row*HD + i*64 + lane] = f2bf(nv[i]*rn);
  float fp = 0.f;
#pragma unroll
  for (int i = 0; i < 8; ++i) { const float d = xv[i] - Ps[am*HD + i*64 + lane]; fp += d*d; }
  fp = waveSum(fp);
  if (lane == 0) fred[tid >> 6] = fp;
  __syncthreads();
  if (tid == 0) feapart[blockIdx.x] = fred[0] + fred[1] + fred[2] + fred[3];
}

__global__ __launch_bounds__(256) void fea_finalize(const float* __restrict__ feapart,
                                                    float* __restrict__ out) {
  __shared__ float red[256];
  float s = 0.f;
  for (int i = threadIdx.x; i < NBLK_ROWK; i += 256) s += feapart[i];
  red[threadIdx.x] = s; __syncthreads();
  for (int st = 128; st; st >>= 1) {
    if (threadIdx.x < st) red[threadIdx.x] += red[threadIdx.x + st];
    __syncthreads();
  }
  if (threadIdx.x == 0) out[OUT_UPD] = red[0] / (float)((size_t)NQB*SEQ*HD);
}

__global__ __launch_bounds__(256) void bn2_apply(const float* __restrict__ y2, const float* __restrict__ scale,
    const float* __restrict__ shift, const float* __restrict__ query, float* __restrict__ out) {
  __shared__ float tile[32][33];
  const int n = blockIdx.z, o0 = blockIdx.y*32, hw0 = blockIdx.x*32;
  const int tj = threadIdx.x & 31, ti = threadIdx.x >> 5;
#pragma unroll
  for (int it = 0; it < 4; ++it) {
    const int hw = hw0 + it*8 + ti;
    const int o = o0 + tj;
    float v = 0.f;
    if (hw < SEQ) v = fmaxf(fmaf(y2[((size_t)n*SEQ + hw)*FDIMC + o], scale[o], shift[o]), 0.f);
    tile[it*8 + ti][tj] = v;
  }
  __syncthreads();
#pragma unroll
  for (int it = 0; it < 4; ++it) {
    const int o = o0 + it*8 + ti;
    const int hw = hw0 + tj;
    if (hw < SEQ) {
      const size_t oi = ((size_t)n*FDIMC + o)*SEQ + hw;
      out[oi] = tile[tj][it*8 + ti] + query[oi];
    }
  }
}

extern "C" void kernel_launch(void* const* d_in, const int* in_sizes, int n_in,
                              void* d_out, int out_size, void* d_ws, size_t ws_size,
                              hipStream_t stream) {
  const float* key   = (const float*)d_in[0];
  const float* query = (const float*)d_in[1];
  const float* Wc    = (const float*)d_in[2];
  const float* bc    = (const float*)d_in[3];
  const float* g1    = (const float*)d_in[4];
  const float* b1    = (const float*)d_in[5];
  const float* Wq    = (const float*)d_in[6];
  const float* bq    = (const float*)d_in[7];
  const float* Wk    = (const float*)d_in[8];
  const float* bk    = (const float*)d_in[9];
  const float* Wv    = (const float*)d_in[10];
  const float* bv    = (const float*)d_in[11];
  const float* Wa    = (const float*)d_in[12];
  const float* ba    = (const float*)d_in[13];
  const float* ln_g  = (const float*)d_in[14];
  const float* ln_b  = (const float*)d_in[15];
  const float* Wm    = (const float*)d_in[16];
  const float* Wo    = (const float*)d_in[17];
  const float* bo    = (const float*)d_in[18];
  const float* g2    = (const float*)d_in[19];
  const float* b2    = (const float*)d_in[20];
  float* out = (float*)d_out;
  float* w = (float*)d_ws;

  ushort* y1h   = (ushort*)(w + RB);
  ushort* P     = (ushort*)(w + RB);
  float*  y2f   = w + RB;
  ushort* xouth = (ushort*)(w + OFF_XOUT);
  ushort* VT    = (ushort*)(w + RC);
  ushort* keyT  = (ushort*)(w + RD);
  float*  tmpf  = w + RD;
  ushort* xbufh = (ushort*)(w + RE);
  ushort* srawh = (ushort*)(w + RF);
  ushort* newq  = (ushort*)(w + RF);
  ushort* ctx   = (ushort*)(w + RG);
  ushort* wh    = (ushort*)(w + RH);
  ushort* qkv   = (ushort*)(w + RQ);
  float*  feapart = w + OFF_FEAP;
  float*  bqkv  = w + OFF_BQKV;
  float*  wsm   = w + OFF_WSM;
  float*  ppart = w + OFF_PPART;
  ushort* Wcb = wh;
  ushort* Wqb = wh + 327680;     // [Wq;Wk;Wv] contiguous = fused [1536,512]
  ushort* Wab = wh + 1114112;
  ushort* Wob = wh + 1376256;

  hipMemsetAsync(w, 0, ZERO_FLOATS*sizeof(float), stream);

  key_transpose<<<dim3(7, 20, NB), 256, 0, stream>>>(key, keyT);
  wconvert<<<6656, 256, 0, stream>>>(Wc, Wq, Wk, Wv, Wa, Wo, wh);
  qkv_bias<<<6, 256, 0, stream>>>(bq, bk, bv, bqkv);

  // conv1 (bf16 MFMA, counted-vmcnt pipeline, fused BN col-stats) -> y1h bf16
  gemm_bf<1,1><<<dim3(4, 154), 256, 0, stream>>>(keyT, Wcb, bc, nullptr, y1h, M1, HD, FDIMC,
                                                 w + OFF_CS1S, w + OFF_CS1Q);
  bn_finalize<<<2, 256, 0, stream>>>(w + OFF_CS1S, w + OFF_CS1Q, g1, b1, HD, 1.f/M1,
                                     w + OFF_ST1SC, w + OFF_ST1SH);
  bn1_apply<<<M1*HD/8/256, 256, 0, stream>>>(y1h, w + OFF_ST1SC, w + OFF_ST1SH, srawh, xbufh);
  support_mean<<<WAYS*SEQ*HD/8/256, 256, 0, stream>>>(srawh, xbufh);

  // fused QKV projection: N=1536, q-range scaled by 1/8 in epilogue
  gemm_bf<3,0><<<dim3(12, 123), 256, 0, stream>>>(xbufh, Wqb, bqkv, nullptr, qkv,
                                                  MMHA, QKVS, HD, nullptr, nullptr);

  v_transpose<<<NMHA*8, 256, 0, stream>>>(qkv, VT);
  attn_qk<<<NMHA*8, 256, 0, stream>>>(qkv, P);
  attn_pv<<<NMHA*8, 256, 0, stream>>>(P, VT, ctx);

  // out-proj -> tmp fp32 (precision-critical: pre-LN residual path)
  gemm_bf<0,0><<<dim3(4, 123), 256, 0, stream>>>(ctx, Wab, ba, tmpf, nullptr, MMHA, HD, HD, nullptr, nullptr);
  ln_kernel<<<MMHA/4, 256, 0, stream>>>(tmpf, xbufh, ln_g, ln_b, xouth);

  // prototypes + losses
  mw_kernel<<<245, 256, 0, stream>>>(xouth, Wm, w + OFF_M);
  wsm_kernel<<<PP, 256, 0, stream>>>(w + OFF_M, wsm);
  protos_part<<<dim3(20, PP), 256, 0, stream>>>(wsm, xouth, ppart);
  protos_fin<<<PP, 256, 0, stream>>>(ppart, w + OFF_PN);
  losses_kernel<<<1, 256, 0, stream>>>(w + OFF_PN, out);
  rowk<<<NBLK_ROWK, 256, 0, stream>>>(xouth, w + OFF_PN, newq, feapart);

  // conv2 -> y2 fp32 (precision-critical), fused BN col-stats
  gemm_bf<0,1><<<dim3(5, 115), 256, 0, stream>>>(newq, Wob, bo, y2f, nullptr, MQ, FDIMC, HD,
                                                 w + OFF_CS2S, w + OFF_CS2Q);
  bn_finalize<<<3, 256, 0, stream>>>(w + OFF_CS2S, w + OFF_CS2Q, g2, b2, FDIMC, 1.f/MQ,
                                     w + OFF_ST2SC, w + OFF_ST2SH);
  fea_finalize<<<1, 256, 0, stream>>>(feapart, out);
  bn2_apply<<<dim3(7, 20, NQB), 256, 0, stream>>>(y2f, w + OFF_ST2SC, w + OFF_ST2SH, query, out);
}